// Round 9
// baseline (1821.552 us; speedup 1.0000x reference)
//
#include <hip/hip_runtime.h>
#include <stdint.h>

typedef unsigned short u16;
typedef unsigned int u32;
typedef __attribute__((ext_vector_type(8))) short short8;
typedef __attribute__((ext_vector_type(8))) _Float16 half8;
typedef __attribute__((ext_vector_type(4))) float f32x4;

static constexpr int NE = 16, NB = 4096, DIN = 1024, DH = 2048, DOUT = 1024;
#define THR_GAP1 5e-3f   // tier-1: plain-fp16 bid gap (~30 sigma of gap error)
#define THR_GAP2 1e-4f   // tier-2: split-fp16 bid gap

// ---- ws layout (bytes), overlays by lifetime, total ~235 MiB ----
static constexpr size_t PX_OFF      = 0;
static constexpr size_t XSEL_OFF    = 0;                                   // 32 MiB (after repair1)
static constexpr size_t CONTRIB_OFF = 0;                                   // 32 MiB
static constexpr size_t PW1_OFF     = (size_t)32 * 1024 * 1024;            // 128 MiB
static constexpr size_t PW2_OFF     = PW1_OFF;                             // 64 MiB (after hsel)
static constexpr size_t HSEL_OFF    = PW1_OFF + (size_t)128 * 1024 * 1024; // 64 MiB
static constexpr size_t BIDS_OFF    = HSEL_OFF + (size_t)16384 * 2048 * 2;
static constexpr size_t LISTS_OFF   = BIDS_OFF + (size_t)NE * NB * 4;
static constexpr size_t CNT_OFF     = LISTS_OFF + (size_t)NE * NB * 4;
static constexpr size_t RCNT_OFF    = CNT_OFF + 64;                        // rcnt1 @+0, rcnt2 @+4
static constexpr size_t RLIST1_OFF  = RCNT_OFF + 64;
static constexpr size_t RLIST2_OFF  = RLIST1_OFF + (size_t)4096 * 4;
static constexpr size_t RPART_OFF   = RLIST2_OFF + (size_t)4096 * 4;       // 4 MiB fp64 partials
static constexpr size_t RBP_OFF     = RPART_OFF + (size_t)4096 * 128 * 8;  // 4 MiB tier-1 partial bids (16 ng)
static constexpr size_t WS_NEED     = RBP_OFF + (size_t)16 * 16 * 4096 * 4;

__device__ __forceinline__ u16 f2h(float f) {
  union { _Float16 h; u16 u; } c; c.h = (_Float16)f; return c.u;
}
__device__ __forceinline__ float h2f(u16 v) {
  union { _Float16 h; u16 u; } c; c.u = v; return (float)c.h;
}
__device__ __forceinline__ void glds16(const void* gsrc, void* ldst) {
  __builtin_amdgcn_global_load_lds(
      (const __attribute__((address_space(1))) u32*)gsrc,
      (__attribute__((address_space(3))) u32*)ldst, 16, 0, 0);
}

// ---------- pack kernels: fp32 -> hi/lo fp16 MFMA-fragment images ----------
__global__ void pack_x_kernel(const float* __restrict__ x, u16* __restrict__ px) {
  int gid = blockIdx.x * 256 + threadIdx.x;      // 4096*128
  int kk = gid & 127, b = gid >> 7;
  int k0 = kk * 8;
  const float* xp = x + (size_t)b * DIN + k0;
  short8 hv, lv;
#pragma unroll
  for (int i = 0; i < 8; ++i) {
    float f = xp[i];
    u16 hb = f2h(f);
    hv[i] = (short)hb;
    lv[i] = (short)f2h(f - h2f(hb));
  }
  int mtile = b >> 7, m = b & 127;
  int kstep = k0 >> 6, kt = (k0 >> 5) & 1;
  int lane = (m & 15) + (((k0 >> 3) & 3) << 4);
  int sub = (m >> 4) * 2 + kt;
  u16* img = px + (size_t)(mtile * 16 + kstep) * 16384;
  *(short8*)(img + (size_t)((0 + sub) * 64 + lane) * 8) = hv;
  *(short8*)(img + (size_t)((16 + sub) * 64 + lane) * 8) = lv;
}

__global__ void pack_w1_kernel(const float* __restrict__ W1, u16* __restrict__ pw1) {
  int gid = blockIdx.x * 256 + threadIdx.x;      // 16*128*2048
  int n = gid & 2047;
  int kc = (gid >> 11) & 127;
  int e = gid >> 18;
  int k0 = kc * 8;
  const float* wp = W1 + ((size_t)e * DIN + k0) * DH + n;
  short8 hv, lv;
#pragma unroll
  for (int i = 0; i < 8; ++i) {
    float f = wp[(size_t)i * DH];
    u16 hb = f2h(f);
    hv[i] = (short)hb;
    lv[i] = (short)f2h(f - h2f(hb));
  }
  int ntile = n >> 7, nt4 = (n >> 4) & 7, kt = (k0 >> 5) & 1;
  int lane = (n & 15) + (((k0 >> 3) & 3) << 4);
  int sub = nt4 * 2 + kt;
  u16* img = pw1 + (size_t)((e * 16 + ntile) * 16 + (k0 >> 6)) * 16384;
  *(short8*)(img + (size_t)((0 + sub) * 64 + lane) * 8) = hv;
  *(short8*)(img + (size_t)((16 + sub) * 64 + lane) * 8) = lv;
}

__global__ void pack_w2_kernel(const float* __restrict__ W2, u16* __restrict__ pw2) {
  int gid = blockIdx.x * 256 + threadIdx.x;      // 16*256*1024
  int n = gid & 1023;
  int kc = (gid >> 10) & 255;
  int e = gid >> 18;
  int k0 = kc * 8;
  const float* wp = W2 + ((size_t)e * DH + k0) * DOUT + n;
  short8 hv;
#pragma unroll
  for (int i = 0; i < 8; ++i) hv[i] = (short)f2h(wp[(size_t)i * DOUT]);
  int ntile = n >> 7, nt4 = (n >> 4) & 7, kt = (k0 >> 5) & 1;
  int lane = (n & 15) + (((k0 >> 3) & 3) << 4);
  int sub = nt4 * 2 + kt;
  u16* img = pw2 + (size_t)((e * 8 + ntile) * 32 + (k0 >> 6)) * 8192;
  *(short8*)(img + (size_t)(sub * 64 + lane) * 8) = hv;
}

// ---------- GEMM1 (bids only): PLAIN fp16 layer1 (hi plane), streaming n-tiles ----------
__global__ __launch_bounds__(256, 3) void gemm1_bids_kernel(
    const u16* __restrict__ px, const u16* __restrict__ pw1,
    const float* __restrict__ b1, const float* __restrict__ Wb,
    const float* __restrict__ bb, float* __restrict__ bids)
{
  __shared__ u16 ldsA[8192];   // 16 KiB hi only
  __shared__ u16 ldsB[8192];
  __shared__ float bidred[2][128];
  const int mtile = blockIdx.x, e = blockIdx.y;
  const int tid = threadIdx.x, w = tid >> 6, lane = tid & 63;
  const int wm = w >> 1, wn = w & 1;

  const char* Abase = (const char*)px + (size_t)(mtile * 16) * 32768;
  const char* BbaseE = (const char*)pw1 + (size_t)(e * 16) * 16 * 32768;

  float bp[4][4];
#pragma unroll
  for (int mi = 0; mi < 4; ++mi)
#pragma unroll
    for (int r = 0; r < 4; ++r) bp[mi][r] = 0.f;

  for (int nt = 0; nt < 16; ++nt) {
    f32x4 acc[4][4];
#pragma unroll
    for (int i = 0; i < 4; ++i)
#pragma unroll
      for (int j = 0; j < 4; ++j) acc[i][j] = (f32x4)0.f;
    const char* Bnt = BbaseE + (size_t)nt * 16 * 32768;

    for (int ks = 0; ks < 16; ++ks) {
      __syncthreads();
      const char* Ak = Abase + (size_t)ks * 32768;   // hi plane = first 16 KiB
      const char* Bk = Bnt + (size_t)ks * 32768;
#pragma unroll
      for (int i = 0; i < 4; ++i) {
        int c = w * 4 + i;
        glds16(Ak + c * 1024 + lane * 16, (char*)ldsA + c * 1024);
        glds16(Bk + c * 1024 + lane * 16, (char*)ldsB + c * 1024);
      }
      __syncthreads();
#pragma unroll
      for (int ksub = 0; ksub < 2; ++ksub) {
        half8 ah[4], bh[4];
#pragma unroll
        for (int mi = 0; mi < 4; ++mi)
          ah[mi] = *(const half8*)(const void*)(ldsA + (size_t)(((wm * 4 + mi) * 2 + ksub) * 64 + lane) * 8);
#pragma unroll
        for (int ni = 0; ni < 4; ++ni)
          bh[ni] = *(const half8*)(const void*)(ldsB + (size_t)(((wn * 4 + ni) * 2 + ksub) * 64 + lane) * 8);
#pragma unroll
        for (int mi = 0; mi < 4; ++mi)
#pragma unroll
          for (int ni = 0; ni < 4; ++ni)
            acc[mi][ni] = __builtin_amdgcn_mfma_f32_16x16x32_f16(ah[mi], bh[ni], acc[mi][ni], 0, 0, 0);
      }
    }
    float b1v[4], wbv[4];
#pragma unroll
    for (int ni = 0; ni < 4; ++ni) {
      int n = nt * 128 + wn * 64 + ni * 16 + (lane & 15);
      b1v[ni] = b1[e * DH + n];
      wbv[ni] = Wb[e * DH + n];
    }
#pragma unroll
    for (int mi = 0; mi < 4; ++mi)
#pragma unroll
      for (int r = 0; r < 4; ++r)
#pragma unroll
        for (int ni = 0; ni < 4; ++ni) {
          float v = fmaxf(acc[mi][ni][r] + b1v[ni], 0.f);
          bp[mi][r] += v * wbv[ni];
        }
  }
#pragma unroll
  for (int mi = 0; mi < 4; ++mi)
#pragma unroll
    for (int r = 0; r < 4; ++r) {
      float s = bp[mi][r];
      s += __shfl_xor(s, 1);
      s += __shfl_xor(s, 2);
      s += __shfl_xor(s, 4);
      s += __shfl_xor(s, 8);
      if ((lane & 15) == 0)
        bidred[wn][wm * 64 + mi * 16 + ((lane >> 4) << 2) + r] = s;
    }
  __syncthreads();
  if (tid < 128)
    bids[(size_t)e * NB + mtile * 128 + tid] = bidred[0][tid] + bidred[1][tid] + bb[e];
}

// ---------- top-4 (stable, strict >) + tier-1 flagging ----------
__global__ void topk_kernel(const float* __restrict__ bids, float* __restrict__ outIdx,
                            int* __restrict__ rcnt1, u32* __restrict__ rlist1)
{
  int b = blockIdx.x * 256 + threadIdx.x;
  float v[16];
#pragma unroll
  for (int e = 0; e < 16; ++e) v[e] = bids[(size_t)e * NB + b];
  int ord[16]; u32 used = 0;
  for (int j = 0; j < 16; ++j) {
    int best = 0; float bv = -3.4e38f;
    for (int t = 0; t < 16; ++t)
      if (!((used >> t) & 1) && v[t] > bv) { bv = v[t]; best = t; }
    ord[j] = best; used |= 1u << best;
  }
  for (int k = 0; k < 4; ++k) outIdx[b * 4 + k] = (float)ord[k];
  bool flag = false;
  for (int j = 0; j < 4; ++j)
    if (v[ord[j]] - v[ord[j + 1]] < THR_GAP1) flag = true;
  if (flag) {
    int slot = atomicAdd(rcnt1, 1);
    rlist1[slot] = (u32)b;
  }
}

// ---------- tier-1 repair: grid (nt=16, e=16); B slab per block, m-loop inside ----------
__global__ __launch_bounds__(256, 2) void repair1_kernel(
    const u16* __restrict__ px, const u16* __restrict__ pw1,
    const float* __restrict__ b1, const float* __restrict__ Wb,
    const int* __restrict__ rcnt1, const u32* __restrict__ rlist1,
    float* __restrict__ rbp)
{
  __shared__ u16 ldsA[16384];   // 32 KiB hi+lo
  __shared__ u16 ldsB[16384];
  __shared__ float bidred[2][128];
  const int nt = blockIdx.x, e = blockIdx.y;
  const int cnt = *rcnt1;
  if (cnt == 0) return;
  const int nm = (cnt + 127) >> 7;
  const int tid = threadIdx.x, w = tid >> 6, lane = tid & 63;
  const int wm = w >> 1, wn = w & 1;
  const char* Bnt = (const char*)pw1 + (size_t)((e * 16 + nt) * 16) * 32768;

  float b1v[4], wbv[4];
#pragma unroll
  for (int ni = 0; ni < 4; ++ni) {
    int n = nt * 128 + wn * 64 + ni * 16 + (lane & 15);
    b1v[ni] = b1[e * DH + n];
    wbv[ni] = Wb[e * DH + n];
  }

  for (int m = 0; m < nm; ++m) {
    int rowb[4];
#pragma unroll
    for (int t = 0; t < 4; ++t) {
      int ri = m * 128 + ((w & 1) * 4 + t) * 16 + (lane & 15);
      rowb[t] = (int)rlist1[(ri < cnt) ? ri : (cnt - 1)];
    }
    f32x4 acc[4][4];
#pragma unroll
    for (int i = 0; i < 4; ++i)
#pragma unroll
      for (int j = 0; j < 4; ++j) acc[i][j] = (f32x4)0.f;

    for (int ks = 0; ks < 16; ++ks) {
      __syncthreads();
#pragma unroll
      for (int i = 0; i < 8; ++i) {
        int c = w * 8 + i;
        int b = rowb[i >> 1];
        const char* srcA = (const char*)px
            + (size_t)((b >> 7) * 16 + ks) * 32768
            + (c >> 4) * 16384
            + (((b & 127) >> 4) * 2 + (i & 1)) * 1024
            + ((b & 15) + ((lane >> 4) << 4)) * 16;
        glds16(srcA, (char*)ldsA + c * 1024);
        glds16(Bnt + (size_t)ks * 32768 + c * 1024 + lane * 16, (char*)ldsB + c * 1024);
      }
      __syncthreads();
#pragma unroll
      for (int ksub = 0; ksub < 2; ++ksub) {
        half8 ah[4], bh[4], t[4];
#pragma unroll
        for (int mi = 0; mi < 4; ++mi)
          ah[mi] = *(const half8*)(const void*)(ldsA + (size_t)(((wm * 4 + mi) * 2 + ksub) * 64 + lane) * 8);
#pragma unroll
        for (int ni = 0; ni < 4; ++ni)
          bh[ni] = *(const half8*)(const void*)(ldsB + (size_t)(((wn * 4 + ni) * 2 + ksub) * 64 + lane) * 8);
#pragma unroll
        for (int mi = 0; mi < 4; ++mi)
#pragma unroll
          for (int ni = 0; ni < 4; ++ni)
            acc[mi][ni] = __builtin_amdgcn_mfma_f32_16x16x32_f16(ah[mi], bh[ni], acc[mi][ni], 0, 0, 0);
#pragma unroll
        for (int ni = 0; ni < 4; ++ni)
          t[ni] = *(const half8*)(const void*)(ldsB + (size_t)((16 + (wn * 4 + ni) * 2 + ksub) * 64 + lane) * 8);
#pragma unroll
        for (int mi = 0; mi < 4; ++mi)
#pragma unroll
          for (int ni = 0; ni < 4; ++ni)
            acc[mi][ni] = __builtin_amdgcn_mfma_f32_16x16x32_f16(ah[mi], t[ni], acc[mi][ni], 0, 0, 0);
#pragma unroll
        for (int mi = 0; mi < 4; ++mi)
          ah[mi] = *(const half8*)(const void*)(ldsA + (size_t)((16 + (wm * 4 + mi) * 2 + ksub) * 64 + lane) * 8);
#pragma unroll
        for (int mi = 0; mi < 4; ++mi)
#pragma unroll
          for (int ni = 0; ni < 4; ++ni)
            acc[mi][ni] = __builtin_amdgcn_mfma_f32_16x16x32_f16(ah[mi], bh[ni], acc[mi][ni], 0, 0, 0);
      }
    }
    float bp[4][4];
#pragma unroll
    for (int mi = 0; mi < 4; ++mi)
#pragma unroll
      for (int r = 0; r < 4; ++r) {
        bp[mi][r] = 0.f;
#pragma unroll
        for (int ni = 0; ni < 4; ++ni) {
          float v = fmaxf(acc[mi][ni][r] + b1v[ni], 0.f);
          bp[mi][r] += v * wbv[ni];
        }
      }
#pragma unroll
    for (int mi = 0; mi < 4; ++mi)
#pragma unroll
      for (int r = 0; r < 4; ++r) {
        float s = bp[mi][r];
        s += __shfl_xor(s, 1);
        s += __shfl_xor(s, 2);
        s += __shfl_xor(s, 4);
        s += __shfl_xor(s, 8);
        if ((lane & 15) == 0)
          bidred[wn][wm * 64 + mi * 16 + ((lane >> 4) << 2) + r] = s;
      }
    __syncthreads();
    if (tid < 128) {
      int ri = m * 128 + tid;
      if (ri < cnt)
        rbp[(size_t)(e * 16 + nt) * 4096 + ri] = bidred[0][tid] + bidred[1][tid];
    }
  }
}

// ---------- tier-1 finalize: fixed-order partial sum, re-rank, tier-2 flag ----------
__global__ void repair1_final_kernel(const float* __restrict__ bb,
                                     const int* __restrict__ rcnt1,
                                     const u32* __restrict__ rlist1,
                                     const float* __restrict__ rbp,
                                     float* __restrict__ bids,
                                     float* __restrict__ outIdx,
                                     int* __restrict__ rcnt2, u32* __restrict__ rlist2)
{
  int idx = blockIdx.x * 64 + threadIdx.x;
  int cnt = *rcnt1;
  if (idx >= cnt) return;
  int b = (int)rlist1[idx];
  float v[16];
#pragma unroll
  for (int e = 0; e < 16; ++e) {
    float s = bb[e];
    for (int ng = 0; ng < 16; ++ng) s += rbp[(size_t)(e * 16 + ng) * 4096 + idx];
    v[e] = s;
    bids[(size_t)e * NB + b] = s;   // refined bids for tier-2's unmasked experts
  }
  int ord[16]; u32 used = 0;
  for (int j = 0; j < 16; ++j) {
    int best = 0; float bv = -3.4e38f;
    for (int t = 0; t < 16; ++t)
      if (!((used >> t) & 1) && v[t] > bv) { bv = v[t]; best = t; }
    ord[j] = best; used |= 1u << best;
  }
  for (int k = 0; k < 4; ++k) outIdx[b * 4 + k] = (float)ord[k];
  u32 mask = 0;
  for (int j = 0; j < 4; ++j)
    if (v[ord[j]] - v[ord[j + 1]] < THR_GAP2) { mask |= 1u << ord[j]; mask |= 1u << ord[j + 1]; }
  if (mask) {
    int jj = 4;
    while (jj < 15 && ((mask >> ord[jj]) & 1) && v[ord[jj]] - v[ord[jj + 1]] < THR_GAP2) {
      mask |= 1u << ord[jj + 1]; ++jj;
    }
    int slot = atomicAdd(rcnt2, 1);
    rlist2[slot] = (u32)b | (mask << 16);
  }
}

// ---------- tier-2 fp64, stage 1: column-parallel partial bids ----------
__global__ __launch_bounds__(256) void repair_partial_kernel(
    const float* __restrict__ x, const float* __restrict__ W1,
    const float* __restrict__ b1, const float* __restrict__ Wb,
    const int* __restrict__ rcnt2, const u32* __restrict__ rlist2,
    double* __restrict__ rpart)
{
  __shared__ float xrow[DIN];
  __shared__ double red[256];
  const int tid = threadIdx.x;
  int cnt = *rcnt2;
  int nit = cnt << 7;                    // cnt * 16 experts * 8 chunks
  for (int item = blockIdx.x; item < nit; item += gridDim.x) {
    int it = item >> 7, e = (item >> 3) & 15, jc = item & 7;
    u32 ent = rlist2[it];
    if (!((ent >> (16 + e)) & 1)) continue;   // uniform across block
    int b = ent & 0xFFFF;
    for (int i = tid; i < DIN; i += 256) xrow[i] = x[(size_t)b * DIN + i];
    __syncthreads();
    int j = jc * 256 + tid;
    const float* wcol = W1 + (size_t)e * DIN * DH + j;
    double z0 = 0, z1 = 0, z2 = 0, z3 = 0;
    for (int k = 0; k < DIN; k += 4) {
      z0 += (double)xrow[k]     * (double)wcol[(size_t)k * DH];
      z1 += (double)xrow[k + 1] * (double)wcol[(size_t)(k + 1) * DH];
      z2 += (double)xrow[k + 2] * (double)wcol[(size_t)(k + 2) * DH];
      z3 += (double)xrow[k + 3] * (double)wcol[(size_t)(k + 3) * DH];
    }
    double z = ((z0 + z1) + (z2 + z3)) + (double)b1[e * DH + j];
    red[tid] = (z > 0.0) ? z * (double)Wb[e * DH + j] : 0.0;
    __syncthreads();
    for (int off = 128; off > 0; off >>= 1) {
      if (tid < off) red[tid] += red[tid + off];
      __syncthreads();
    }
    if (tid == 0) rpart[item] = red[0];
    __syncthreads();
  }
}

// ---------- tier-2 fp64, stage 2: fixed-order chunk sum + re-rank ----------
__global__ void repair_final_kernel(const float* __restrict__ bids,
                                    const float* __restrict__ bb,
                                    const int* __restrict__ rcnt2,
                                    const u32* __restrict__ rlist2,
                                    const double* __restrict__ rpart,
                                    float* __restrict__ outIdx)
{
  __shared__ double v[16];
  int cnt = *rcnt2;
  int tid = threadIdx.x;
  for (int it = blockIdx.x; it < cnt; it += gridDim.x) {
    u32 ent = rlist2[it];
    int b = ent & 0xFFFF;
    if (tid < 16) {
      double val;
      if ((ent >> (16 + tid)) & 1) {
        double s = (double)bb[tid];
        for (int jc = 0; jc < 8; ++jc) s += rpart[(it << 7) + (tid << 3) + jc];
        val = s;
      } else {
        val = (double)bids[(size_t)tid * NB + b];
      }
      v[tid] = val;
    }
    __syncthreads();
    if (tid == 0) {
      u32 used = 0;
      for (int k = 0; k < 4; ++k) {
        int best = 0; double bv = -1e300;
        for (int t = 0; t < 16; ++t)
          if (!((used >> t) & 1) && v[t] > bv) { bv = v[t]; best = t; }
        outIdx[b * 4 + k] = (float)best; used |= 1u << best;
      }
    }
    __syncthreads();
  }
}

// ---------- deterministic per-expert row-list compaction ----------
__global__ void build_lists_kernel(const float* __restrict__ outIdx,
                                   int* __restrict__ lists, int* __restrict__ counts)
{
  int e = blockIdx.x, tid = threadIdx.x;
  __shared__ int scan[256];
  __shared__ int base;
  if (tid == 0) base = 0;
  __syncthreads();
  for (int chunk = 0; chunk < NB; chunk += 256) {
    int b = chunk + tid;
    int slot = -1;
#pragma unroll
    for (int k = 0; k < 4; ++k)
      if ((int)outIdx[b * 4 + k] == e) slot = k;
    int flag = (slot >= 0) ? 1 : 0;
    scan[tid] = flag;
    __syncthreads();
    for (int off = 1; off < 256; off <<= 1) {
      int t = (tid >= off) ? scan[tid - off] : 0;
      __syncthreads();
      scan[tid] += t;
      __syncthreads();
    }
    if (flag) lists[e * NB + base + scan[tid] - 1] = (b << 2) | slot;
    int tot = scan[255];
    __syncthreads();
    if (tid == 0) base += tot;
    __syncthreads();
  }
  if (tid == 0) counts[e] = base;
}

// ---------- gather winner rows of x into compact row-major fp16 ----------
__global__ void gather_xsel_kernel(const float* __restrict__ x,
                                   const int* __restrict__ lists,
                                   const int* __restrict__ counts,
                                   u16* __restrict__ xsel)
{
  int tid = threadIdx.x;
  int sub = tid >> 6, lane = tid & 63;
  int ri = blockIdx.x * 4 + sub;                 // 16384 compact rows
  int e = 0, off = 0;
  for (int i = 0; i < 16; ++i) {
    int c = counts[i];
    if (ri < off + c) { e = i; break; }
    off += c;
  }
  int b = lists[e * NB + (ri - off)] >> 2;
  const float* src = x + (size_t)b * DIN + lane * 16;
  u16* dst = xsel + (size_t)ri * DIN + lane * 16;
  short8 o0, o1;
#pragma unroll
  for (int j = 0; j < 8; ++j) o0[j] = (short)f2h(src[j]);
#pragma unroll
  for (int j = 0; j < 8; ++j) o1[j] = (short)f2h(src[8 + j]);
  *(short8*)dst = o0;
  *(short8*)(dst + 8) = o1;
}

// ---------- winner-h recompute: grid (nt=16, e=16); B slab per block, m-loop inside ----------
__global__ __launch_bounds__(256, 2) void hsel_kernel(
    const u16* __restrict__ xsel, const u16* __restrict__ pw1,
    const float* __restrict__ b1, const int* __restrict__ counts,
    u16* __restrict__ hselh)
{
  __shared__ u16 ldsA[8192];   // 16 KiB
  __shared__ u16 ldsB[8192];   // 16 KiB
  const int nt = blockIdx.x, e = blockIdx.y;
  const int cnt = counts[e];
  if (cnt == 0) return;
  int offs = 0;
  for (int i = 0; i < e; ++i) offs += counts[i];
  const int tid = threadIdx.x, w = tid >> 6, lane = tid & 63;
  const int wm = w >> 1, wn = w & 1;
  const int nm = (cnt + 127) >> 7;
  const char* Bnt = (const char*)pw1 + (size_t)((e * 16 + nt) * 16) * 32768;

  float b1v[4];
#pragma unroll
  for (int ni = 0; ni < 4; ++ni)
    b1v[ni] = b1[e * DH + nt * 128 + wn * 64 + ni * 16 + (lane & 15)];

  for (int m = 0; m < nm; ++m) {
    int r0 = m * 128 + (w * 2) * 16 + (lane & 15);
    int r1 = r0 + 16;
    r0 = (r0 < cnt) ? r0 : (cnt - 1);
    r1 = (r1 < cnt) ? r1 : (cnt - 1);
    const u16* arow0 = xsel + (size_t)(offs + r0) * DIN;
    const u16* arow1 = xsel + (size_t)(offs + r1) * DIN;

    f32x4 acc[4][4];
#pragma unroll
    for (int i = 0; i < 4; ++i)
#pragma unroll
      for (int j = 0; j < 4; ++j) acc[i][j] = (f32x4)0.f;

    for (int ks = 0; ks < 16; ++ks) {
      __syncthreads();
#pragma unroll
      for (int i = 0; i < 4; ++i) {
        int c = w * 4 + i, kt = c & 1;
        const u16* ga = ((i >> 1) ? arow1 : arow0) + ks * 64 + kt * 32 + ((lane >> 4) << 3);
        glds16(ga, (char*)ldsA + c * 1024);
        glds16(Bnt + (size_t)ks * 32768 + c * 1024 + lane * 16, (char*)ldsB + c * 1024);
      }
      __syncthreads();
#pragma unroll
      for (int ksub = 0; ksub < 2; ++ksub) {
        half8 ah[4], bh[4];
#pragma unroll
        for (int mi = 0; mi < 4; ++mi)
          ah[mi] = *(const half8*)(const void*)(ldsA + (size_t)(((wm * 4 + mi) * 2 + ksub) * 64 + lane) * 8);
#pragma unroll
        for (int ni = 0; ni < 4; ++ni)
          bh[ni] = *(const half8*)(const void*)(ldsB + (size_t)(((wn * 4 + ni) * 2 + ksub) * 64 + lane) * 8);
#pragma unroll
        for (int mi = 0; mi < 4; ++mi)
#pragma unroll
          for (int ni = 0; ni < 4; ++ni)
            acc[mi][ni] = __builtin_amdgcn_mfma_f32_16x16x32_f16(ah[mi], bh[ni], acc[mi][ni], 0, 0, 0);
      }
    }
#pragma unroll
    for (int mi = 0; mi < 4; ++mi)
#pragma unroll
      for (int r = 0; r < 4; ++r) {
        int ri = m * 128 + wm * 64 + mi * 16 + ((lane >> 4) << 2) + r;
        if (ri < cnt) {
          u16* hrow = hselh + (size_t)(offs + ri) * DH;
#pragma unroll
          for (int ni = 0; ni < 4; ++ni) {
            float v = fmaxf(acc[mi][ni][r] + b1v[ni], 0.f);
            hrow[nt * 128 + wn * 64 + ni * 16 + (lane & 15)] = f2h(v);
          }
        }
      }
  }
}

// ---------- GEMM2: grid (ntile=8, e=16, ms=2); B slab per block, m-loop strided ----------
__global__ __launch_bounds__(256, 2) void gemm2_kernel(
    const u16* __restrict__ hselh, const u16* __restrict__ pw2,
    const float* __restrict__ b2, const int* __restrict__ lists,
    const int* __restrict__ counts, u16* __restrict__ contrib)
{
  __shared__ u16 ldsA[8192], ldsB[8192];
  const int ntile = blockIdx.x, e = blockIdx.y, ms = blockIdx.z;
  const int cnt = counts[e];
  if (cnt == 0) return;
  int offs = 0;
  for (int i = 0; i < e; ++i) offs += counts[i];
  const int tid = threadIdx.x, w = tid >> 6, lane = tid & 63;
  const int wm = w >> 1, wn = w & 1;
  const int nm = (cnt + 127) >> 7;
  const char* Bbase = (const char*)pw2 + (size_t)((e * 8 + ntile) * 32) * 16384;

  float b2v[4];
#pragma unroll
  for (int ni = 0; ni < 4; ++ni)
    b2v[ni] = b2[e * DOUT + ntile * 128 + wn * 64 + ni * 16 + (lane & 15)];

  for (int m = ms; m < nm; m += 2) {
    int rowg[2];
#pragma unroll
    for (int t = 0; t < 2; ++t) {
      int ri = m * 128 + (w * 2 + t) * 16 + (lane & 15);
      rowg[t] = offs + ((ri < cnt) ? ri : (cnt - 1));
    }
    f32x4 acc[4][4];
#pragma unroll
    for (int i = 0; i < 4; ++i)
#pragma unroll
      for (int j = 0; j < 4; ++j) acc[i][j] = (f32x4)0.f;

    for (int ks = 0; ks < 32; ++ks) {
      __syncthreads();
#pragma unroll
      for (int i = 0; i < 4; ++i) {
        int c = w * 4 + i, kt = c & 1;
        const u16* ga = hselh + (size_t)rowg[i >> 1] * DH + ks * 64 + kt * 32 + ((lane >> 4) << 3);
        glds16(ga, (char*)ldsA + c * 1024);
        glds16(Bbase + (size_t)ks * 16384 + c * 1024 + lane * 16, (char*)ldsB + c * 1024);
      }
      __syncthreads();
#pragma unroll
      for (int ksub = 0; ksub < 2; ++ksub) {
        half8 af[4], bf[4];
#pragma unroll
        for (int mi = 0; mi < 4; ++mi)
          af[mi] = *(const half8*)(const void*)(ldsA + (size_t)(((wm * 4 + mi) * 2 + ksub) * 64 + lane) * 8);
#pragma unroll
        for (int ni = 0; ni < 4; ++ni)
          bf[ni] = *(const half8*)(const void*)(ldsB + (size_t)(((wn * 4 + ni) * 2 + ksub) * 64 + lane) * 8);
#pragma unroll
        for (int mi = 0; mi < 4; ++mi)
#pragma unroll
          for (int ni = 0; ni < 4; ++ni)
            acc[mi][ni] = __builtin_amdgcn_mfma_f32_16x16x32_f16(af[mi], bf[ni], acc[mi][ni], 0, 0, 0);
      }
    }
#pragma unroll
    for (int mi = 0; mi < 4; ++mi)
#pragma unroll
      for (int r = 0; r < 4; ++r) {
        int ri = m * 128 + wm * 64 + mi * 16 + ((lane >> 4) << 2) + r;
        if (ri < cnt) {
          int ent = lists[e * NB + ri];
          int b = ent >> 2, slot = ent & 3;
#pragma unroll
          for (int ni = 0; ni < 4; ++ni) {
            int o = ntile * 128 + wn * 64 + ni * 16 + (lane & 15);
            contrib[(size_t)(b * 4 + slot) * DOUT + o] = f2h(acc[mi][ni][r] + b2v[ni]);
          }
        }
      }
  }
}

// ---------- final: mean over 4 winner slots ----------
__global__ void finalize_kernel(const u16* __restrict__ contrib, float* __restrict__ out)
{
  int gid = blockIdx.x * 256 + threadIdx.x;    // 524288
  int b = gid >> 7, o8 = (gid & 127) << 3;
  float s[8] = {0, 0, 0, 0, 0, 0, 0, 0};
#pragma unroll
  for (int sl = 0; sl < 4; ++sl) {
    short8 v = *(const short8*)(contrib + (size_t)(b * 4 + sl) * DOUT + o8);
#pragma unroll
    for (int j = 0; j < 8; ++j) s[j] += h2f((u16)v[j]);
  }
  float* op = out + (size_t)b * DOUT + o8;
#pragma unroll
  for (int j = 0; j < 8; ++j) op[j] = s[j] * 0.25f;
}

extern "C" void kernel_launch(void* const* d_in, const int* in_sizes, int n_in,
                              void* d_out, int out_size, void* d_ws, size_t ws_size,
                              hipStream_t stream)
{
  (void)in_sizes; (void)n_in; (void)out_size;
  if (ws_size < WS_NEED) return;   // diagnostic guard: no-op instead of faulting

  const float* x  = (const float*)d_in[0];
  const float* W1 = (const float*)d_in[1];
  const float* b1 = (const float*)d_in[2];
  const float* W2 = (const float*)d_in[3];
  const float* b2 = (const float*)d_in[4];
  const float* Wb = (const float*)d_in[5];
  const float* bb = (const float*)d_in[6];

  char* ws = (char*)d_ws;
  u16* px      = (u16*)(ws + PX_OFF);
  u16* xsel    = (u16*)(ws + XSEL_OFF);
  u16* contrib = (u16*)(ws + CONTRIB_OFF);
  u16* pw1     = (u16*)(ws + PW1_OFF);
  u16* pw2     = (u16*)(ws + PW2_OFF);
  u16* hselh   = (u16*)(ws + HSEL_OFF);
  float* bids  = (float*)(ws + BIDS_OFF);
  int* lists   = (int*)(ws + LISTS_OFF);
  int* counts  = (int*)(ws + CNT_OFF);
  int* rcnt1   = (int*)(ws + RCNT_OFF);
  int* rcnt2   = (int*)(ws + RCNT_OFF + 4);
  u32* rlist1  = (u32*)(ws + RLIST1_OFF);
  u32* rlist2  = (u32*)(ws + RLIST2_OFF);
  double* rpart = (double*)(ws + RPART_OFF);
  float* rbp   = (float*)(ws + RBP_OFF);

  float* outMain = (float*)d_out;
  float* outIdx  = (float*)d_out + (size_t)NB * DOUT;

  hipMemsetAsync(rcnt1, 0, 2 * sizeof(int), stream);
  pack_x_kernel <<<2048, 256, 0, stream>>>(x, px);
  pack_w1_kernel<<<16384, 256, 0, stream>>>(W1, pw1);
  gemm1_bids_kernel<<<dim3(32, 16), 256, 0, stream>>>(px, pw1, b1, Wb, bb, bids);
  topk_kernel<<<16, 256, 0, stream>>>(bids, outIdx, rcnt1, rlist1);
  repair1_kernel<<<dim3(16, 16), 256, 0, stream>>>(px, pw1, b1, Wb, rcnt1, rlist1, rbp);
  repair1_final_kernel<<<64, 64, 0, stream>>>(bb, rcnt1, rlist1, rbp, bids, outIdx, rcnt2, rlist2);
  repair_partial_kernel<<<2048, 256, 0, stream>>>(x, W1, b1, Wb, rcnt2, rlist2, rpart);
  repair_final_kernel<<<64, 64, 0, stream>>>(bids, bb, rcnt2, rlist2, rpart, outIdx);
  build_lists_kernel<<<16, 256, 0, stream>>>(outIdx, lists, counts);
  gather_xsel_kernel<<<4096, 256, 0, stream>>>(x, lists, counts, xsel);     // overlays px (dead after repair1)
  hsel_kernel<<<dim3(16, 16), 256, 0, stream>>>(xsel, pw1, b1, counts, hselh);
  pack_w2_kernel<<<16384, 256, 0, stream>>>(W2, pw2);                       // overlays pw1 (dead after hsel)
  gemm2_kernel<<<dim3(8, 16, 2), 256, 0, stream>>>(hselh, pw2, b2, lists, counts, contrib);
  finalize_kernel<<<2048, 256, 0, stream>>>(contrib, outMain);
}

// Round 10
// 1133.693 us; speedup vs baseline: 1.6067x; 1.6067x over previous
//
#include <hip/hip_runtime.h>
#include <stdint.h>

typedef unsigned short u16;
typedef unsigned char u8;
typedef unsigned int u32;
typedef __attribute__((ext_vector_type(8))) short short8;
typedef __attribute__((ext_vector_type(8))) _Float16 half8;
typedef __attribute__((ext_vector_type(4))) float f32x4;

static constexpr int NE = 16, NB = 4096, DIN = 1024, DH = 2048, DOUT = 1024;
#define THR_GAP1 5e-3f
#define THR_GAP2 1e-4f

// ---- SMALL-path ws layout (round-8, ~235 MiB) ----
static constexpr size_t PX_OFF      = 0;
static constexpr size_t XSEL_OFF    = 0;
static constexpr size_t CONTRIB_OFF = 0;
static constexpr size_t PW1_OFF     = (size_t)32 * 1024 * 1024;
static constexpr size_t PW2_OFF     = PW1_OFF;
static constexpr size_t HSEL_OFF    = PW1_OFF + (size_t)128 * 1024 * 1024;
static constexpr size_t BIDS_OFF    = HSEL_OFF + (size_t)16384 * 2048 * 2;
static constexpr size_t LISTS_OFF   = BIDS_OFF + (size_t)NE * NB * 4;
static constexpr size_t CNT_OFF     = LISTS_OFF + (size_t)NE * NB * 4;
static constexpr size_t RCNT_OFF    = CNT_OFF + 64;
static constexpr size_t RLIST1_OFF  = RCNT_OFF + 64;
static constexpr size_t RLIST2_OFF  = RLIST1_OFF + (size_t)4096 * 4;
static constexpr size_t RPART_OFF   = RLIST2_OFF + (size_t)4096 * 4;
static constexpr size_t RBP_OFF     = RPART_OFF + (size_t)4096 * 128 * 8;
static constexpr size_t WS_NEED_SM  = RBP_OFF + (size_t)16 * 16 * 4096 * 4;

// ---- BIG-path ws layout (~281 MiB): hfull fp8 replaces hsel/xsel ----
static constexpr size_t PXB      = 0;                                    // 16 MiB
static constexpr size_t PW1B     = (size_t)16 * 1024 * 1024;             // 128 MiB (dead after repair1)
static constexpr size_t HFULLB   = (size_t)144 * 1024 * 1024;            // 128 MiB fp8 h[e][b][n]
static constexpr size_t PW2F8B   = (size_t)16 * 1024 * 1024;             // 32 MiB (overlay pw1)
static constexpr size_t CONTRB   = (size_t)48 * 1024 * 1024;             // 32 MiB (overlay pw1)
static constexpr size_t BIDSB    = (size_t)272 * 1024 * 1024;
static constexpr size_t LISTSB   = BIDSB + (size_t)NE * NB * 4;
static constexpr size_t CNTB     = LISTSB + (size_t)NE * NB * 4;
static constexpr size_t RCNTB    = CNTB + 64;
static constexpr size_t RLIST1B  = RCNTB + 64;
static constexpr size_t RLIST2B  = RLIST1B + (size_t)4096 * 4;
static constexpr size_t RPARTB   = RLIST2B + (size_t)4096 * 4;
static constexpr size_t RBPB     = RPARTB + (size_t)4096 * 128 * 8;
static constexpr size_t WS_NEED_BIG = RBPB + (size_t)16 * 16 * 4096 * 4;

__device__ __forceinline__ u16 f2h(float f) {
  union { _Float16 h; u16 u; } c; c.h = (_Float16)f; return c.u;
}
__device__ __forceinline__ float h2f(u16 v) {
  union { _Float16 h; u16 u; } c; c.u = v; return (float)c.h;
}
__device__ __forceinline__ u8 f2e4m3(float f) {
  return (u8)(__builtin_amdgcn_cvt_pk_fp8_f32(f, f, 0, false) & 0xFF);
}
__device__ __forceinline__ void glds16(const void* gsrc, void* ldst) {
  __builtin_amdgcn_global_load_lds(
      (const __attribute__((address_space(1))) u32*)gsrc,
      (__attribute__((address_space(3))) u32*)ldst, 16, 0, 0);
}

// ---------- pack kernels ----------
__global__ void pack_x_kernel(const float* __restrict__ x, u16* __restrict__ px) {
  int gid = blockIdx.x * 256 + threadIdx.x;
  int kk = gid & 127, b = gid >> 7;
  int k0 = kk * 8;
  const float* xp = x + (size_t)b * DIN + k0;
  short8 hv, lv;
#pragma unroll
  for (int i = 0; i < 8; ++i) {
    float f = xp[i];
    u16 hb = f2h(f);
    hv[i] = (short)hb;
    lv[i] = (short)f2h(f - h2f(hb));
  }
  int mtile = b >> 7, m = b & 127;
  int kstep = k0 >> 6, kt = (k0 >> 5) & 1;
  int lane = (m & 15) + (((k0 >> 3) & 3) << 4);
  int sub = (m >> 4) * 2 + kt;
  u16* img = px + (size_t)(mtile * 16 + kstep) * 16384;
  *(short8*)(img + (size_t)((0 + sub) * 64 + lane) * 8) = hv;
  *(short8*)(img + (size_t)((16 + sub) * 64 + lane) * 8) = lv;
}

__global__ void pack_w1_kernel(const float* __restrict__ W1, u16* __restrict__ pw1) {
  int gid = blockIdx.x * 256 + threadIdx.x;
  int n = gid & 2047;
  int kc = (gid >> 11) & 127;
  int e = gid >> 18;
  int k0 = kc * 8;
  const float* wp = W1 + ((size_t)e * DIN + k0) * DH + n;
  short8 hv, lv;
#pragma unroll
  for (int i = 0; i < 8; ++i) {
    float f = wp[(size_t)i * DH];
    u16 hb = f2h(f);
    hv[i] = (short)hb;
    lv[i] = (short)f2h(f - h2f(hb));
  }
  int ntile = n >> 7, nt4 = (n >> 4) & 7, kt = (k0 >> 5) & 1;
  int lane = (n & 15) + (((k0 >> 3) & 3) << 4);
  int sub = nt4 * 2 + kt;
  u16* img = pw1 + (size_t)((e * 16 + ntile) * 16 + (k0 >> 6)) * 16384;
  *(short8*)(img + (size_t)((0 + sub) * 64 + lane) * 8) = hv;
  *(short8*)(img + (size_t)((16 + sub) * 64 + lane) * 8) = lv;
}

// fp16 W2 image (small path)
__global__ void pack_w2_kernel(const float* __restrict__ W2, u16* __restrict__ pw2) {
  int gid = blockIdx.x * 256 + threadIdx.x;
  int n = gid & 1023;
  int kc = (gid >> 10) & 255;
  int e = gid >> 18;
  int k0 = kc * 8;
  const float* wp = W2 + ((size_t)e * DH + k0) * DOUT + n;
  short8 hv;
#pragma unroll
  for (int i = 0; i < 8; ++i) hv[i] = (short)f2h(wp[(size_t)i * DOUT]);
  int ntile = n >> 7, nt4 = (n >> 4) & 7, kt = (k0 >> 5) & 1;
  int lane = (n & 15) + (((k0 >> 3) & 3) << 4);
  int sub = nt4 * 2 + kt;
  u16* img = pw2 + (size_t)((e * 8 + ntile) * 32 + (k0 >> 6)) * 8192;
  *(short8*)(img + (size_t)(sub * 64 + lane) * 8) = hv;
}

// fp8 W2 image (big path), lane-major: per (e,ntile,ks): [chunk(8)][lane(64)][16B]
// staged lane l <-> n = c*16 + (l&15), k-bytes = (l>>4)*16..+16 within 64-k window
__global__ void pack_w2f8_kernel(const float* __restrict__ W2, u8* __restrict__ pw2f8) {
  int gid = blockIdx.x * 256 + threadIdx.x;
  int n = gid & 1023;
  int kc = (gid >> 10) & 255;
  int e = gid >> 18;
  int k0 = kc * 8;
  const float* wp = W2 + ((size_t)e * DH + k0) * DOUT + n;
  float f[8];
#pragma unroll
  for (int i = 0; i < 8; ++i) f[i] = wp[(size_t)i * DOUT];
  u32 lo = (u32)__builtin_amdgcn_cvt_pk_fp8_f32(f[0], f[1], 0, false);
  lo = (u32)__builtin_amdgcn_cvt_pk_fp8_f32(f[2], f[3], (int)lo, true);
  u32 hi = (u32)__builtin_amdgcn_cvt_pk_fp8_f32(f[4], f[5], 0, false);
  hi = (u32)__builtin_amdgcn_cvt_pk_fp8_f32(f[6], f[7], (int)hi, true);
  int ntile = n >> 7, c = (n >> 4) & 7, ks = k0 >> 6;
  int l = (n & 15) + 16 * ((k0 & 63) >> 4);
  u8* img = pw2f8 + (size_t)((e * 8 + ntile) * 32 + ks) * 8192 + c * 1024 + l * 16 + (k0 & 15);
  *(u32*)img = lo;
  *(u32*)(img + 4) = hi;
}

// ---------- GEMM1: plain fp16 bids; optional full-h fp8 store ----------
template <bool SH>
__global__ __launch_bounds__(256, 3) void gemm1_bids_kernel(
    const u16* __restrict__ px, const u16* __restrict__ pw1,
    const float* __restrict__ b1, const float* __restrict__ Wb,
    const float* __restrict__ bb, float* __restrict__ bids,
    u8* __restrict__ hfull)
{
  __shared__ u16 ldsA[8192];
  __shared__ u16 ldsB[8192];
  __shared__ float bidred[2][128];
  const int mtile = blockIdx.x, e = blockIdx.y;
  const int tid = threadIdx.x, w = tid >> 6, lane = tid & 63;
  const int wm = w >> 1, wn = w & 1;

  const char* Abase = (const char*)px + (size_t)(mtile * 16) * 32768;
  const char* BbaseE = (const char*)pw1 + (size_t)(e * 16) * 16 * 32768;

  float bp[4][4];
#pragma unroll
  for (int mi = 0; mi < 4; ++mi)
#pragma unroll
    for (int r = 0; r < 4; ++r) bp[mi][r] = 0.f;

  for (int nt = 0; nt < 16; ++nt) {
    f32x4 acc[4][4];
#pragma unroll
    for (int i = 0; i < 4; ++i)
#pragma unroll
      for (int j = 0; j < 4; ++j) acc[i][j] = (f32x4)0.f;
    const char* Bnt = BbaseE + (size_t)nt * 16 * 32768;

    for (int ks = 0; ks < 16; ++ks) {
      __syncthreads();
      const char* Ak = Abase + (size_t)ks * 32768;
      const char* Bk = Bnt + (size_t)ks * 32768;
#pragma unroll
      for (int i = 0; i < 4; ++i) {
        int c = w * 4 + i;
        glds16(Ak + c * 1024 + lane * 16, (char*)ldsA + c * 1024);
        glds16(Bk + c * 1024 + lane * 16, (char*)ldsB + c * 1024);
      }
      __syncthreads();
#pragma unroll
      for (int ksub = 0; ksub < 2; ++ksub) {
        half8 ah[4], bh[4];
#pragma unroll
        for (int mi = 0; mi < 4; ++mi)
          ah[mi] = *(const half8*)(const void*)(ldsA + (size_t)(((wm * 4 + mi) * 2 + ksub) * 64 + lane) * 8);
#pragma unroll
        for (int ni = 0; ni < 4; ++ni)
          bh[ni] = *(const half8*)(const void*)(ldsB + (size_t)(((wn * 4 + ni) * 2 + ksub) * 64 + lane) * 8);
#pragma unroll
        for (int mi = 0; mi < 4; ++mi)
#pragma unroll
          for (int ni = 0; ni < 4; ++ni)
            acc[mi][ni] = __builtin_amdgcn_mfma_f32_16x16x32_f16(ah[mi], bh[ni], acc[mi][ni], 0, 0, 0);
      }
    }
    float b1v[4], wbv[4];
#pragma unroll
    for (int ni = 0; ni < 4; ++ni) {
      int n = nt * 128 + wn * 64 + ni * 16 + (lane & 15);
      b1v[ni] = b1[e * DH + n];
      wbv[ni] = Wb[e * DH + n];
    }
#pragma unroll
    for (int mi = 0; mi < 4; ++mi)
#pragma unroll
      for (int r = 0; r < 4; ++r)
#pragma unroll
        for (int ni = 0; ni < 4; ++ni) {
          float v = fmaxf(acc[mi][ni][r] + b1v[ni], 0.f);
          bp[mi][r] += v * wbv[ni];
        }
    if (SH) {
#pragma unroll
      for (int mi = 0; mi < 4; ++mi)
#pragma unroll
        for (int r = 0; r < 4; ++r) {
          int row = mtile * 128 + wm * 64 + mi * 16 + ((lane >> 4) << 2) + r;
          u8* hrow = hfull + ((size_t)e * NB + row) * DH;
#pragma unroll
          for (int ni = 0; ni < 4; ++ni) {
            float v = fmaxf(acc[mi][ni][r] + b1v[ni], 0.f);
            hrow[nt * 128 + wn * 64 + ni * 16 + (lane & 15)] = f2e4m3(v);
          }
        }
    }
  }
#pragma unroll
  for (int mi = 0; mi < 4; ++mi)
#pragma unroll
    for (int r = 0; r < 4; ++r) {
      float s = bp[mi][r];
      s += __shfl_xor(s, 1);
      s += __shfl_xor(s, 2);
      s += __shfl_xor(s, 4);
      s += __shfl_xor(s, 8);
      if ((lane & 15) == 0)
        bidred[wn][wm * 64 + mi * 16 + ((lane >> 4) << 2) + r] = s;
    }
  __syncthreads();
  if (tid < 128)
    bids[(size_t)e * NB + mtile * 128 + tid] = bidred[0][tid] + bidred[1][tid] + bb[e];
}

// ---------- top-4 + tier-1 flagging ----------
__global__ void topk_kernel(const float* __restrict__ bids, float* __restrict__ outIdx,
                            int* __restrict__ rcnt1, u32* __restrict__ rlist1)
{
  int b = blockIdx.x * 256 + threadIdx.x;
  float v[16];
#pragma unroll
  for (int e = 0; e < 16; ++e) v[e] = bids[(size_t)e * NB + b];
  int ord[16]; u32 used = 0;
  for (int j = 0; j < 16; ++j) {
    int best = 0; float bv = -3.4e38f;
    for (int t = 0; t < 16; ++t)
      if (!((used >> t) & 1) && v[t] > bv) { bv = v[t]; best = t; }
    ord[j] = best; used |= 1u << best;
  }
  for (int k = 0; k < 4; ++k) outIdx[b * 4 + k] = (float)ord[k];
  bool flag = false;
  for (int j = 0; j < 4; ++j)
    if (v[ord[j]] - v[ord[j + 1]] < THR_GAP1) flag = true;
  if (flag) {
    int slot = atomicAdd(rcnt1, 1);
    rlist1[slot] = (u32)b;
  }
}

// ---------- tier-1 repair: grid (nt=16, e=16); B slab per block, m-loop inside ----------
__global__ __launch_bounds__(256, 2) void repair1_kernel(
    const u16* __restrict__ px, const u16* __restrict__ pw1,
    const float* __restrict__ b1, const float* __restrict__ Wb,
    const int* __restrict__ rcnt1, const u32* __restrict__ rlist1,
    float* __restrict__ rbp)
{
  __shared__ u16 ldsA[16384];
  __shared__ u16 ldsB[16384];
  __shared__ float bidred[2][128];
  const int nt = blockIdx.x, e = blockIdx.y;
  const int cnt = *rcnt1;
  if (cnt == 0) return;
  const int nm = (cnt + 127) >> 7;
  const int tid = threadIdx.x, w = tid >> 6, lane = tid & 63;
  const int wm = w >> 1, wn = w & 1;
  const char* Bnt = (const char*)pw1 + (size_t)((e * 16 + nt) * 16) * 32768;

  float b1v[4], wbv[4];
#pragma unroll
  for (int ni = 0; ni < 4; ++ni) {
    int n = nt * 128 + wn * 64 + ni * 16 + (lane & 15);
    b1v[ni] = b1[e * DH + n];
    wbv[ni] = Wb[e * DH + n];
  }

  for (int m = 0; m < nm; ++m) {
    int rowb[4];
#pragma unroll
    for (int t = 0; t < 4; ++t) {
      int ri = m * 128 + ((w & 1) * 4 + t) * 16 + (lane & 15);
      rowb[t] = (int)rlist1[(ri < cnt) ? ri : (cnt - 1)];
    }
    f32x4 acc[4][4];
#pragma unroll
    for (int i = 0; i < 4; ++i)
#pragma unroll
      for (int j = 0; j < 4; ++j) acc[i][j] = (f32x4)0.f;

    for (int ks = 0; ks < 16; ++ks) {
      __syncthreads();
#pragma unroll
      for (int i = 0; i < 8; ++i) {
        int c = w * 8 + i;
        int b = rowb[i >> 1];
        const char* srcA = (const char*)px
            + (size_t)((b >> 7) * 16 + ks) * 32768
            + (c >> 4) * 16384
            + (((b & 127) >> 4) * 2 + (i & 1)) * 1024
            + ((b & 15) + ((lane >> 4) << 4)) * 16;
        glds16(srcA, (char*)ldsA + c * 1024);
        glds16(Bnt + (size_t)ks * 32768 + c * 1024 + lane * 16, (char*)ldsB + c * 1024);
      }
      __syncthreads();
#pragma unroll
      for (int ksub = 0; ksub < 2; ++ksub) {
        half8 ah[4], bh[4], t[4];
#pragma unroll
        for (int mi = 0; mi < 4; ++mi)
          ah[mi] = *(const half8*)(const void*)(ldsA + (size_t)(((wm * 4 + mi) * 2 + ksub) * 64 + lane) * 8);
#pragma unroll
        for (int ni = 0; ni < 4; ++ni)
          bh[ni] = *(const half8*)(const void*)(ldsB + (size_t)(((wn * 4 + ni) * 2 + ksub) * 64 + lane) * 8);
#pragma unroll
        for (int mi = 0; mi < 4; ++mi)
#pragma unroll
          for (int ni = 0; ni < 4; ++ni)
            acc[mi][ni] = __builtin_amdgcn_mfma_f32_16x16x32_f16(ah[mi], bh[ni], acc[mi][ni], 0, 0, 0);
#pragma unroll
        for (int ni = 0; ni < 4; ++ni)
          t[ni] = *(const half8*)(const void*)(ldsB + (size_t)((16 + (wn * 4 + ni) * 2 + ksub) * 64 + lane) * 8);
#pragma unroll
        for (int mi = 0; mi < 4; ++mi)
#pragma unroll
          for (int ni = 0; ni < 4; ++ni)
            acc[mi][ni] = __builtin_amdgcn_mfma_f32_16x16x32_f16(ah[mi], t[ni], acc[mi][ni], 0, 0, 0);
#pragma unroll
        for (int mi = 0; mi < 4; ++mi)
          ah[mi] = *(const half8*)(const void*)(ldsA + (size_t)((16 + (wm * 4 + mi) * 2 + ksub) * 64 + lane) * 8);
#pragma unroll
        for (int mi = 0; mi < 4; ++mi)
#pragma unroll
          for (int ni = 0; ni < 4; ++ni)
            acc[mi][ni] = __builtin_amdgcn_mfma_f32_16x16x32_f16(ah[mi], bh[ni], acc[mi][ni], 0, 0, 0);
      }
    }
    float bp[4][4];
#pragma unroll
    for (int mi = 0; mi < 4; ++mi)
#pragma unroll
      for (int r = 0; r < 4; ++r) {
        bp[mi][r] = 0.f;
#pragma unroll
        for (int ni = 0; ni < 4; ++ni) {
          float v = fmaxf(acc[mi][ni][r] + b1v[ni], 0.f);
          bp[mi][r] += v * wbv[ni];
        }
      }
#pragma unroll
    for (int mi = 0; mi < 4; ++mi)
#pragma unroll
      for (int r = 0; r < 4; ++r) {
        float s = bp[mi][r];
        s += __shfl_xor(s, 1);
        s += __shfl_xor(s, 2);
        s += __shfl_xor(s, 4);
        s += __shfl_xor(s, 8);
        if ((lane & 15) == 0)
          bidred[wn][wm * 64 + mi * 16 + ((lane >> 4) << 2) + r] = s;
      }
    __syncthreads();
    if (tid < 128) {
      int ri = m * 128 + tid;
      if (ri < cnt)
        rbp[(size_t)(e * 16 + nt) * 4096 + ri] = bidred[0][tid] + bidred[1][tid];
    }
  }
}

// ---------- tier-1 finalize ----------
__global__ void repair1_final_kernel(const float* __restrict__ bb,
                                     const int* __restrict__ rcnt1,
                                     const u32* __restrict__ rlist1,
                                     const float* __restrict__ rbp,
                                     float* __restrict__ bids,
                                     float* __restrict__ outIdx,
                                     int* __restrict__ rcnt2, u32* __restrict__ rlist2)
{
  int idx = blockIdx.x * 64 + threadIdx.x;
  int cnt = *rcnt1;
  if (idx >= cnt) return;
  int b = (int)rlist1[idx];
  float v[16];
#pragma unroll
  for (int e = 0; e < 16; ++e) {
    float s = bb[e];
    for (int ng = 0; ng < 16; ++ng) s += rbp[(size_t)(e * 16 + ng) * 4096 + idx];
    v[e] = s;
    bids[(size_t)e * NB + b] = s;
  }
  int ord[16]; u32 used = 0;
  for (int j = 0; j < 16; ++j) {
    int best = 0; float bv = -3.4e38f;
    for (int t = 0; t < 16; ++t)
      if (!((used >> t) & 1) && v[t] > bv) { bv = v[t]; best = t; }
    ord[j] = best; used |= 1u << best;
  }
  for (int k = 0; k < 4; ++k) outIdx[b * 4 + k] = (float)ord[k];
  u32 mask = 0;
  for (int j = 0; j < 4; ++j)
    if (v[ord[j]] - v[ord[j + 1]] < THR_GAP2) { mask |= 1u << ord[j]; mask |= 1u << ord[j + 1]; }
  if (mask) {
    int jj = 4;
    while (jj < 15 && ((mask >> ord[jj]) & 1) && v[ord[jj]] - v[ord[jj + 1]] < THR_GAP2) {
      mask |= 1u << ord[jj + 1]; ++jj;
    }
    int slot = atomicAdd(rcnt2, 1);
    rlist2[slot] = (u32)b | (mask << 16);
  }
}

// ---------- tier-2 fp64 ----------
__global__ __launch_bounds__(256) void repair_partial_kernel(
    const float* __restrict__ x, const float* __restrict__ W1,
    const float* __restrict__ b1, const float* __restrict__ Wb,
    const int* __restrict__ rcnt2, const u32* __restrict__ rlist2,
    double* __restrict__ rpart)
{
  __shared__ float xrow[DIN];
  __shared__ double red[256];
  const int tid = threadIdx.x;
  int cnt = *rcnt2;
  int nit = cnt << 7;
  for (int item = blockIdx.x; item < nit; item += gridDim.x) {
    int it = item >> 7, e = (item >> 3) & 15, jc = item & 7;
    u32 ent = rlist2[it];
    if (!((ent >> (16 + e)) & 1)) continue;
    int b = ent & 0xFFFF;
    for (int i = tid; i < DIN; i += 256) xrow[i] = x[(size_t)b * DIN + i];
    __syncthreads();
    int j = jc * 256 + tid;
    const float* wcol = W1 + (size_t)e * DIN * DH + j;
    double z0 = 0, z1 = 0, z2 = 0, z3 = 0;
    for (int k = 0; k < DIN; k += 4) {
      z0 += (double)xrow[k]     * (double)wcol[(size_t)k * DH];
      z1 += (double)xrow[k + 1] * (double)wcol[(size_t)(k + 1) * DH];
      z2 += (double)xrow[k + 2] * (double)wcol[(size_t)(k + 2) * DH];
      z3 += (double)xrow[k + 3] * (double)wcol[(size_t)(k + 3) * DH];
    }
    double z = ((z0 + z1) + (z2 + z3)) + (double)b1[e * DH + j];
    red[tid] = (z > 0.0) ? z * (double)Wb[e * DH + j] : 0.0;
    __syncthreads();
    for (int off = 128; off > 0; off >>= 1) {
      if (tid < off) red[tid] += red[tid + off];
      __syncthreads();
    }
    if (tid == 0) rpart[item] = red[0];
    __syncthreads();
  }
}

__global__ void repair_final_kernel(const float* __restrict__ bids,
                                    const float* __restrict__ bb,
                                    const int* __restrict__ rcnt2,
                                    const u32* __restrict__ rlist2,
                                    const double* __restrict__ rpart,
                                    float* __restrict__ outIdx)
{
  __shared__ double v[16];
  int cnt = *rcnt2;
  int tid = threadIdx.x;
  for (int it = blockIdx.x; it < cnt; it += gridDim.x) {
    u32 ent = rlist2[it];
    int b = ent & 0xFFFF;
    if (tid < 16) {
      double val;
      if ((ent >> (16 + tid)) & 1) {
        double s = (double)bb[tid];
        for (int jc = 0; jc < 8; ++jc) s += rpart[(it << 7) + (tid << 3) + jc];
        val = s;
      } else {
        val = (double)bids[(size_t)tid * NB + b];
      }
      v[tid] = val;
    }
    __syncthreads();
    if (tid == 0) {
      u32 used = 0;
      for (int k = 0; k < 4; ++k) {
        int best = 0; double bv = -1e300;
        for (int t = 0; t < 16; ++t)
          if (!((used >> t) & 1) && v[t] > bv) { bv = v[t]; best = t; }
        outIdx[b * 4 + k] = (float)best; used |= 1u << best;
      }
    }
    __syncthreads();
  }
}

// ---------- per-expert row lists ----------
__global__ void build_lists_kernel(const float* __restrict__ outIdx,
                                   int* __restrict__ lists, int* __restrict__ counts)
{
  int e = blockIdx.x, tid = threadIdx.x;
  __shared__ int scan[256];
  __shared__ int base;
  if (tid == 0) base = 0;
  __syncthreads();
  for (int chunk = 0; chunk < NB; chunk += 256) {
    int b = chunk + tid;
    int slot = -1;
#pragma unroll
    for (int k = 0; k < 4; ++k)
      if ((int)outIdx[b * 4 + k] == e) slot = k;
    int flag = (slot >= 0) ? 1 : 0;
    scan[tid] = flag;
    __syncthreads();
    for (int off = 1; off < 256; off <<= 1) {
      int t = (tid >= off) ? scan[tid - off] : 0;
      __syncthreads();
      scan[tid] += t;
      __syncthreads();
    }
    if (flag) lists[e * NB + base + scan[tid] - 1] = (b << 2) | slot;
    int tot = scan[255];
    __syncthreads();
    if (tid == 0) base += tot;
    __syncthreads();
  }
  if (tid == 0) counts[e] = base;
}

// ============ SMALL path: gather + hsel + gemm2 fp16 (round-8 forms) ============
__global__ void gather_xsel_kernel(const float* __restrict__ x,
                                   const int* __restrict__ lists,
                                   const int* __restrict__ counts,
                                   u16* __restrict__ xsel)
{
  int tid = threadIdx.x;
  int sub = tid >> 6, lane = tid & 63;
  int ri = blockIdx.x * 4 + sub;
  int e = 0, off = 0;
  for (int i = 0; i < 16; ++i) {
    int c = counts[i];
    if (ri < off + c) { e = i; break; }
    off += c;
  }
  int b = lists[e * NB + (ri - off)] >> 2;
  const float* src = x + (size_t)b * DIN + lane * 16;
  u16* dst = xsel + (size_t)ri * DIN + lane * 16;
  short8 o0, o1;
#pragma unroll
  for (int j = 0; j < 8; ++j) o0[j] = (short)f2h(src[j]);
#pragma unroll
  for (int j = 0; j < 8; ++j) o1[j] = (short)f2h(src[8 + j]);
  *(short8*)dst = o0;
  *(short8*)(dst + 8) = o1;
}

__global__ __launch_bounds__(256, 2) void hsel_kernel(
    const u16* __restrict__ xsel, const u16* __restrict__ pw1,
    const float* __restrict__ b1, const int* __restrict__ counts,
    u16* __restrict__ hselh)
{
  __shared__ u16 ldsA[8192];
  __shared__ u16 ldsB[8192];
  const int mtile = blockIdx.x, e = blockIdx.y, ng = blockIdx.z;
  const int cnt = counts[e];
  if (mtile * 128 >= cnt) return;
  int offs = 0;
  for (int i = 0; i < e; ++i) offs += counts[i];
  const int tid = threadIdx.x, w = tid >> 6, lane = tid & 63;
  const int wm = w >> 1, wn = w & 1;

  int r0 = mtile * 128 + (w * 2) * 16 + (lane & 15);
  int r1 = r0 + 16;
  r0 = (r0 < cnt) ? r0 : (cnt - 1);
  r1 = (r1 < cnt) ? r1 : (cnt - 1);
  const u16* arow0 = xsel + (size_t)(offs + r0) * DIN;
  const u16* arow1 = xsel + (size_t)(offs + r1) * DIN;
  const char* BbaseE = (const char*)pw1 + (size_t)(e * 16) * 16 * 32768;

  for (int nto = 0; nto < 4; ++nto) {
    int nt = ng * 4 + nto;
    f32x4 acc[4][4];
#pragma unroll
    for (int i = 0; i < 4; ++i)
#pragma unroll
      for (int j = 0; j < 4; ++j) acc[i][j] = (f32x4)0.f;
    const char* Bnt = BbaseE + (size_t)nt * 16 * 32768;

    for (int ks = 0; ks < 16; ++ks) {
      __syncthreads();
#pragma unroll
      for (int i = 0; i < 4; ++i) {
        int c = w * 4 + i, kt = c & 1;
        const u16* ga = ((i >> 1) ? arow1 : arow0) + ks * 64 + kt * 32 + ((lane >> 4) << 3);
        glds16(ga, (char*)ldsA + c * 1024);
        glds16(Bnt + (size_t)ks * 32768 + c * 1024 + lane * 16, (char*)ldsB + c * 1024);
      }
      __syncthreads();
#pragma unroll
      for (int ksub = 0; ksub < 2; ++ksub) {
        half8 ah[4], bh[4];
#pragma unroll
        for (int mi = 0; mi < 4; ++mi)
          ah[mi] = *(const half8*)(const void*)(ldsA + (size_t)(((wm * 4 + mi) * 2 + ksub) * 64 + lane) * 8);
#pragma unroll
        for (int ni = 0; ni < 4; ++ni)
          bh[ni] = *(const half8*)(const void*)(ldsB + (size_t)(((wn * 4 + ni) * 2 + ksub) * 64 + lane) * 8);
#pragma unroll
        for (int mi = 0; mi < 4; ++mi)
#pragma unroll
          for (int ni = 0; ni < 4; ++ni)
            acc[mi][ni] = __builtin_amdgcn_mfma_f32_16x16x32_f16(ah[mi], bh[ni], acc[mi][ni], 0, 0, 0);
      }
    }
    float b1v[4];
#pragma unroll
    for (int ni = 0; ni < 4; ++ni)
      b1v[ni] = b1[e * DH + nt * 128 + wn * 64 + ni * 16 + (lane & 15)];
#pragma unroll
    for (int mi = 0; mi < 4; ++mi)
#pragma unroll
      for (int r = 0; r < 4; ++r) {
        int ri = mtile * 128 + wm * 64 + mi * 16 + ((lane >> 4) << 2) + r;
        if (ri < cnt) {
          u16* hrow = hselh + (size_t)(offs + ri) * DH;
#pragma unroll
          for (int ni = 0; ni < 4; ++ni) {
            float v = fmaxf(acc[mi][ni][r] + b1v[ni], 0.f);
            hrow[nt * 128 + wn * 64 + ni * 16 + (lane & 15)] = f2h(v);
          }
        }
      }
  }
}

__global__ __launch_bounds__(256, 2) void gemm2_kernel(
    const u16* __restrict__ hselh, const u16* __restrict__ pw2,
    const float* __restrict__ b2, const int* __restrict__ lists,
    const int* __restrict__ counts, u16* __restrict__ contrib)
{
  __shared__ u16 ldsA[8192], ldsB[8192];
  const int mtile = blockIdx.x, ntile = blockIdx.y, e = blockIdx.z;
  const int cnt = counts[e];
  if (mtile * 128 >= cnt) return;
  int offs = 0;
  for (int i = 0; i < e; ++i) offs += counts[i];
  const int tid = threadIdx.x, w = tid >> 6, lane = tid & 63;
  const int wm = w >> 1, wn = w & 1;

  int rowg[2];
#pragma unroll
  for (int t = 0; t < 2; ++t) {
    int ri = mtile * 128 + (w * 2 + t) * 16 + (lane & 15);
    rowg[t] = offs + ((ri < cnt) ? ri : (cnt - 1));
  }
  const char* Bbase = (const char*)pw2 + (size_t)((e * 8 + ntile) * 32) * 16384;

  f32x4 acc[4][4];
#pragma unroll
  for (int i = 0; i < 4; ++i)
#pragma unroll
    for (int j = 0; j < 4; ++j) acc[i][j] = (f32x4)0.f;

  for (int ks = 0; ks < 32; ++ks) {
    __syncthreads();
#pragma unroll
    for (int i = 0; i < 4; ++i) {
      int c = w * 4 + i, kt = c & 1;
      const u16* ga = hselh + (size_t)rowg[i >> 1] * DH + ks * 64 + kt * 32 + ((lane >> 4) << 3);
      glds16(ga, (char*)ldsA + c * 1024);
      glds16(Bbase + (size_t)ks * 16384 + c * 1024 + lane * 16, (char*)ldsB + c * 1024);
    }
    __syncthreads();
#pragma unroll
    for (int ksub = 0; ksub < 2; ++ksub) {
      half8 af[4], bf[4];
#pragma unroll
      for (int mi = 0; mi < 4; ++mi)
        af[mi] = *(const half8*)(const void*)(ldsA + (size_t)(((wm * 4 + mi) * 2 + ksub) * 64 + lane) * 8);
#pragma unroll
      for (int ni = 0; ni < 4; ++ni)
        bf[ni] = *(const half8*)(const void*)(ldsB + (size_t)(((wn * 4 + ni) * 2 + ksub) * 64 + lane) * 8);
#pragma unroll
      for (int mi = 0; mi < 4; ++mi)
#pragma unroll
        for (int ni = 0; ni < 4; ++ni)
          acc[mi][ni] = __builtin_amdgcn_mfma_f32_16x16x32_f16(af[mi], bf[ni], acc[mi][ni], 0, 0, 0);
    }
  }
  float b2v[4];
#pragma unroll
  for (int ni = 0; ni < 4; ++ni)
    b2v[ni] = b2[e * DOUT + ntile * 128 + wn * 64 + ni * 16 + (lane & 15)];
#pragma unroll
  for (int mi = 0; mi < 4; ++mi)
#pragma unroll
    for (int r = 0; r < 4; ++r) {
      int ri = mtile * 128 + wm * 64 + mi * 16 + ((lane >> 4) << 2) + r;
      if (ri < cnt) {
        int ent = lists[e * NB + ri];
        int b = ent >> 2, slot = ent & 3;
#pragma unroll
        for (int ni = 0; ni < 4; ++ni) {
          int o = ntile * 128 + wn * 64 + ni * 16 + (lane & 15);
          contrib[(size_t)(b * 4 + slot) * DOUT + o] = f2h(acc[mi][ni][r] + b2v[ni]);
        }
      }
    }
}

// ============ BIG path: gemm2 fp8 directly from hfull ============
// LDS lane-major: chunk c, lane l holds row (c*16 + l&15), k-bytes (l>>4)*16..+16
__global__ __launch_bounds__(256, 2) void gemm2f8_kernel(
    const u8* __restrict__ hfull, const u8* __restrict__ pw2f8,
    const float* __restrict__ b2, const int* __restrict__ lists,
    const int* __restrict__ counts, u16* __restrict__ contrib)
{
  __shared__ u8 ldsA[8192], ldsB[8192];
  const int mtile = blockIdx.x, ntile = blockIdx.y, e = blockIdx.z;
  const int cnt = counts[e];
  if (mtile * 128 >= cnt) return;
  const int tid = threadIdx.x, w = tid >> 6, lane = tid & 63;
  const int wm = w >> 1, wn = w & 1;

  const u8* arow[2];
#pragma unroll
  for (int t = 0; t < 2; ++t) {
    int ri = mtile * 128 + (w * 2 + t) * 16 + (lane & 15);
    int b = lists[e * NB + ((ri < cnt) ? ri : (cnt - 1))] >> 2;
    arow[t] = hfull + ((size_t)e * NB + b) * DH;
  }
  const u8* Bbase = pw2f8 + (size_t)((e * 8 + ntile) * 32) * 8192;

  f32x4 acc[4][4];
#pragma unroll
  for (int i = 0; i < 4; ++i)
#pragma unroll
    for (int j = 0; j < 4; ++j) acc[i][j] = (f32x4)0.f;

  for (int ks = 0; ks < 32; ++ks) {
    __syncthreads();
#pragma unroll
    for (int i = 0; i < 2; ++i) {
      int c = w * 2 + i;
      glds16(arow[i] + ks * 64 + ((lane >> 4) << 4), ldsA + c * 1024);
      glds16(Bbase + (size_t)ks * 8192 + c * 1024 + lane * 16, ldsB + c * 1024);
    }
    __syncthreads();
    // fragment read: chunk c, addr = c*1024 + (l&15)*16 + (ksub*2 + ((l>>4)>>1))*256 + ((l>>4)&1)*8
    int fo = (lane & 15) * 16 + (((lane >> 4) >> 1)) * 256 + ((lane >> 4) & 1) * 8;
#pragma unroll
    for (int ksub = 0; ksub < 2; ++ksub) {
      long a8[4], b8[4];
#pragma unroll
      for (int mi = 0; mi < 4; ++mi)
        a8[mi] = *(const long*)(const void*)(ldsA + (wm * 4 + mi) * 1024 + ksub * 512 + fo);
#pragma unroll
      for (int ni = 0; ni < 4; ++ni)
        b8[ni] = *(const long*)(const void*)(ldsB + (wn * 4 + ni) * 1024 + ksub * 512 + fo);
#pragma unroll
      for (int mi = 0; mi < 4; ++mi)
#pragma unroll
        for (int ni = 0; ni < 4; ++ni)
          acc[mi][ni] = __builtin_amdgcn_mfma_f32_16x16x32_fp8_fp8(a8[mi], b8[ni], acc[mi][ni], 0, 0, 0);
    }
  }
  float b2v[4];
#pragma unroll
  for (int ni = 0; ni < 4; ++ni)
    b2v[ni] = b2[e * DOUT + ntile * 128 + wn * 64 + ni * 16 + (lane & 15)];
#pragma unroll
  for (int mi = 0; mi < 4; ++mi)
#pragma unroll
    for (int r = 0; r < 4; ++r) {
      int ri = mtile * 128 + wm * 64 + mi * 16 + ((lane >> 4) << 2) + r;
      if (ri < cnt) {
        int ent = lists[e * NB + ri];
        int b = ent >> 2, slot = ent & 3;
#pragma unroll
        for (int ni = 0; ni < 4; ++ni) {
          int o = ntile * 128 + wn * 64 + ni * 16 + (lane & 15);
          contrib[(size_t)(b * 4 + slot) * DOUT + o] = f2h(acc[mi][ni][r] + b2v[ni]);
        }
      }
    }
}

// ---------- final: mean over 4 winner slots ----------
__global__ void finalize_kernel(const u16* __restrict__ contrib, float* __restrict__ out)
{
  int gid = blockIdx.x * 256 + threadIdx.x;
  int b = gid >> 7, o8 = (gid & 127) << 3;
  float s[8] = {0, 0, 0, 0, 0, 0, 0, 0};
#pragma unroll
  for (int sl = 0; sl < 4; ++sl) {
    short8 v = *(const short8*)(contrib + (size_t)(b * 4 + sl) * DOUT + o8);
#pragma unroll
    for (int j = 0; j < 8; ++j) s[j] += h2f((u16)v[j]);
  }
  float* op = out + (size_t)b * DOUT + o8;
#pragma unroll
  for (int j = 0; j < 8; ++j) op[j] = s[j] * 0.25f;
}

extern "C" void kernel_launch(void* const* d_in, const int* in_sizes, int n_in,
                              void* d_out, int out_size, void* d_ws, size_t ws_size,
                              hipStream_t stream)
{
  (void)in_sizes; (void)n_in; (void)out_size;
  if (ws_size < WS_NEED_SM) return;
  const bool big = (ws_size >= WS_NEED_BIG);

  const float* x  = (const float*)d_in[0];
  const float* W1 = (const float*)d_in[1];
  const float* b1 = (const float*)d_in[2];
  const float* W2 = (const float*)d_in[3];
  const float* b2 = (const float*)d_in[4];
  const float* Wb = (const float*)d_in[5];
  const float* bb = (const float*)d_in[6];

  char* ws = (char*)d_ws;
  float* outMain = (float*)d_out;
  float* outIdx  = (float*)d_out + (size_t)NB * DOUT;

  if (big) {
    u16* px      = (u16*)(ws + PXB);
    u16* pw1     = (u16*)(ws + PW1B);
    u8*  hfull   = (u8*)(ws + HFULLB);
    u8*  pw2f8   = (u8*)(ws + PW2F8B);
    u16* contrib = (u16*)(ws + CONTRB);
    float* bids  = (float*)(ws + BIDSB);
    int* lists   = (int*)(ws + LISTSB);
    int* counts  = (int*)(ws + CNTB);
    int* rcnt1   = (int*)(ws + RCNTB);
    int* rcnt2   = (int*)(ws + RCNTB + 4);
    u32* rlist1  = (u32*)(ws + RLIST1B);
    u32* rlist2  = (u32*)(ws + RLIST2B);
    double* rpart = (double*)(ws + RPARTB);
    float* rbp   = (float*)(ws + RBPB);

    hipMemsetAsync(rcnt1, 0, 2 * sizeof(int), stream);
    pack_x_kernel <<<2048, 256, 0, stream>>>(x, px);
    pack_w1_kernel<<<16384, 256, 0, stream>>>(W1, pw1);
    gemm1_bids_kernel<true><<<dim3(32, 16), 256, 0, stream>>>(px, pw1, b1, Wb, bb, bids, hfull);
    topk_kernel<<<16, 256, 0, stream>>>(bids, outIdx, rcnt1, rlist1);
    repair1_kernel<<<dim3(16, 16), 256, 0, stream>>>(px, pw1, b1, Wb, rcnt1, rlist1, rbp);
    repair1_final_kernel<<<64, 64, 0, stream>>>(bb, rcnt1, rlist1, rbp, bids, outIdx, rcnt2, rlist2);
    repair_partial_kernel<<<2048, 256, 0, stream>>>(x, W1, b1, Wb, rcnt2, rlist2, rpart);
    repair_final_kernel<<<64, 64, 0, stream>>>(bids, bb, rcnt2, rlist2, rpart, outIdx);
    build_lists_kernel<<<16, 256, 0, stream>>>(outIdx, lists, counts);
    pack_w2f8_kernel<<<16384, 256, 0, stream>>>(W2, pw2f8);   // overlays pw1 (dead after repair1)
    gemm2f8_kernel<<<dim3(32, 8, 16), 256, 0, stream>>>(hfull, pw2f8, b2, lists, counts, contrib);
    finalize_kernel<<<2048, 256, 0, stream>>>(contrib, outMain);
  } else {
    u16* px      = (u16*)(ws + PX_OFF);
    u16* xsel    = (u16*)(ws + XSEL_OFF);
    u16* contrib = (u16*)(ws + CONTRIB_OFF);
    u16* pw1     = (u16*)(ws + PW1_OFF);
    u16* pw2     = (u16*)(ws + PW2_OFF);
    u16* hselh   = (u16*)(ws + HSEL_OFF);
    float* bids  = (float*)(ws + BIDS_OFF);
    int* lists   = (int*)(ws + LISTS_OFF);
    int* counts  = (int*)(ws + CNT_OFF);
    int* rcnt1   = (int*)(ws + RCNT_OFF);
    int* rcnt2   = (int*)(ws + RCNT_OFF + 4);
    u32* rlist1  = (u32*)(ws + RLIST1_OFF);
    u32* rlist2  = (u32*)(ws + RLIST2_OFF);
    double* rpart = (double*)(ws + RPART_OFF);
    float* rbp   = (float*)(ws + RBP_OFF);

    hipMemsetAsync(rcnt1, 0, 2 * sizeof(int), stream);
    pack_x_kernel <<<2048, 256, 0, stream>>>(x, px);
    pack_w1_kernel<<<16384, 256, 0, stream>>>(W1, pw1);
    gemm1_bids_kernel<false><<<dim3(32, 16), 256, 0, stream>>>(px, pw1, b1, Wb, bb, bids, nullptr);
    topk_kernel<<<16, 256, 0, stream>>>(bids, outIdx, rcnt1, rlist1);
    repair1_kernel<<<dim3(16, 16), 256, 0, stream>>>(px, pw1, b1, Wb, rcnt1, rlist1, rbp);
    repair1_final_kernel<<<64, 64, 0, stream>>>(bb, rcnt1, rlist1, rbp, bids, outIdx, rcnt2, rlist2);
    repair_partial_kernel<<<2048, 256, 0, stream>>>(x, W1, b1, Wb, rcnt2, rlist2, rpart);
    repair_final_kernel<<<64, 64, 0, stream>>>(bids, bb, rcnt2, rlist2, rpart, outIdx);
    build_lists_kernel<<<16, 256, 0, stream>>>(outIdx, lists, counts);
    gather_xsel_kernel<<<4096, 256, 0, stream>>>(x, lists, counts, xsel);
    hsel_kernel<<<dim3(32, 16, 4), 256, 0, stream>>>(xsel, pw1, b1, counts, hselh);
    pack_w2_kernel<<<16384, 256, 0, stream>>>(W2, pw2);
    gemm2_kernel<<<dim3(32, 8, 16), 256, 0, stream>>>(hselh, pw2, b2, lists, counts, contrib);
    finalize_kernel<<<2048, 256, 0, stream>>>(contrib, outMain);
  }
}

// Round 12
// 1009.691 us; speedup vs baseline: 1.8041x; 1.1228x over previous
//
#include <hip/hip_runtime.h>
#include <stdint.h>

typedef unsigned short u16;
typedef unsigned char u8;
typedef unsigned int u32;
typedef __attribute__((ext_vector_type(8))) short short8;
typedef __attribute__((ext_vector_type(8))) _Float16 half8;
typedef __attribute__((ext_vector_type(4))) float f32x4;

static constexpr int NE = 16, NB = 4096, DIN = 1024, DH = 2048, DOUT = 1024;
#define THR_GAP1 5e-3f
#define THR_GAP2 1e-4f

// ---- SMALL-path ws layout (~235 MiB) ----
static constexpr size_t PX_OFF      = 0;
static constexpr size_t XSEL_OFF    = 0;
static constexpr size_t CONTRIB_OFF = 0;
static constexpr size_t PW1_OFF     = (size_t)32 * 1024 * 1024;
static constexpr size_t PW2_OFF     = PW1_OFF;
static constexpr size_t HSEL_OFF    = PW1_OFF + (size_t)128 * 1024 * 1024;
static constexpr size_t BIDS_OFF    = HSEL_OFF + (size_t)16384 * 2048 * 2;
static constexpr size_t LISTS_OFF   = BIDS_OFF + (size_t)NE * NB * 4;   // rle early / lists late
static constexpr size_t CNT_OFF     = LISTS_OFF + (size_t)NE * NB * 4;
static constexpr size_t RCNT_OFF    = CNT_OFF + 64;
static constexpr size_t RLIST1_OFF  = RCNT_OFF + 64;
static constexpr size_t RLIST2_OFF  = RLIST1_OFF + (size_t)4096 * 4;
static constexpr size_t RPART_OFF   = RLIST2_OFF + (size_t)4096 * 4;    // bidp+cnt1e early / rpart late
static constexpr size_t RBP_OFF     = RPART_OFF + (size_t)4096 * 128 * 8;
static constexpr size_t WS_NEED_SM  = RBP_OFF + (size_t)16 * 16 * 4096 * 4;

// ---- BIG-path ws layout (~281 MiB) ----
static constexpr size_t PXB      = 0;                                    // 16 MiB
static constexpr size_t PW1B     = (size_t)16 * 1024 * 1024;             // 128 MiB (dead after repair1)
static constexpr size_t HFULLB   = (size_t)144 * 1024 * 1024;            // 128 MiB fp8 h
static constexpr size_t PW2F8B   = (size_t)16 * 1024 * 1024;             // 32 MiB (overlay pw1 after repair1)
static constexpr size_t CONTRB   = (size_t)48 * 1024 * 1024;             // 32 MiB (overlay pw1; late)
static constexpr size_t BIDSB    = (size_t)272 * 1024 * 1024;
static constexpr size_t LISTSB   = BIDSB + (size_t)NE * NB * 4;          // rle early / lists late
static constexpr size_t CNTB     = LISTSB + (size_t)NE * NB * 4;
static constexpr size_t RCNTB    = CNTB + 64;
static constexpr size_t RLIST1B  = RCNTB + 64;
static constexpr size_t RLIST2B  = RLIST1B + (size_t)4096 * 4;
static constexpr size_t RPARTB   = RLIST2B + (size_t)4096 * 4;           // bidp+cnt1e early / rpart late
static constexpr size_t RBPB     = RPARTB + (size_t)4096 * 128 * 8;
static constexpr size_t WS_NEED_BIG = RBPB + (size_t)16 * 16 * 4096 * 4;
// bidp (512 KB) + cnt1e (64 B) live at RPART*_OFF: written by gemm1/topk, read by
// topk/repair1, DEAD before repair_partial (the rpart region's first writer).

__device__ __forceinline__ u16 f2h(float f) {
  union { _Float16 h; u16 u; } c; c.h = (_Float16)f; return c.u;
}
__device__ __forceinline__ float h2f(u16 v) {
  union { _Float16 h; u16 u; } c; c.u = v; return (float)c.h;
}
__device__ __forceinline__ u8 f2e4m3(float f) {
  return (u8)(__builtin_amdgcn_cvt_pk_fp8_f32(f, f, 0, false) & 0xFF);
}
__device__ __forceinline__ void glds16(const void* gsrc, void* ldst) {
  __builtin_amdgcn_global_load_lds(
      (const __attribute__((address_space(1))) u32*)gsrc,
      (__attribute__((address_space(3))) u32*)ldst, 16, 0, 0);
}

// ---------- pack kernels ----------
__global__ void pack_x_kernel(const float* __restrict__ x, u16* __restrict__ px) {
  int gid = blockIdx.x * 256 + threadIdx.x;
  int kk = gid & 127, b = gid >> 7;
  int k0 = kk * 8;
  const float* xp = x + (size_t)b * DIN + k0;
  short8 hv, lv;
#pragma unroll
  for (int i = 0; i < 8; ++i) {
    float f = xp[i];
    u16 hb = f2h(f);
    hv[i] = (short)hb;
    lv[i] = (short)f2h(f - h2f(hb));
  }
  int mtile = b >> 7, m = b & 127;
  int kstep = k0 >> 6, kt = (k0 >> 5) & 1;
  int lane = (m & 15) + (((k0 >> 3) & 3) << 4);
  int sub = (m >> 4) * 2 + kt;
  u16* img = px + (size_t)(mtile * 16 + kstep) * 16384;
  *(short8*)(img + (size_t)((0 + sub) * 64 + lane) * 8) = hv;
  *(short8*)(img + (size_t)((16 + sub) * 64 + lane) * 8) = lv;
}

__global__ void pack_w1_kernel(const float* __restrict__ W1, u16* __restrict__ pw1) {
  int gid = blockIdx.x * 256 + threadIdx.x;
  int n = gid & 2047;
  int kc = (gid >> 11) & 127;
  int e = gid >> 18;
  int k0 = kc * 8;
  const float* wp = W1 + ((size_t)e * DIN + k0) * DH + n;
  short8 hv, lv;
#pragma unroll
  for (int i = 0; i < 8; ++i) {
    float f = wp[(size_t)i * DH];
    u16 hb = f2h(f);
    hv[i] = (short)hb;
    lv[i] = (short)f2h(f - h2f(hb));
  }
  int ntile = n >> 7, nt4 = (n >> 4) & 7, kt = (k0 >> 5) & 1;
  int lane = (n & 15) + (((k0 >> 3) & 3) << 4);
  int sub = nt4 * 2 + kt;
  u16* img = pw1 + (size_t)((e * 16 + ntile) * 16 + (k0 >> 6)) * 16384;
  *(short8*)(img + (size_t)((0 + sub) * 64 + lane) * 8) = hv;
  *(short8*)(img + (size_t)((16 + sub) * 64 + lane) * 8) = lv;
}

// fp16 W2 image (small path)
__global__ void pack_w2_kernel(const float* __restrict__ W2, u16* __restrict__ pw2) {
  int gid = blockIdx.x * 256 + threadIdx.x;
  int n = gid & 1023;
  int kc = (gid >> 10) & 255;
  int e = gid >> 18;
  int k0 = kc * 8;
  const float* wp = W2 + ((size_t)e * DH + k0) * DOUT + n;
  short8 hv;
#pragma unroll
  for (int i = 0; i < 8; ++i) hv[i] = (short)f2h(wp[(size_t)i * DOUT]);
  int ntile = n >> 7, nt4 = (n >> 4) & 7, kt = (k0 >> 5) & 1;
  int lane = (n & 15) + (((k0 >> 3) & 3) << 4);
  int sub = nt4 * 2 + kt;
  u16* img = pw2 + (size_t)((e * 8 + ntile) * 32 + (k0 >> 6)) * 8192;
  *(short8*)(img + (size_t)(sub * 64 + lane) * 8) = hv;
}

// fp8 W2 image (big path)
__global__ void pack_w2f8_kernel(const float* __restrict__ W2, u8* __restrict__ pw2f8) {
  int gid = blockIdx.x * 256 + threadIdx.x;
  int n = gid & 1023;
  int kc = (gid >> 10) & 255;
  int e = gid >> 18;
  int k0 = kc * 8;
  const float* wp = W2 + ((size_t)e * DH + k0) * DOUT + n;
  float f[8];
#pragma unroll
  for (int i = 0; i < 8; ++i) f[i] = wp[(size_t)i * DOUT];
  u32 lo = (u32)__builtin_amdgcn_cvt_pk_fp8_f32(f[0], f[1], 0, false);
  lo = (u32)__builtin_amdgcn_cvt_pk_fp8_f32(f[2], f[3], (int)lo, true);
  u32 hi = (u32)__builtin_amdgcn_cvt_pk_fp8_f32(f[4], f[5], 0, false);
  hi = (u32)__builtin_amdgcn_cvt_pk_fp8_f32(f[6], f[7], (int)hi, true);
  int ntile = n >> 7, c = (n >> 4) & 7, ks = k0 >> 6;
  int l = (n & 15) + 16 * ((k0 & 63) >> 4);
  u8* img = pw2f8 + (size_t)((e * 8 + ntile) * 32 + ks) * 8192 + c * 1024 + l * 16 + (k0 & 15);
  *(u32*)img = lo;
  *(u32*)(img + 4) = hi;
}

// ---------- GEMM1: plain fp16, ng-split x2, partial bids; optional fp8 h store ----------
template <bool SH>
__global__ __launch_bounds__(256, 4) void gemm1_bids_kernel(
    const u16* __restrict__ px, const u16* __restrict__ pw1,
    const float* __restrict__ b1, const float* __restrict__ Wb,
    float* __restrict__ bidp, u8* __restrict__ hfull)
{
  __shared__ u16 ldsA[8192];
  __shared__ u16 ldsB[8192];
  __shared__ float bidred[2][128];
  const int mtile = blockIdx.x, e = blockIdx.y, ng = blockIdx.z;
  const int tid = threadIdx.x, w = tid >> 6, lane = tid & 63;
  const int wm = w >> 1, wn = w & 1;

  const char* Abase = (const char*)px + (size_t)(mtile * 16) * 32768;
  const char* BbaseE = (const char*)pw1 + (size_t)(e * 16) * 16 * 32768;

  float bp[4][4];
#pragma unroll
  for (int mi = 0; mi < 4; ++mi)
#pragma unroll
    for (int r = 0; r < 4; ++r) bp[mi][r] = 0.f;

  for (int nto = 0; nto < 8; ++nto) {
    int nt = ng * 8 + nto;
    f32x4 acc[4][4];
#pragma unroll
    for (int i = 0; i < 4; ++i)
#pragma unroll
      for (int j = 0; j < 4; ++j) acc[i][j] = (f32x4)0.f;
    const char* Bnt = BbaseE + (size_t)nt * 16 * 32768;

    for (int ks = 0; ks < 16; ++ks) {
      __syncthreads();
      const char* Ak = Abase + (size_t)ks * 32768;
      const char* Bk = Bnt + (size_t)ks * 32768;
#pragma unroll
      for (int i = 0; i < 4; ++i) {
        int c = w * 4 + i;
        glds16(Ak + c * 1024 + lane * 16, (char*)ldsA + c * 1024);
        glds16(Bk + c * 1024 + lane * 16, (char*)ldsB + c * 1024);
      }
      __syncthreads();
#pragma unroll
      for (int ksub = 0; ksub < 2; ++ksub) {
        half8 ah[4], bh[4];
#pragma unroll
        for (int mi = 0; mi < 4; ++mi)
          ah[mi] = *(const half8*)(const void*)(ldsA + (size_t)(((wm * 4 + mi) * 2 + ksub) * 64 + lane) * 8);
#pragma unroll
        for (int ni = 0; ni < 4; ++ni)
          bh[ni] = *(const half8*)(const void*)(ldsB + (size_t)(((wn * 4 + ni) * 2 + ksub) * 64 + lane) * 8);
#pragma unroll
        for (int mi = 0; mi < 4; ++mi)
#pragma unroll
          for (int ni = 0; ni < 4; ++ni)
            acc[mi][ni] = __builtin_amdgcn_mfma_f32_16x16x32_f16(ah[mi], bh[ni], acc[mi][ni], 0, 0, 0);
      }
    }
    float b1v[4], wbv[4];
#pragma unroll
    for (int ni = 0; ni < 4; ++ni) {
      int n = nt * 128 + wn * 64 + ni * 16 + (lane & 15);
      b1v[ni] = b1[e * DH + n];
      wbv[ni] = Wb[e * DH + n];
    }
#pragma unroll
    for (int mi = 0; mi < 4; ++mi)
#pragma unroll
      for (int r = 0; r < 4; ++r)
#pragma unroll
        for (int ni = 0; ni < 4; ++ni) {
          float v = fmaxf(acc[mi][ni][r] + b1v[ni], 0.f);
          bp[mi][r] += v * wbv[ni];
        }
    if (SH) {
#pragma unroll
      for (int mi = 0; mi < 4; ++mi)
#pragma unroll
        for (int r = 0; r < 4; ++r) {
          int row = mtile * 128 + wm * 64 + mi * 16 + ((lane >> 4) << 2) + r;
          u8* hrow = hfull + ((size_t)e * NB + row) * DH;
#pragma unroll
          for (int ni = 0; ni < 4; ++ni) {
            float v = fmaxf(acc[mi][ni][r] + b1v[ni], 0.f);
            hrow[nt * 128 + wn * 64 + ni * 16 + (lane & 15)] = f2e4m3(v);
          }
        }
    }
  }
#pragma unroll
  for (int mi = 0; mi < 4; ++mi)
#pragma unroll
    for (int r = 0; r < 4; ++r) {
      float s = bp[mi][r];
      s += __shfl_xor(s, 1);
      s += __shfl_xor(s, 2);
      s += __shfl_xor(s, 4);
      s += __shfl_xor(s, 8);
      if ((lane & 15) == 0)
        bidred[wn][wm * 64 + mi * 16 + ((lane >> 4) << 2) + r] = s;
    }
  __syncthreads();
  if (tid < 128)
    bidp[(size_t)(e * 2 + ng) * NB + mtile * 128 + tid] = bidred[0][tid] + bidred[1][tid];
}

// ---------- top-4 + tier-1 flagging with ambiguous-expert mask + per-expert lists ----------
__global__ void topk_kernel(const float* __restrict__ bidp, const float* __restrict__ bb,
                            float* __restrict__ bids, float* __restrict__ outIdx,
                            int* __restrict__ rcnt1, u32* __restrict__ rlist1,
                            int* __restrict__ cnt1e, int* __restrict__ rle)
{
  int b = blockIdx.x * 256 + threadIdx.x;
  float v[16];
#pragma unroll
  for (int e = 0; e < 16; ++e) {
    float s = bidp[(size_t)(e * 2) * NB + b] + bidp[(size_t)(e * 2 + 1) * NB + b] + bb[e];
    v[e] = s;
    bids[(size_t)e * NB + b] = s;
  }
  int ord[16]; u32 used = 0;
  for (int j = 0; j < 16; ++j) {
    int best = 0; float bv = -3.4e38f;
    for (int t = 0; t < 16; ++t)
      if (!((used >> t) & 1) && v[t] > bv) { bv = v[t]; best = t; }
    ord[j] = best; used |= 1u << best;
  }
  for (int k = 0; k < 4; ++k) outIdx[b * 4 + k] = (float)ord[k];
  bool flag = false;
  for (int j = 0; j < 4; ++j)
    if (v[ord[j]] - v[ord[j + 1]] < THR_GAP1) flag = true;
  if (flag) {
    float vmin = v[ord[3]] - 2.f * THR_GAP1;
    u32 mask = 0;
    for (int e = 0; e < 16; ++e)
      if (v[e] >= vmin) mask |= 1u << e;
    int slot = atomicAdd(rcnt1, 1);
    rlist1[slot] = (u32)b | (mask << 16);
    for (int e = 0; e < 16; ++e)
      if ((mask >> e) & 1) {
        int p = atomicAdd(&cnt1e[e], 1);
        rle[e * NB + p] = b;
      }
  }
}

// ---------- tier-1 repair: grid (nt=16, e=16); per-expert ambiguous lists; row-indexed partials ----------
__global__ __launch_bounds__(256, 2) void repair1_kernel(
    const u16* __restrict__ px, const u16* __restrict__ pw1,
    const float* __restrict__ b1, const float* __restrict__ Wb,
    const int* __restrict__ cnt1e, const int* __restrict__ rle,
    float* __restrict__ rbp)
{
  __shared__ u16 ldsA[16384];
  __shared__ u16 ldsB[16384];
  __shared__ float bidred[2][128];
  const int nt = blockIdx.x, e = blockIdx.y;
  const int cnt = cnt1e[e];
  if (cnt == 0) return;
  const int nm = (cnt + 127) >> 7;
  const int tid = threadIdx.x, w = tid >> 6, lane = tid & 63;
  const int wm = w >> 1, wn = w & 1;
  const char* Bnt = (const char*)pw1 + (size_t)((e * 16 + nt) * 16) * 32768;
  const int* myList = rle + e * NB;

  float b1v[4], wbv[4];
#pragma unroll
  for (int ni = 0; ni < 4; ++ni) {
    int n = nt * 128 + wn * 64 + ni * 16 + (lane & 15);
    b1v[ni] = b1[e * DH + n];
    wbv[ni] = Wb[e * DH + n];
  }

  for (int m = 0; m < nm; ++m) {
    int rowb[4];
#pragma unroll
    for (int t = 0; t < 4; ++t) {
      int ri = m * 128 + ((w & 1) * 4 + t) * 16 + (lane & 15);
      rowb[t] = myList[(ri < cnt) ? ri : (cnt - 1)];
    }
    f32x4 acc[4][4];
#pragma unroll
    for (int i = 0; i < 4; ++i)
#pragma unroll
      for (int j = 0; j < 4; ++j) acc[i][j] = (f32x4)0.f;

    for (int ks = 0; ks < 16; ++ks) {
      __syncthreads();
#pragma unroll
      for (int i = 0; i < 8; ++i) {
        int c = w * 8 + i;
        int b = rowb[i >> 1];
        const char* srcA = (const char*)px
            + (size_t)((b >> 7) * 16 + ks) * 32768
            + (c >> 4) * 16384
            + (((b & 127) >> 4) * 2 + (i & 1)) * 1024
            + ((b & 15) + ((lane >> 4) << 4)) * 16;
        glds16(srcA, (char*)ldsA + c * 1024);
        glds16(Bnt + (size_t)ks * 32768 + c * 1024 + lane * 16, (char*)ldsB + c * 1024);
      }
      __syncthreads();
#pragma unroll
      for (int ksub = 0; ksub < 2; ++ksub) {
        half8 ah[4], bh[4], t[4];
#pragma unroll
        for (int mi = 0; mi < 4; ++mi)
          ah[mi] = *(const half8*)(const void*)(ldsA + (size_t)(((wm * 4 + mi) * 2 + ksub) * 64 + lane) * 8);
#pragma unroll
        for (int ni = 0; ni < 4; ++ni)
          bh[ni] = *(const half8*)(const void*)(ldsB + (size_t)(((wn * 4 + ni) * 2 + ksub) * 64 + lane) * 8);
#pragma unroll
        for (int mi = 0; mi < 4; ++mi)
#pragma unroll
          for (int ni = 0; ni < 4; ++ni)
            acc[mi][ni] = __builtin_amdgcn_mfma_f32_16x16x32_f16(ah[mi], bh[ni], acc[mi][ni], 0, 0, 0);
#pragma unroll
        for (int ni = 0; ni < 4; ++ni)
          t[ni] = *(const half8*)(const void*)(ldsB + (size_t)((16 + (wn * 4 + ni) * 2 + ksub) * 64 + lane) * 8);
#pragma unroll
        for (int mi = 0; mi < 4; ++mi)
#pragma unroll
          for (int ni = 0; ni < 4; ++ni)
            acc[mi][ni] = __builtin_amdgcn_mfma_f32_16x16x32_f16(ah[mi], t[ni], acc[mi][ni], 0, 0, 0);
#pragma unroll
        for (int mi = 0; mi < 4; ++mi)
          ah[mi] = *(const half8*)(const void*)(ldsA + (size_t)((16 + (wm * 4 + mi) * 2 + ksub) * 64 + lane) * 8);
#pragma unroll
        for (int mi = 0; mi < 4; ++mi)
#pragma unroll
          for (int ni = 0; ni < 4; ++ni)
            acc[mi][ni] = __builtin_amdgcn_mfma_f32_16x16x32_f16(ah[mi], bh[ni], acc[mi][ni], 0, 0, 0);
      }
    }
    float bp[4][4];
#pragma unroll
    for (int mi = 0; mi < 4; ++mi)
#pragma unroll
      for (int r = 0; r < 4; ++r) {
        bp[mi][r] = 0.f;
#pragma unroll
        for (int ni = 0; ni < 4; ++ni) {
          float v = fmaxf(acc[mi][ni][r] + b1v[ni], 0.f);
          bp[mi][r] += v * wbv[ni];
        }
      }
#pragma unroll
    for (int mi = 0; mi < 4; ++mi)
#pragma unroll
      for (int r = 0; r < 4; ++r) {
        float s = bp[mi][r];
        s += __shfl_xor(s, 1);
        s += __shfl_xor(s, 2);
        s += __shfl_xor(s, 4);
        s += __shfl_xor(s, 8);
        if ((lane & 15) == 0)
          bidred[wn][wm * 64 + mi * 16 + ((lane >> 4) << 2) + r] = s;
      }
    __syncthreads();
    if (tid < 128) {
      int ri = m * 128 + tid;
      if (ri < cnt) {
        int row = myList[ri];
        rbp[(size_t)(e * 16 + nt) * 4096 + row] = bidred[0][tid] + bidred[1][tid];
      }
    }
  }
}

// ---------- tier-1 finalize ----------
__global__ void repair1_final_kernel(const float* __restrict__ bb,
                                     const int* __restrict__ rcnt1,
                                     const u32* __restrict__ rlist1,
                                     const float* __restrict__ rbp,
                                     float* __restrict__ bids,
                                     float* __restrict__ outIdx,
                                     int* __restrict__ rcnt2, u32* __restrict__ rlist2)
{
  int idx = blockIdx.x * 64 + threadIdx.x;
  int cnt = *rcnt1;
  if (idx >= cnt) return;
  u32 ent1 = rlist1[idx];
  int b = ent1 & 0xFFFF;
  u32 mask1 = ent1 >> 16;
  float v[16];
#pragma unroll
  for (int e = 0; e < 16; ++e) {
    if ((mask1 >> e) & 1) {
      float s = bb[e];
      for (int nt = 0; nt < 16; ++nt) s += rbp[(size_t)(e * 16 + nt) * 4096 + b];
      v[e] = s;
      bids[(size_t)e * NB + b] = s;
    } else {
      v[e] = bids[(size_t)e * NB + b];
    }
  }
  int ord[16]; u32 used = 0;
  for (int j = 0; j < 16; ++j) {
    int best = 0; float bv = -3.4e38f;
    for (int t = 0; t < 16; ++t)
      if (!((used >> t) & 1) && v[t] > bv) { bv = v[t]; best = t; }
    ord[j] = best; used |= 1u << best;
  }
  for (int k = 0; k < 4; ++k) outIdx[b * 4 + k] = (float)ord[k];
  u32 mask = 0;
  for (int j = 0; j < 4; ++j)
    if (v[ord[j]] - v[ord[j + 1]] < THR_GAP2) { mask |= 1u << ord[j]; mask |= 1u << ord[j + 1]; }
  if (mask) {
    int jj = 4;
    while (jj < 15 && ((mask >> ord[jj]) & 1) && v[ord[jj]] - v[ord[jj + 1]] < THR_GAP2) {
      mask |= 1u << ord[jj + 1]; ++jj;
    }
    int slot = atomicAdd(rcnt2, 1);
    rlist2[slot] = (u32)b | (mask << 16);
  }
}

// ---------- tier-2 fp64 ----------
__global__ __launch_bounds__(256) void repair_partial_kernel(
    const float* __restrict__ x, const float* __restrict__ W1,
    const float* __restrict__ b1, const float* __restrict__ Wb,
    const int* __restrict__ rcnt2, const u32* __restrict__ rlist2,
    double* __restrict__ rpart)
{
  __shared__ float xrow[DIN];
  __shared__ double red[256];
  const int tid = threadIdx.x;
  int cnt = *rcnt2;
  int nit = cnt << 7;
  for (int item = blockIdx.x; item < nit; item += gridDim.x) {
    int it = item >> 7, e = (item >> 3) & 15, jc = item & 7;
    u32 ent = rlist2[it];
    if (!((ent >> (16 + e)) & 1)) continue;
    int b = ent & 0xFFFF;
    for (int i = tid; i < DIN; i += 256) xrow[i] = x[(size_t)b * DIN + i];
    __syncthreads();
    int j = jc * 256 + tid;
    const float* wcol = W1 + (size_t)e * DIN * DH + j;
    double z0 = 0, z1 = 0, z2 = 0, z3 = 0;
    for (int k = 0; k < DIN; k += 4) {
      z0 += (double)xrow[k]     * (double)wcol[(size_t)k * DH];
      z1 += (double)xrow[k + 1] * (double)wcol[(size_t)(k + 1) * DH];
      z2 += (double)xrow[k + 2] * (double)wcol[(size_t)(k + 2) * DH];
      z3 += (double)xrow[k + 3] * (double)wcol[(size_t)(k + 3) * DH];
    }
    double z = ((z0 + z1) + (z2 + z3)) + (double)b1[e * DH + j];
    red[tid] = (z > 0.0) ? z * (double)Wb[e * DH + j] : 0.0;
    __syncthreads();
    for (int off = 128; off > 0; off >>= 1) {
      if (tid < off) red[tid] += red[tid + off];
      __syncthreads();
    }
    if (tid == 0) rpart[item] = red[0];
    __syncthreads();
  }
}

__global__ void repair_final_kernel(const float* __restrict__ bids,
                                    const float* __restrict__ bb,
                                    const int* __restrict__ rcnt2,
                                    const u32* __restrict__ rlist2,
                                    const double* __restrict__ rpart,
                                    float* __restrict__ outIdx)
{
  __shared__ double v[16];
  int cnt = *rcnt2;
  int tid = threadIdx.x;
  for (int it = blockIdx.x; it < cnt; it += gridDim.x) {
    u32 ent = rlist2[it];
    int b = ent & 0xFFFF;
    if (tid < 16) {
      double val;
      if ((ent >> (16 + tid)) & 1) {
        double s = (double)bb[tid];
        for (int jc = 0; jc < 8; ++jc) s += rpart[(it << 7) + (tid << 3) + jc];
        val = s;
      } else {
        val = (double)bids[(size_t)tid * NB + b];
      }
      v[tid] = val;
    }
    __syncthreads();
    if (tid == 0) {
      u32 used = 0;
      for (int k = 0; k < 4; ++k) {
        int best = 0; double bv = -1e300;
        for (int t = 0; t < 16; ++t)
          if (!((used >> t) & 1) && v[t] > bv) { bv = v[t]; best = t; }
        outIdx[b * 4 + k] = (float)best; used |= 1u << best;
      }
    }
    __syncthreads();
  }
}

// ---------- per-expert row lists ----------
__global__ void build_lists_kernel(const float* __restrict__ outIdx,
                                   int* __restrict__ lists, int* __restrict__ counts)
{
  int e = blockIdx.x, tid = threadIdx.x;
  __shared__ int scan[256];
  __shared__ int base;
  if (tid == 0) base = 0;
  __syncthreads();
  for (int chunk = 0; chunk < NB; chunk += 256) {
    int b = chunk + tid;
    int slot = -1;
#pragma unroll
    for (int k = 0; k < 4; ++k)
      if ((int)outIdx[b * 4 + k] == e) slot = k;
    int flag = (slot >= 0) ? 1 : 0;
    scan[tid] = flag;
    __syncthreads();
    for (int off = 1; off < 256; off <<= 1) {
      int t = (tid >= off) ? scan[tid - off] : 0;
      __syncthreads();
      scan[tid] += t;
      __syncthreads();
    }
    if (flag) lists[e * NB + base + scan[tid] - 1] = (b << 2) | slot;
    int tot = scan[255];
    __syncthreads();
    if (tid == 0) base += tot;
    __syncthreads();
  }
  if (tid == 0) counts[e] = base;
}

// ============ SMALL path ============
__global__ void gather_xsel_kernel(const float* __restrict__ x,
                                   const int* __restrict__ lists,
                                   const int* __restrict__ counts,
                                   u16* __restrict__ xsel)
{
  int tid = threadIdx.x;
  int sub = tid >> 6, lane = tid & 63;
  int ri = blockIdx.x * 4 + sub;
  int e = 0, off = 0;
  for (int i = 0; i < 16; ++i) {
    int c = counts[i];
    if (ri < off + c) { e = i; break; }
    off += c;
  }
  int b = lists[e * NB + (ri - off)] >> 2;
  const float* src = x + (size_t)b * DIN + lane * 16;
  u16* dst = xsel + (size_t)ri * DIN + lane * 16;
  short8 o0, o1;
#pragma unroll
  for (int j = 0; j < 8; ++j) o0[j] = (short)f2h(src[j]);
#pragma unroll
  for (int j = 0; j < 8; ++j) o1[j] = (short)f2h(src[8 + j]);
  *(short8*)dst = o0;
  *(short8*)(dst + 8) = o1;
}

__global__ __launch_bounds__(256, 2) void hsel_kernel(
    const u16* __restrict__ xsel, const u16* __restrict__ pw1,
    const float* __restrict__ b1, const int* __restrict__ counts,
    u16* __restrict__ hselh)
{
  __shared__ u16 ldsA[8192];
  __shared__ u16 ldsB[8192];
  const int mtile = blockIdx.x, e = blockIdx.y, ng = blockIdx.z;
  const int cnt = counts[e];
  if (mtile * 128 >= cnt) return;
  int offs = 0;
  for (int i = 0; i < e; ++i) offs += counts[i];
  const int tid = threadIdx.x, w = tid >> 6, lane = tid & 63;
  const int wm = w >> 1, wn = w & 1;

  int r0 = mtile * 128 + (w * 2) * 16 + (lane & 15);
  int r1 = r0 + 16;
  r0 = (r0 < cnt) ? r0 : (cnt - 1);
  r1 = (r1 < cnt) ? r1 : (cnt - 1);
  const u16* arow0 = xsel + (size_t)(offs + r0) * DIN;
  const u16* arow1 = xsel + (size_t)(offs + r1) * DIN;
  const char* BbaseE = (const char*)pw1 + (size_t)(e * 16) * 16 * 32768;

  for (int nto = 0; nto < 4; ++nto) {
    int nt = ng * 4 + nto;
    f32x4 acc[4][4];
#pragma unroll
    for (int i = 0; i < 4; ++i)
#pragma unroll
      for (int j = 0; j < 4; ++j) acc[i][j] = (f32x4)0.f;
    const char* Bnt = BbaseE + (size_t)nt * 16 * 32768;

    for (int ks = 0; ks < 16; ++ks) {
      __syncthreads();
#pragma unroll
      for (int i = 0; i < 4; ++i) {
        int c = w * 4 + i, kt = c & 1;
        const u16* ga = ((i >> 1) ? arow1 : arow0) + ks * 64 + kt * 32 + ((lane >> 4) << 3);
        glds16(ga, (char*)ldsA + c * 1024);
        glds16(Bnt + (size_t)ks * 32768 + c * 1024 + lane * 16, (char*)ldsB + c * 1024);
      }
      __syncthreads();
#pragma unroll
      for (int ksub = 0; ksub < 2; ++ksub) {
        half8 ah[4], bh[4];
#pragma unroll
        for (int mi = 0; mi < 4; ++mi)
          ah[mi] = *(const half8*)(const void*)(ldsA + (size_t)(((wm * 4 + mi) * 2 + ksub) * 64 + lane) * 8);
#pragma unroll
        for (int ni = 0; ni < 4; ++ni)
          bh[ni] = *(const half8*)(const void*)(ldsB + (size_t)(((wn * 4 + ni) * 2 + ksub) * 64 + lane) * 8);
#pragma unroll
        for (int mi = 0; mi < 4; ++mi)
#pragma unroll
          for (int ni = 0; ni < 4; ++ni)
            acc[mi][ni] = __builtin_amdgcn_mfma_f32_16x16x32_f16(ah[mi], bh[ni], acc[mi][ni], 0, 0, 0);
      }
    }
    float b1v[4];
#pragma unroll
    for (int ni = 0; ni < 4; ++ni)
      b1v[ni] = b1[e * DH + nt * 128 + wn * 64 + ni * 16 + (lane & 15)];
#pragma unroll
    for (int mi = 0; mi < 4; ++mi)
#pragma unroll
      for (int r = 0; r < 4; ++r) {
        int ri = mtile * 128 + wm * 64 + mi * 16 + ((lane >> 4) << 2) + r;
        if (ri < cnt) {
          u16* hrow = hselh + (size_t)(offs + ri) * DH;
#pragma unroll
          for (int ni = 0; ni < 4; ++ni) {
            float v = fmaxf(acc[mi][ni][r] + b1v[ni], 0.f);
            hrow[nt * 128 + wn * 64 + ni * 16 + (lane & 15)] = f2h(v);
          }
        }
      }
  }
}

__global__ __launch_bounds__(256, 2) void gemm2_kernel(
    const u16* __restrict__ hselh, const u16* __restrict__ pw2,
    const float* __restrict__ b2, const int* __restrict__ lists,
    const int* __restrict__ counts, u16* __restrict__ contrib)
{
  __shared__ u16 ldsA[8192], ldsB[8192];
  const int mtile = blockIdx.x, ntile = blockIdx.y, e = blockIdx.z;
  const int cnt = counts[e];
  if (mtile * 128 >= cnt) return;
  int offs = 0;
  for (int i = 0; i < e; ++i) offs += counts[i];
  const int tid = threadIdx.x, w = tid >> 6, lane = tid & 63;
  const int wm = w >> 1, wn = w & 1;

  int rowg[2];
#pragma unroll
  for (int t = 0; t < 2; ++t) {
    int ri = mtile * 128 + (w * 2 + t) * 16 + (lane & 15);
    rowg[t] = offs + ((ri < cnt) ? ri : (cnt - 1));
  }
  const char* Bbase = (const char*)pw2 + (size_t)((e * 8 + ntile) * 32) * 16384;

  f32x4 acc[4][4];
#pragma unroll
  for (int i = 0; i < 4; ++i)
#pragma unroll
    for (int j = 0; j < 4; ++j) acc[i][j] = (f32x4)0.f;

  for (int ks = 0; ks < 32; ++ks) {
    __syncthreads();
#pragma unroll
    for (int i = 0; i < 4; ++i) {
      int c = w * 4 + i, kt = c & 1;
      const u16* ga = hselh + (size_t)rowg[i >> 1] * DH + ks * 64 + kt * 32 + ((lane >> 4) << 3);
      glds16(ga, (char*)ldsA + c * 1024);
      glds16(Bbase + (size_t)ks * 16384 + c * 1024 + lane * 16, (char*)ldsB + c * 1024);
    }
    __syncthreads();
#pragma unroll
    for (int ksub = 0; ksub < 2; ++ksub) {
      half8 af[4], bf[4];
#pragma unroll
      for (int mi = 0; mi < 4; ++mi)
        af[mi] = *(const half8*)(const void*)(ldsA + (size_t)(((wm * 4 + mi) * 2 + ksub) * 64 + lane) * 8);
#pragma unroll
      for (int ni = 0; ni < 4; ++ni)
        bf[ni] = *(const half8*)(const void*)(ldsB + (size_t)(((wn * 4 + ni) * 2 + ksub) * 64 + lane) * 8);
#pragma unroll
      for (int mi = 0; mi < 4; ++mi)
#pragma unroll
        for (int ni = 0; ni < 4; ++ni)
          acc[mi][ni] = __builtin_amdgcn_mfma_f32_16x16x32_f16(af[mi], bf[ni], acc[mi][ni], 0, 0, 0);
    }
  }
  float b2v[4];
#pragma unroll
  for (int ni = 0; ni < 4; ++ni)
    b2v[ni] = b2[e * DOUT + ntile * 128 + wn * 64 + ni * 16 + (lane & 15)];
#pragma unroll
  for (int mi = 0; mi < 4; ++mi)
#pragma unroll
    for (int r = 0; r < 4; ++r) {
      int ri = mtile * 128 + wm * 64 + mi * 16 + ((lane >> 4) << 2) + r;
      if (ri < cnt) {
        int ent = lists[e * NB + ri];
        int b = ent >> 2, slot = ent & 3;
#pragma unroll
        for (int ni = 0; ni < 4; ++ni) {
          int o = ntile * 128 + wn * 64 + ni * 16 + (lane & 15);
          contrib[(size_t)(b * 4 + slot) * DOUT + o] = f2h(acc[mi][ni][r] + b2v[ni]);
        }
      }
    }
}

// ============ BIG path: gemm2 fp8 ============
__global__ __launch_bounds__(256, 2) void gemm2f8_kernel(
    const u8* __restrict__ hfull, const u8* __restrict__ pw2f8,
    const float* __restrict__ b2, const int* __restrict__ lists,
    const int* __restrict__ counts, u16* __restrict__ contrib)
{
  __shared__ u8 ldsA[8192], ldsB[8192];
  const int mtile = blockIdx.x, ntile = blockIdx.y, e = blockIdx.z;
  const int cnt = counts[e];
  if (mtile * 128 >= cnt) return;
  const int tid = threadIdx.x, w = tid >> 6, lane = tid & 63;
  const int wm = w >> 1, wn = w & 1;

  const u8* arow[2];
#pragma unroll
  for (int t = 0; t < 2; ++t) {
    int ri = mtile * 128 + (w * 2 + t) * 16 + (lane & 15);
    int b = lists[e * NB + ((ri < cnt) ? ri : (cnt - 1))] >> 2;
    arow[t] = hfull + ((size_t)e * NB + b) * DH;
  }
  const u8* Bbase = pw2f8 + (size_t)((e * 8 + ntile) * 32) * 8192;

  f32x4 acc[4][4];
#pragma unroll
  for (int i = 0; i < 4; ++i)
#pragma unroll
    for (int j = 0; j < 4; ++j) acc[i][j] = (f32x4)0.f;

  for (int ks = 0; ks < 32; ++ks) {
    __syncthreads();
#pragma unroll
    for (int i = 0; i < 2; ++i) {
      int c = w * 2 + i;
      glds16(arow[i] + ks * 64 + ((lane >> 4) << 4), ldsA + c * 1024);
      glds16(Bbase + (size_t)ks * 8192 + c * 1024 + lane * 16, ldsB + c * 1024);
    }
    __syncthreads();
    int fo = (lane & 15) * 16 + (((lane >> 4) >> 1)) * 256 + ((lane >> 4) & 1) * 8;
#pragma unroll
    for (int ksub = 0; ksub < 2; ++ksub) {
      long a8[4], b8[4];
#pragma unroll
      for (int mi = 0; mi < 4; ++mi)
        a8[mi] = *(const long*)(const void*)(ldsA + (wm * 4 + mi) * 1024 + ksub * 512 + fo);
#pragma unroll
      for (int ni = 0; ni < 4; ++ni)
        b8[ni] = *(const long*)(const void*)(ldsB + (wn * 4 + ni) * 1024 + ksub * 512 + fo);
#pragma unroll
      for (int mi = 0; mi < 4; ++mi)
#pragma unroll
        for (int ni = 0; ni < 4; ++ni)
          acc[mi][ni] = __builtin_amdgcn_mfma_f32_16x16x32_fp8_fp8(a8[mi], b8[ni], acc[mi][ni], 0, 0, 0);
    }
  }
  float b2v[4];
#pragma unroll
  for (int ni = 0; ni < 4; ++ni)
    b2v[ni] = b2[e * DOUT + ntile * 128 + wn * 64 + ni * 16 + (lane & 15)];
#pragma unroll
  for (int mi = 0; mi < 4; ++mi)
#pragma unroll
    for (int r = 0; r < 4; ++r) {
      int ri = mtile * 128 + wm * 64 + mi * 16 + ((lane >> 4) << 2) + r;
      if (ri < cnt) {
        int ent = lists[e * NB + ri];
        int b = ent >> 2, slot = ent & 3;
#pragma unroll
        for (int ni = 0; ni < 4; ++ni) {
          int o = ntile * 128 + wn * 64 + ni * 16 + (lane & 15);
          contrib[(size_t)(b * 4 + slot) * DOUT + o] = f2h(acc[mi][ni][r] + b2v[ni]);
        }
      }
    }
}

// ---------- final: mean over 4 winner slots ----------
__global__ void finalize_kernel(const u16* __restrict__ contrib, float* __restrict__ out)
{
  int gid = blockIdx.x * 256 + threadIdx.x;
  int b = gid >> 7, o8 = (gid & 127) << 3;
  float s[8] = {0, 0, 0, 0, 0, 0, 0, 0};
#pragma unroll
  for (int sl = 0; sl < 4; ++sl) {
    short8 v = *(const short8*)(contrib + (size_t)(b * 4 + sl) * DOUT + o8);
#pragma unroll
    for (int j = 0; j < 8; ++j) s[j] += h2f((u16)v[j]);
  }
  float* op = out + (size_t)b * DOUT + o8;
#pragma unroll
  for (int j = 0; j < 8; ++j) op[j] = s[j] * 0.25f;
}

extern "C" void kernel_launch(void* const* d_in, const int* in_sizes, int n_in,
                              void* d_out, int out_size, void* d_ws, size_t ws_size,
                              hipStream_t stream)
{
  (void)in_sizes; (void)n_in; (void)out_size;
  if (ws_size < WS_NEED_SM) return;
  const bool big = (ws_size >= WS_NEED_BIG);

  const float* x  = (const float*)d_in[0];
  const float* W1 = (const float*)d_in[1];
  const float* b1 = (const float*)d_in[2];
  const float* W2 = (const float*)d_in[3];
  const float* b2 = (const float*)d_in[4];
  const float* Wb = (const float*)d_in[5];
  const float* bb = (const float*)d_in[6];

  char* ws = (char*)d_ws;
  float* outMain = (float*)d_out;
  float* outIdx  = (float*)d_out + (size_t)NB * DOUT;

  if (big) {
    u16* px      = (u16*)(ws + PXB);
    u16* pw1     = (u16*)(ws + PW1B);
    u8*  hfull   = (u8*)(ws + HFULLB);
    u8*  pw2f8   = (u8*)(ws + PW2F8B);
    u16* contrib = (u16*)(ws + CONTRB);
    float* bidp  = (float*)(ws + RPARTB);                        // early (dead before rpart writes)
    int* cnt1e   = (int*)(ws + RPARTB + (size_t)512 * 1024);     // early
    float* bids  = (float*)(ws + BIDSB);
    int* lists   = (int*)(ws + LISTSB);
    int* rle     = (int*)(ws + LISTSB);                          // early (dead before build_lists)
    int* counts  = (int*)(ws + CNTB);
    int* rcnt1   = (int*)(ws + RCNTB);
    int* rcnt2   = (int*)(ws + RCNTB + 4);
    u32* rlist1  = (u32*)(ws + RLIST1B);
    u32* rlist2  = (u32*)(ws + RLIST2B);
    double* rpart = (double*)(ws + RPARTB);
    float* rbp   = (float*)(ws + RBPB);

    hipMemsetAsync(rcnt1, 0, 2 * sizeof(int), stream);
    hipMemsetAsync(cnt1e, 0, 16 * sizeof(int), stream);
    pack_x_kernel <<<2048, 256, 0, stream>>>(x, px);
    pack_w1_kernel<<<16384, 256, 0, stream>>>(W1, pw1);
    gemm1_bids_kernel<true><<<dim3(32, 16, 2), 256, 0, stream>>>(px, pw1, b1, Wb, bidp, hfull);
    topk_kernel<<<16, 256, 0, stream>>>(bidp, bb, bids, outIdx, rcnt1, rlist1, cnt1e, rle);
    repair1_kernel<<<dim3(16, 16), 256, 0, stream>>>(px, pw1, b1, Wb, cnt1e, rle, rbp);
    repair1_final_kernel<<<64, 64, 0, stream>>>(bb, rcnt1, rlist1, rbp, bids, outIdx, rcnt2, rlist2);
    repair_partial_kernel<<<2048, 256, 0, stream>>>(x, W1, b1, Wb, rcnt2, rlist2, rpart);  // overwrites bidp/cnt1e (dead)
    repair_final_kernel<<<64, 64, 0, stream>>>(bids, bb, rcnt2, rlist2, rpart, outIdx);
    build_lists_kernel<<<16, 256, 0, stream>>>(outIdx, lists, counts);   // overwrites rle (dead)
    pack_w2f8_kernel<<<16384, 256, 0, stream>>>(W2, pw2f8);              // overlays pw1 (dead)
    gemm2f8_kernel<<<dim3(32, 8, 16), 256, 0, stream>>>(hfull, pw2f8, b2, lists, counts, contrib);
    finalize_kernel<<<2048, 256, 0, stream>>>(contrib, outMain);
  } else {
    u16* px      = (u16*)(ws + PX_OFF);
    u16* xsel    = (u16*)(ws + XSEL_OFF);
    u16* contrib = (u16*)(ws + CONTRIB_OFF);
    float* bidp  = (float*)(ws + RPART_OFF);                     // early (dead before rpart writes)
    int* cnt1e   = (int*)(ws + RPART_OFF + (size_t)512 * 1024);  // early
    u16* pw1     = (u16*)(ws + PW1_OFF);
    u16* pw2     = (u16*)(ws + PW2_OFF);
    u16* hselh   = (u16*)(ws + HSEL_OFF);
    float* bids  = (float*)(ws + BIDS_OFF);
    int* lists   = (int*)(ws + LISTS_OFF);
    int* rle     = (int*)(ws + LISTS_OFF);                       // early
    int* counts  = (int*)(ws + CNT_OFF);
    int* rcnt1   = (int*)(ws + RCNT_OFF);
    int* rcnt2   = (int*)(ws + RCNT_OFF + 4);
    u32* rlist1  = (u32*)(ws + RLIST1_OFF);
    u32* rlist2  = (u32*)(ws + RLIST2_OFF);
    double* rpart = (double*)(ws + RPART_OFF);
    float* rbp   = (float*)(ws + RBP_OFF);

    hipMemsetAsync(rcnt1, 0, 2 * sizeof(int), stream);
    hipMemsetAsync(cnt1e, 0, 16 * sizeof(int), stream);
    pack_x_kernel <<<2048, 256, 0, stream>>>(x, px);
    pack_w1_kernel<<<16384, 256, 0, stream>>>(W1, pw1);
    gemm1_bids_kernel<false><<<dim3(32, 16, 2), 256, 0, stream>>>(px, pw1, b1, Wb, bidp, nullptr);
    topk_kernel<<<16, 256, 0, stream>>>(bidp, bb, bids, outIdx, rcnt1, rlist1, cnt1e, rle);
    repair1_kernel<<<dim3(16, 16), 256, 0, stream>>>(px, pw1, b1, Wb, cnt1e, rle, rbp);
    repair1_final_kernel<<<64, 64, 0, stream>>>(bb, rcnt1, rlist1, rbp, bids, outIdx, rcnt2, rlist2);
    repair_partial_kernel<<<2048, 256, 0, stream>>>(x, W1, b1, Wb, rcnt2, rlist2, rpart);
    repair_final_kernel<<<64, 64, 0, stream>>>(bids, bb, rcnt2, rlist2, rpart, outIdx);
    build_lists_kernel<<<16, 256, 0, stream>>>(outIdx, lists, counts);
    gather_xsel_kernel<<<4096, 256, 0, stream>>>(x, lists, counts, xsel);
    hsel_kernel<<<dim3(32, 16, 4), 256, 0, stream>>>(xsel, pw1, b1, counts, hselh);
    pack_w2_kernel<<<16384, 256, 0, stream>>>(W2, pw2);
    gemm2_kernel<<<dim3(32, 8, 16), 256, 0, stream>>>(hselh, pw2, b2, lists, counts, contrib);
    finalize_kernel<<<2048, 256, 0, stream>>>(contrib, outMain);
  }
}

// Round 13
// 914.864 us; speedup vs baseline: 1.9911x; 1.1037x over previous
//
#include <hip/hip_runtime.h>
#include <stdint.h>

typedef unsigned short u16;
typedef unsigned char u8;
typedef unsigned int u32;
typedef __attribute__((ext_vector_type(8))) short short8;
typedef __attribute__((ext_vector_type(8))) _Float16 half8;
typedef __attribute__((ext_vector_type(4))) float f32x4;

static constexpr int NE = 16, NB = 4096, DIN = 1024, DH = 2048, DOUT = 1024;
#define THR_GAP1 5e-3f
#define THR_GAP2 1e-4f

// ---- SMALL-path ws layout (~235 MiB) ----
static constexpr size_t PX_OFF      = 0;
static constexpr size_t XSEL_OFF    = 0;
static constexpr size_t CONTRIB_OFF = 0;
static constexpr size_t PW1_OFF     = (size_t)32 * 1024 * 1024;
static constexpr size_t PW2_OFF     = PW1_OFF;
static constexpr size_t HSEL_OFF    = PW1_OFF + (size_t)128 * 1024 * 1024;
static constexpr size_t BIDS_OFF    = HSEL_OFF + (size_t)16384 * 2048 * 2;
static constexpr size_t LISTS_OFF   = BIDS_OFF + (size_t)NE * NB * 4;   // rle early / lists late
static constexpr size_t CNT_OFF     = LISTS_OFF + (size_t)NE * NB * 4;
static constexpr size_t RCNT_OFF    = CNT_OFF + 64;
static constexpr size_t RLIST1_OFF  = RCNT_OFF + 64;
static constexpr size_t RLIST2_OFF  = RLIST1_OFF + (size_t)4096 * 4;
static constexpr size_t RPART_OFF   = RLIST2_OFF + (size_t)4096 * 4;    // bidp+cnt1e early / rpart late
static constexpr size_t RBP_OFF     = RPART_OFF + (size_t)4096 * 128 * 8;
static constexpr size_t WS_NEED_SM  = RBP_OFF + (size_t)16 * 16 * 4096 * 4;

// ---- BIG-path ws layout (~281 MiB) ----
static constexpr size_t PXB      = 0;                                    // 16 MiB
static constexpr size_t PW1B     = (size_t)16 * 1024 * 1024;             // 128 MiB (dead after repair1)
static constexpr size_t HFULLB   = (size_t)144 * 1024 * 1024;            // 128 MiB fp8 h
static constexpr size_t PW2F8B   = (size_t)16 * 1024 * 1024;             // 32 MiB (overlay pw1 after repair1)
static constexpr size_t CONTRB   = (size_t)48 * 1024 * 1024;             // 32 MiB (overlay pw1; late)
static constexpr size_t BIDSB    = (size_t)272 * 1024 * 1024;
static constexpr size_t LISTSB   = BIDSB + (size_t)NE * NB * 4;          // rle early / lists late
static constexpr size_t CNTB     = LISTSB + (size_t)NE * NB * 4;
static constexpr size_t RCNTB    = CNTB + 64;
static constexpr size_t RLIST1B  = RCNTB + 64;
static constexpr size_t RLIST2B  = RLIST1B + (size_t)4096 * 4;
static constexpr size_t RPARTB   = RLIST2B + (size_t)4096 * 4;           // bidp+cnt1e early / rpart late
static constexpr size_t RBPB     = RPARTB + (size_t)4096 * 128 * 8;
static constexpr size_t WS_NEED_BIG = RBPB + (size_t)16 * 16 * 4096 * 4;
// bidp (512 KB) + cnt1e (64 B) live at RPART*_OFF: written by gemm1/topk, read by
// topk/repair1, DEAD before repair_partial (the rpart region's first writer).

__device__ __forceinline__ u16 f2h(float f) {
  union { _Float16 h; u16 u; } c; c.h = (_Float16)f; return c.u;
}
__device__ __forceinline__ float h2f(u16 v) {
  union { _Float16 h; u16 u; } c; c.u = v; return (float)c.h;
}
__device__ __forceinline__ u8 f2e4m3(float f) {
  return (u8)(__builtin_amdgcn_cvt_pk_fp8_f32(f, f, 0, false) & 0xFF);
}
__device__ __forceinline__ void glds16(const void* gsrc, void* ldst) {
  __builtin_amdgcn_global_load_lds(
      (const __attribute__((address_space(1))) u32*)gsrc,
      (__attribute__((address_space(3))) u32*)ldst, 16, 0, 0);
}

// ---------- pack kernels ----------
__global__ void pack_x_kernel(const float* __restrict__ x, u16* __restrict__ px) {
  int gid = blockIdx.x * 256 + threadIdx.x;
  int kk = gid & 127, b = gid >> 7;
  int k0 = kk * 8;
  const float* xp = x + (size_t)b * DIN + k0;
  short8 hv, lv;
#pragma unroll
  for (int i = 0; i < 8; ++i) {
    float f = xp[i];
    u16 hb = f2h(f);
    hv[i] = (short)hb;
    lv[i] = (short)f2h(f - h2f(hb));
  }
  int mtile = b >> 7, m = b & 127;
  int kstep = k0 >> 6, kt = (k0 >> 5) & 1;
  int lane = (m & 15) + (((k0 >> 3) & 3) << 4);
  int sub = (m >> 4) * 2 + kt;
  u16* img = px + (size_t)(mtile * 16 + kstep) * 16384;
  *(short8*)(img + (size_t)((0 + sub) * 64 + lane) * 8) = hv;
  *(short8*)(img + (size_t)((16 + sub) * 64 + lane) * 8) = lv;
}

__global__ void pack_w1_kernel(const float* __restrict__ W1, u16* __restrict__ pw1) {
  int gid = blockIdx.x * 256 + threadIdx.x;
  int n = gid & 2047;
  int kc = (gid >> 11) & 127;
  int e = gid >> 18;
  int k0 = kc * 8;
  const float* wp = W1 + ((size_t)e * DIN + k0) * DH + n;
  short8 hv, lv;
#pragma unroll
  for (int i = 0; i < 8; ++i) {
    float f = wp[(size_t)i * DH];
    u16 hb = f2h(f);
    hv[i] = (short)hb;
    lv[i] = (short)f2h(f - h2f(hb));
  }
  int ntile = n >> 7, nt4 = (n >> 4) & 7, kt = (k0 >> 5) & 1;
  int lane = (n & 15) + (((k0 >> 3) & 3) << 4);
  int sub = nt4 * 2 + kt;
  u16* img = pw1 + (size_t)((e * 16 + ntile) * 16 + (k0 >> 6)) * 16384;
  *(short8*)(img + (size_t)((0 + sub) * 64 + lane) * 8) = hv;
  *(short8*)(img + (size_t)((16 + sub) * 64 + lane) * 8) = lv;
}

// fp16 W2 image (small path)
__global__ void pack_w2_kernel(const float* __restrict__ W2, u16* __restrict__ pw2) {
  int gid = blockIdx.x * 256 + threadIdx.x;
  int n = gid & 1023;
  int kc = (gid >> 10) & 255;
  int e = gid >> 18;
  int k0 = kc * 8;
  const float* wp = W2 + ((size_t)e * DH + k0) * DOUT + n;
  short8 hv;
#pragma unroll
  for (int i = 0; i < 8; ++i) hv[i] = (short)f2h(wp[(size_t)i * DOUT]);
  int ntile = n >> 7, nt4 = (n >> 4) & 7, kt = (k0 >> 5) & 1;
  int lane = (n & 15) + (((k0 >> 3) & 3) << 4);
  int sub = nt4 * 2 + kt;
  u16* img = pw2 + (size_t)((e * 8 + ntile) * 32 + (k0 >> 6)) * 8192;
  *(short8*)(img + (size_t)(sub * 64 + lane) * 8) = hv;
}

// fp8 W2 image (big path)
__global__ void pack_w2f8_kernel(const float* __restrict__ W2, u8* __restrict__ pw2f8) {
  int gid = blockIdx.x * 256 + threadIdx.x;
  int n = gid & 1023;
  int kc = (gid >> 10) & 255;
  int e = gid >> 18;
  int k0 = kc * 8;
  const float* wp = W2 + ((size_t)e * DH + k0) * DOUT + n;
  float f[8];
#pragma unroll
  for (int i = 0; i < 8; ++i) f[i] = wp[(size_t)i * DOUT];
  u32 lo = (u32)__builtin_amdgcn_cvt_pk_fp8_f32(f[0], f[1], 0, false);
  lo = (u32)__builtin_amdgcn_cvt_pk_fp8_f32(f[2], f[3], (int)lo, true);
  u32 hi = (u32)__builtin_amdgcn_cvt_pk_fp8_f32(f[4], f[5], 0, false);
  hi = (u32)__builtin_amdgcn_cvt_pk_fp8_f32(f[6], f[7], (int)hi, true);
  int ntile = n >> 7, c = (n >> 4) & 7, ks = k0 >> 6;
  int l = (n & 15) + 16 * ((k0 & 63) >> 4);
  u8* img = pw2f8 + (size_t)((e * 8 + ntile) * 32 + ks) * 8192 + c * 1024 + l * 16 + (k0 & 15);
  *(u32*)img = lo;
  *(u32*)(img + 4) = hi;
}

// ---------- GEMM1: plain fp16, ng-split x2, XCD-chunked swizzle, partial bids ----------
// 1D grid 1024 = 8 XCD chunks x 128; swz clusters same-(e,ng) mtile-blocks per XCD
template <bool SH>
__global__ __launch_bounds__(256, 4) void gemm1_bids_kernel(
    const u16* __restrict__ px, const u16* __restrict__ pw1,
    const float* __restrict__ b1, const float* __restrict__ Wb,
    float* __restrict__ bidp, u8* __restrict__ hfull)
{
  __shared__ u16 ldsA[8192];
  __shared__ u16 ldsB[8192];
  __shared__ float bidred[2][128];
  const int id = blockIdx.x;
  const int swz = (id & 7) * 128 + (id >> 3);          // bijective (1024 % 8 == 0)
  const int mtile = swz & 31, e = (swz >> 5) & 15, ng = swz >> 9;
  const int tid = threadIdx.x, w = tid >> 6, lane = tid & 63;
  const int wm = w >> 1, wn = w & 1;

  const char* Abase = (const char*)px + (size_t)(mtile * 16) * 32768;
  const char* BbaseE = (const char*)pw1 + (size_t)(e * 16) * 16 * 32768;

  float bp[4][4];
#pragma unroll
  for (int mi = 0; mi < 4; ++mi)
#pragma unroll
    for (int r = 0; r < 4; ++r) bp[mi][r] = 0.f;

  for (int nto = 0; nto < 8; ++nto) {
    int nt = ng * 8 + nto;
    f32x4 acc[4][4];
#pragma unroll
    for (int i = 0; i < 4; ++i)
#pragma unroll
      for (int j = 0; j < 4; ++j) acc[i][j] = (f32x4)0.f;
    const char* Bnt = BbaseE + (size_t)nt * 16 * 32768;

    for (int ks = 0; ks < 16; ++ks) {
      __syncthreads();
      const char* Ak = Abase + (size_t)ks * 32768;
      const char* Bk = Bnt + (size_t)ks * 32768;
#pragma unroll
      for (int i = 0; i < 4; ++i) {
        int c = w * 4 + i;
        glds16(Ak + c * 1024 + lane * 16, (char*)ldsA + c * 1024);
        glds16(Bk + c * 1024 + lane * 16, (char*)ldsB + c * 1024);
      }
      __syncthreads();
#pragma unroll
      for (int ksub = 0; ksub < 2; ++ksub) {
        half8 ah[4], bh[4];
#pragma unroll
        for (int mi = 0; mi < 4; ++mi)
          ah[mi] = *(const half8*)(const void*)(ldsA + (size_t)(((wm * 4 + mi) * 2 + ksub) * 64 + lane) * 8);
#pragma unroll
        for (int ni = 0; ni < 4; ++ni)
          bh[ni] = *(const half8*)(const void*)(ldsB + (size_t)(((wn * 4 + ni) * 2 + ksub) * 64 + lane) * 8);
#pragma unroll
        for (int mi = 0; mi < 4; ++mi)
#pragma unroll
          for (int ni = 0; ni < 4; ++ni)
            acc[mi][ni] = __builtin_amdgcn_mfma_f32_16x16x32_f16(ah[mi], bh[ni], acc[mi][ni], 0, 0, 0);
      }
    }
    float b1v[4], wbv[4];
#pragma unroll
    for (int ni = 0; ni < 4; ++ni) {
      int n = nt * 128 + wn * 64 + ni * 16 + (lane & 15);
      b1v[ni] = b1[e * DH + n];
      wbv[ni] = Wb[e * DH + n];
    }
#pragma unroll
    for (int mi = 0; mi < 4; ++mi)
#pragma unroll
      for (int r = 0; r < 4; ++r)
#pragma unroll
        for (int ni = 0; ni < 4; ++ni) {
          float v = fmaxf(acc[mi][ni][r] + b1v[ni], 0.f);
          bp[mi][r] += v * wbv[ni];
        }
    if (SH) {
#pragma unroll
      for (int mi = 0; mi < 4; ++mi)
#pragma unroll
        for (int r = 0; r < 4; ++r) {
          int row = mtile * 128 + wm * 64 + mi * 16 + ((lane >> 4) << 2) + r;
          u8* hrow = hfull + ((size_t)e * NB + row) * DH;
#pragma unroll
          for (int ni = 0; ni < 4; ++ni) {
            float v = fmaxf(acc[mi][ni][r] + b1v[ni], 0.f);
            hrow[nt * 128 + wn * 64 + ni * 16 + (lane & 15)] = f2e4m3(v);
          }
        }
    }
  }
#pragma unroll
  for (int mi = 0; mi < 4; ++mi)
#pragma unroll
    for (int r = 0; r < 4; ++r) {
      float s = bp[mi][r];
      s += __shfl_xor(s, 1);
      s += __shfl_xor(s, 2);
      s += __shfl_xor(s, 4);
      s += __shfl_xor(s, 8);
      if ((lane & 15) == 0)
        bidred[wn][wm * 64 + mi * 16 + ((lane >> 4) << 2) + r] = s;
    }
  __syncthreads();
  if (tid < 128)
    bidp[(size_t)(e * 2 + ng) * NB + mtile * 128 + tid] = bidred[0][tid] + bidred[1][tid];
}

// ---------- top-4 + tier-1 flagging with ambiguous-expert mask + per-expert lists ----------
__global__ void topk_kernel(const float* __restrict__ bidp, const float* __restrict__ bb,
                            float* __restrict__ bids, float* __restrict__ outIdx,
                            int* __restrict__ rcnt1, u32* __restrict__ rlist1,
                            int* __restrict__ cnt1e, int* __restrict__ rle)
{
  int b = blockIdx.x * 256 + threadIdx.x;
  float v[16];
#pragma unroll
  for (int e = 0; e < 16; ++e) {
    float s = bidp[(size_t)(e * 2) * NB + b] + bidp[(size_t)(e * 2 + 1) * NB + b] + bb[e];
    v[e] = s;
    bids[(size_t)e * NB + b] = s;
  }
  int ord[16]; u32 used = 0;
  for (int j = 0; j < 16; ++j) {
    int best = 0; float bv = -3.4e38f;
    for (int t = 0; t < 16; ++t)
      if (!((used >> t) & 1) && v[t] > bv) { bv = v[t]; best = t; }
    ord[j] = best; used |= 1u << best;
  }
  for (int k = 0; k < 4; ++k) outIdx[b * 4 + k] = (float)ord[k];
  bool flag = false;
  for (int j = 0; j < 4; ++j)
    if (v[ord[j]] - v[ord[j + 1]] < THR_GAP1) flag = true;
  if (flag) {
    float vmin = v[ord[3]] - 2.f * THR_GAP1;
    u32 mask = 0;
    for (int e = 0; e < 16; ++e)
      if (v[e] >= vmin) mask |= 1u << e;
    int slot = atomicAdd(rcnt1, 1);
    rlist1[slot] = (u32)b | (mask << 16);
    for (int e = 0; e < 16; ++e)
      if ((mask >> e) & 1) {
        int p = atomicAdd(&cnt1e[e], 1);
        rle[e * NB + p] = b;
      }
  }
}

// ---------- tier-1 repair: grid (nt=16, e=16); per-expert ambiguous lists; row-indexed partials ----------
__global__ __launch_bounds__(256, 2) void repair1_kernel(
    const u16* __restrict__ px, const u16* __restrict__ pw1,
    const float* __restrict__ b1, const float* __restrict__ Wb,
    const int* __restrict__ cnt1e, const int* __restrict__ rle,
    float* __restrict__ rbp)
{
  __shared__ u16 ldsA[16384];
  __shared__ u16 ldsB[16384];
  __shared__ float bidred[2][128];
  const int nt = blockIdx.x, e = blockIdx.y;
  const int cnt = cnt1e[e];
  if (cnt == 0) return;
  const int nm = (cnt + 127) >> 7;
  const int tid = threadIdx.x, w = tid >> 6, lane = tid & 63;
  const int wm = w >> 1, wn = w & 1;
  const char* Bnt = (const char*)pw1 + (size_t)((e * 16 + nt) * 16) * 32768;
  const int* myList = rle + e * NB;

  float b1v[4], wbv[4];
#pragma unroll
  for (int ni = 0; ni < 4; ++ni) {
    int n = nt * 128 + wn * 64 + ni * 16 + (lane & 15);
    b1v[ni] = b1[e * DH + n];
    wbv[ni] = Wb[e * DH + n];
  }

  for (int m = 0; m < nm; ++m) {
    int rowb[4];
#pragma unroll
    for (int t = 0; t < 4; ++t) {
      int ri = m * 128 + ((w & 1) * 4 + t) * 16 + (lane & 15);
      rowb[t] = myList[(ri < cnt) ? ri : (cnt - 1)];
    }
    f32x4 acc[4][4];
#pragma unroll
    for (int i = 0; i < 4; ++i)
#pragma unroll
      for (int j = 0; j < 4; ++j) acc[i][j] = (f32x4)0.f;

    for (int ks = 0; ks < 16; ++ks) {
      __syncthreads();
#pragma unroll
      for (int i = 0; i < 8; ++i) {
        int c = w * 8 + i;
        int b = rowb[i >> 1];
        const char* srcA = (const char*)px
            + (size_t)((b >> 7) * 16 + ks) * 32768
            + (c >> 4) * 16384
            + (((b & 127) >> 4) * 2 + (i & 1)) * 1024
            + ((b & 15) + ((lane >> 4) << 4)) * 16;
        glds16(srcA, (char*)ldsA + c * 1024);
        glds16(Bnt + (size_t)ks * 32768 + c * 1024 + lane * 16, (char*)ldsB + c * 1024);
      }
      __syncthreads();
#pragma unroll
      for (int ksub = 0; ksub < 2; ++ksub) {
        half8 ah[4], bh[4], t[4];
#pragma unroll
        for (int mi = 0; mi < 4; ++mi)
          ah[mi] = *(const half8*)(const void*)(ldsA + (size_t)(((wm * 4 + mi) * 2 + ksub) * 64 + lane) * 8);
#pragma unroll
        for (int ni = 0; ni < 4; ++ni)
          bh[ni] = *(const half8*)(const void*)(ldsB + (size_t)(((wn * 4 + ni) * 2 + ksub) * 64 + lane) * 8);
#pragma unroll
        for (int mi = 0; mi < 4; ++mi)
#pragma unroll
          for (int ni = 0; ni < 4; ++ni)
            acc[mi][ni] = __builtin_amdgcn_mfma_f32_16x16x32_f16(ah[mi], bh[ni], acc[mi][ni], 0, 0, 0);
#pragma unroll
        for (int ni = 0; ni < 4; ++ni)
          t[ni] = *(const half8*)(const void*)(ldsB + (size_t)((16 + (wn * 4 + ni) * 2 + ksub) * 64 + lane) * 8);
#pragma unroll
        for (int mi = 0; mi < 4; ++mi)
#pragma unroll
          for (int ni = 0; ni < 4; ++ni)
            acc[mi][ni] = __builtin_amdgcn_mfma_f32_16x16x32_f16(ah[mi], t[ni], acc[mi][ni], 0, 0, 0);
#pragma unroll
        for (int mi = 0; mi < 4; ++mi)
          ah[mi] = *(const half8*)(const void*)(ldsA + (size_t)((16 + (wm * 4 + mi) * 2 + ksub) * 64 + lane) * 8);
#pragma unroll
        for (int mi = 0; mi < 4; ++mi)
#pragma unroll
          for (int ni = 0; ni < 4; ++ni)
            acc[mi][ni] = __builtin_amdgcn_mfma_f32_16x16x32_f16(ah[mi], bh[ni], acc[mi][ni], 0, 0, 0);
      }
    }
    float bp[4][4];
#pragma unroll
    for (int mi = 0; mi < 4; ++mi)
#pragma unroll
      for (int r = 0; r < 4; ++r) {
        bp[mi][r] = 0.f;
#pragma unroll
        for (int ni = 0; ni < 4; ++ni) {
          float v = fmaxf(acc[mi][ni][r] + b1v[ni], 0.f);
          bp[mi][r] += v * wbv[ni];
        }
      }
#pragma unroll
    for (int mi = 0; mi < 4; ++mi)
#pragma unroll
      for (int r = 0; r < 4; ++r) {
        float s = bp[mi][r];
        s += __shfl_xor(s, 1);
        s += __shfl_xor(s, 2);
        s += __shfl_xor(s, 4);
        s += __shfl_xor(s, 8);
        if ((lane & 15) == 0)
          bidred[wn][wm * 64 + mi * 16 + ((lane >> 4) << 2) + r] = s;
      }
    __syncthreads();
    if (tid < 128) {
      int ri = m * 128 + tid;
      if (ri < cnt) {
        int row = myList[ri];
        rbp[(size_t)(e * 16 + nt) * 4096 + row] = bidred[0][tid] + bidred[1][tid];
      }
    }
  }
}

// ---------- tier-1 finalize ----------
__global__ void repair1_final_kernel(const float* __restrict__ bb,
                                     const int* __restrict__ rcnt1,
                                     const u32* __restrict__ rlist1,
                                     const float* __restrict__ rbp,
                                     float* __restrict__ bids,
                                     float* __restrict__ outIdx,
                                     int* __restrict__ rcnt2, u32* __restrict__ rlist2)
{
  int idx = blockIdx.x * 64 + threadIdx.x;
  int cnt = *rcnt1;
  if (idx >= cnt) return;
  u32 ent1 = rlist1[idx];
  int b = ent1 & 0xFFFF;
  u32 mask1 = ent1 >> 16;
  float v[16];
#pragma unroll
  for (int e = 0; e < 16; ++e) {
    if ((mask1 >> e) & 1) {
      float s = bb[e];
      for (int nt = 0; nt < 16; ++nt) s += rbp[(size_t)(e * 16 + nt) * 4096 + b];
      v[e] = s;
      bids[(size_t)e * NB + b] = s;
    } else {
      v[e] = bids[(size_t)e * NB + b];
    }
  }
  int ord[16]; u32 used = 0;
  for (int j = 0; j < 16; ++j) {
    int best = 0; float bv = -3.4e38f;
    for (int t = 0; t < 16; ++t)
      if (!((used >> t) & 1) && v[t] > bv) { bv = v[t]; best = t; }
    ord[j] = best; used |= 1u << best;
  }
  for (int k = 0; k < 4; ++k) outIdx[b * 4 + k] = (float)ord[k];
  u32 mask = 0;
  for (int j = 0; j < 4; ++j)
    if (v[ord[j]] - v[ord[j + 1]] < THR_GAP2) { mask |= 1u << ord[j]; mask |= 1u << ord[j + 1]; }
  if (mask) {
    int jj = 4;
    while (jj < 15 && ((mask >> ord[jj]) & 1) && v[ord[jj]] - v[ord[jj + 1]] < THR_GAP2) {
      mask |= 1u << ord[jj + 1]; ++jj;
    }
    int slot = atomicAdd(rcnt2, 1);
    rlist2[slot] = (u32)b | (mask << 16);
  }
}

// ---------- tier-2 fp64 ----------
__global__ __launch_bounds__(256) void repair_partial_kernel(
    const float* __restrict__ x, const float* __restrict__ W1,
    const float* __restrict__ b1, const float* __restrict__ Wb,
    const int* __restrict__ rcnt2, const u32* __restrict__ rlist2,
    double* __restrict__ rpart)
{
  __shared__ float xrow[DIN];
  __shared__ double red[256];
  const int tid = threadIdx.x;
  int cnt = *rcnt2;
  int nit = cnt << 7;
  for (int item = blockIdx.x; item < nit; item += gridDim.x) {
    int it = item >> 7, e = (item >> 3) & 15, jc = item & 7;
    u32 ent = rlist2[it];
    if (!((ent >> (16 + e)) & 1)) continue;
    int b = ent & 0xFFFF;
    for (int i = tid; i < DIN; i += 256) xrow[i] = x[(size_t)b * DIN + i];
    __syncthreads();
    int j = jc * 256 + tid;
    const float* wcol = W1 + (size_t)e * DIN * DH + j;
    double z0 = 0, z1 = 0, z2 = 0, z3 = 0;
    for (int k = 0; k < DIN; k += 4) {
      z0 += (double)xrow[k]     * (double)wcol[(size_t)k * DH];
      z1 += (double)xrow[k + 1] * (double)wcol[(size_t)(k + 1) * DH];
      z2 += (double)xrow[k + 2] * (double)wcol[(size_t)(k + 2) * DH];
      z3 += (double)xrow[k + 3] * (double)wcol[(size_t)(k + 3) * DH];
    }
    double z = ((z0 + z1) + (z2 + z3)) + (double)b1[e * DH + j];
    red[tid] = (z > 0.0) ? z * (double)Wb[e * DH + j] : 0.0;
    __syncthreads();
    for (int off = 128; off > 0; off >>= 1) {
      if (tid < off) red[tid] += red[tid + off];
      __syncthreads();
    }
    if (tid == 0) rpart[item] = red[0];
    __syncthreads();
  }
}

__global__ void repair_final_kernel(const float* __restrict__ bids,
                                    const float* __restrict__ bb,
                                    const int* __restrict__ rcnt2,
                                    const u32* __restrict__ rlist2,
                                    const double* __restrict__ rpart,
                                    float* __restrict__ outIdx)
{
  __shared__ double v[16];
  int cnt = *rcnt2;
  int tid = threadIdx.x;
  for (int it = blockIdx.x; it < cnt; it += gridDim.x) {
    u32 ent = rlist2[it];
    int b = ent & 0xFFFF;
    if (tid < 16) {
      double val;
      if ((ent >> (16 + tid)) & 1) {
        double s = (double)bb[tid];
        for (int jc = 0; jc < 8; ++jc) s += rpart[(it << 7) + (tid << 3) + jc];
        val = s;
      } else {
        val = (double)bids[(size_t)tid * NB + b];
      }
      v[tid] = val;
    }
    __syncthreads();
    if (tid == 0) {
      u32 used = 0;
      for (int k = 0; k < 4; ++k) {
        int best = 0; double bv = -1e300;
        for (int t = 0; t < 16; ++t)
          if (!((used >> t) & 1) && v[t] > bv) { bv = v[t]; best = t; }
        outIdx[b * 4 + k] = (float)best; used |= 1u << best;
      }
    }
    __syncthreads();
  }
}

// ---------- per-expert row lists ----------
__global__ void build_lists_kernel(const float* __restrict__ outIdx,
                                   int* __restrict__ lists, int* __restrict__ counts)
{
  int e = blockIdx.x, tid = threadIdx.x;
  __shared__ int scan[256];
  __shared__ int base;
  if (tid == 0) base = 0;
  __syncthreads();
  for (int chunk = 0; chunk < NB; chunk += 256) {
    int b = chunk + tid;
    int slot = -1;
#pragma unroll
    for (int k = 0; k < 4; ++k)
      if ((int)outIdx[b * 4 + k] == e) slot = k;
    int flag = (slot >= 0) ? 1 : 0;
    scan[tid] = flag;
    __syncthreads();
    for (int off = 1; off < 256; off <<= 1) {
      int t = (tid >= off) ? scan[tid - off] : 0;
      __syncthreads();
      scan[tid] += t;
      __syncthreads();
    }
    if (flag) lists[e * NB + base + scan[tid] - 1] = (b << 2) | slot;
    int tot = scan[255];
    __syncthreads();
    if (tid == 0) base += tot;
    __syncthreads();
  }
  if (tid == 0) counts[e] = base;
}

// ============ SMALL path ============
__global__ void gather_xsel_kernel(const float* __restrict__ x,
                                   const int* __restrict__ lists,
                                   const int* __restrict__ counts,
                                   u16* __restrict__ xsel)
{
  int tid = threadIdx.x;
  int sub = tid >> 6, lane = tid & 63;
  int ri = blockIdx.x * 4 + sub;
  int e = 0, off = 0;
  for (int i = 0; i < 16; ++i) {
    int c = counts[i];
    if (ri < off + c) { e = i; break; }
    off += c;
  }
  int b = lists[e * NB + (ri - off)] >> 2;
  const float* src = x + (size_t)b * DIN + lane * 16;
  u16* dst = xsel + (size_t)ri * DIN + lane * 16;
  short8 o0, o1;
#pragma unroll
  for (int j = 0; j < 8; ++j) o0[j] = (short)f2h(src[j]);
#pragma unroll
  for (int j = 0; j < 8; ++j) o1[j] = (short)f2h(src[8 + j]);
  *(short8*)dst = o0;
  *(short8*)(dst + 8) = o1;
}

__global__ __launch_bounds__(256, 2) void hsel_kernel(
    const u16* __restrict__ xsel, const u16* __restrict__ pw1,
    const float* __restrict__ b1, const int* __restrict__ counts,
    u16* __restrict__ hselh)
{
  __shared__ u16 ldsA[8192];
  __shared__ u16 ldsB[8192];
  const int mtile = blockIdx.x, e = blockIdx.y, ng = blockIdx.z;
  const int cnt = counts[e];
  if (mtile * 128 >= cnt) return;
  int offs = 0;
  for (int i = 0; i < e; ++i) offs += counts[i];
  const int tid = threadIdx.x, w = tid >> 6, lane = tid & 63;
  const int wm = w >> 1, wn = w & 1;

  int r0 = mtile * 128 + (w * 2) * 16 + (lane & 15);
  int r1 = r0 + 16;
  r0 = (r0 < cnt) ? r0 : (cnt - 1);
  r1 = (r1 < cnt) ? r1 : (cnt - 1);
  const u16* arow0 = xsel + (size_t)(offs + r0) * DIN;
  const u16* arow1 = xsel + (size_t)(offs + r1) * DIN;
  const char* BbaseE = (const char*)pw1 + (size_t)(e * 16) * 16 * 32768;

  for (int nto = 0; nto < 4; ++nto) {
    int nt = ng * 4 + nto;
    f32x4 acc[4][4];
#pragma unroll
    for (int i = 0; i < 4; ++i)
#pragma unroll
      for (int j = 0; j < 4; ++j) acc[i][j] = (f32x4)0.f;
    const char* Bnt = BbaseE + (size_t)nt * 16 * 32768;

    for (int ks = 0; ks < 16; ++ks) {
      __syncthreads();
#pragma unroll
      for (int i = 0; i < 4; ++i) {
        int c = w * 4 + i, kt = c & 1;
        const u16* ga = ((i >> 1) ? arow1 : arow0) + ks * 64 + kt * 32 + ((lane >> 4) << 3);
        glds16(ga, (char*)ldsA + c * 1024);
        glds16(Bnt + (size_t)ks * 32768 + c * 1024 + lane * 16, (char*)ldsB + c * 1024);
      }
      __syncthreads();
#pragma unroll
      for (int ksub = 0; ksub < 2; ++ksub) {
        half8 ah[4], bh[4];
#pragma unroll
        for (int mi = 0; mi < 4; ++mi)
          ah[mi] = *(const half8*)(const void*)(ldsA + (size_t)(((wm * 4 + mi) * 2 + ksub) * 64 + lane) * 8);
#pragma unroll
        for (int ni = 0; ni < 4; ++ni)
          bh[ni] = *(const half8*)(const void*)(ldsB + (size_t)(((wn * 4 + ni) * 2 + ksub) * 64 + lane) * 8);
#pragma unroll
        for (int mi = 0; mi < 4; ++mi)
#pragma unroll
          for (int ni = 0; ni < 4; ++ni)
            acc[mi][ni] = __builtin_amdgcn_mfma_f32_16x16x32_f16(ah[mi], bh[ni], acc[mi][ni], 0, 0, 0);
      }
    }
    float b1v[4];
#pragma unroll
    for (int ni = 0; ni < 4; ++ni)
      b1v[ni] = b1[e * DH + nt * 128 + wn * 64 + ni * 16 + (lane & 15)];
#pragma unroll
    for (int mi = 0; mi < 4; ++mi)
#pragma unroll
      for (int r = 0; r < 4; ++r) {
        int ri = mtile * 128 + wm * 64 + mi * 16 + ((lane >> 4) << 2) + r;
        if (ri < cnt) {
          u16* hrow = hselh + (size_t)(offs + ri) * DH;
#pragma unroll
          for (int ni = 0; ni < 4; ++ni) {
            float v = fmaxf(acc[mi][ni][r] + b1v[ni], 0.f);
            hrow[nt * 128 + wn * 64 + ni * 16 + (lane & 15)] = f2h(v);
          }
        }
      }
  }
}

__global__ __launch_bounds__(256, 2) void gemm2_kernel(
    const u16* __restrict__ hselh, const u16* __restrict__ pw2,
    const float* __restrict__ b2, const int* __restrict__ lists,
    const int* __restrict__ counts, u16* __restrict__ contrib)
{
  __shared__ u16 ldsA[8192], ldsB[8192];
  const int mtile = blockIdx.x, ntile = blockIdx.y, e = blockIdx.z;
  const int cnt = counts[e];
  if (mtile * 128 >= cnt) return;
  int offs = 0;
  for (int i = 0; i < e; ++i) offs += counts[i];
  const int tid = threadIdx.x, w = tid >> 6, lane = tid & 63;
  const int wm = w >> 1, wn = w & 1;

  int rowg[2];
#pragma unroll
  for (int t = 0; t < 2; ++t) {
    int ri = mtile * 128 + (w * 2 + t) * 16 + (lane & 15);
    rowg[t] = offs + ((ri < cnt) ? ri : (cnt - 1));
  }
  const char* Bbase = (const char*)pw2 + (size_t)((e * 8 + ntile) * 32) * 16384;

  f32x4 acc[4][4];
#pragma unroll
  for (int i = 0; i < 4; ++i)
#pragma unroll
    for (int j = 0; j < 4; ++j) acc[i][j] = (f32x4)0.f;

  for (int ks = 0; ks < 32; ++ks) {
    __syncthreads();
#pragma unroll
    for (int i = 0; i < 4; ++i) {
      int c = w * 4 + i, kt = c & 1;
      const u16* ga = hselh + (size_t)rowg[i >> 1] * DH + ks * 64 + kt * 32 + ((lane >> 4) << 3);
      glds16(ga, (char*)ldsA + c * 1024);
      glds16(Bbase + (size_t)ks * 16384 + c * 1024 + lane * 16, (char*)ldsB + c * 1024);
    }
    __syncthreads();
#pragma unroll
    for (int ksub = 0; ksub < 2; ++ksub) {
      half8 af[4], bf[4];
#pragma unroll
      for (int mi = 0; mi < 4; ++mi)
        af[mi] = *(const half8*)(const void*)(ldsA + (size_t)(((wm * 4 + mi) * 2 + ksub) * 64 + lane) * 8);
#pragma unroll
      for (int ni = 0; ni < 4; ++ni)
        bf[ni] = *(const half8*)(const void*)(ldsB + (size_t)(((wn * 4 + ni) * 2 + ksub) * 64 + lane) * 8);
#pragma unroll
      for (int mi = 0; mi < 4; ++mi)
#pragma unroll
        for (int ni = 0; ni < 4; ++ni)
          acc[mi][ni] = __builtin_amdgcn_mfma_f32_16x16x32_f16(af[mi], bf[ni], acc[mi][ni], 0, 0, 0);
    }
  }
  float b2v[4];
#pragma unroll
  for (int ni = 0; ni < 4; ++ni)
    b2v[ni] = b2[e * DOUT + ntile * 128 + wn * 64 + ni * 16 + (lane & 15)];
#pragma unroll
  for (int mi = 0; mi < 4; ++mi)
#pragma unroll
    for (int r = 0; r < 4; ++r) {
      int ri = mtile * 128 + wm * 64 + mi * 16 + ((lane >> 4) << 2) + r;
      if (ri < cnt) {
        int ent = lists[e * NB + ri];
        int b = ent >> 2, slot = ent & 3;
#pragma unroll
        for (int ni = 0; ni < 4; ++ni) {
          int o = ntile * 128 + wn * 64 + ni * 16 + (lane & 15);
          contrib[(size_t)(b * 4 + slot) * DOUT + o] = f2h(acc[mi][ni][r] + b2v[ni]);
        }
      }
    }
}

// ============ BIG path: gemm2 fp8, XCD-chunked swizzle (1D grid 4096) ============
__global__ __launch_bounds__(256, 2) void gemm2f8_kernel(
    const u8* __restrict__ hfull, const u8* __restrict__ pw2f8,
    const float* __restrict__ b2, const int* __restrict__ lists,
    const int* __restrict__ counts, u16* __restrict__ contrib)
{
  __shared__ u8 ldsA[8192], ldsB[8192];
  const int id = blockIdx.x;
  const int swz = (id & 7) * 512 + (id >> 3);          // bijective (4096 % 8 == 0)
  const int mtile = swz & 31, ntile = (swz >> 5) & 7, e = swz >> 8;
  const int cnt = counts[e];
  if (mtile * 128 >= cnt) return;
  const int tid = threadIdx.x, w = tid >> 6, lane = tid & 63;
  const int wm = w >> 1, wn = w & 1;

  const u8* arow[2];
#pragma unroll
  for (int t = 0; t < 2; ++t) {
    int ri = mtile * 128 + (w * 2 + t) * 16 + (lane & 15);
    int b = lists[e * NB + ((ri < cnt) ? ri : (cnt - 1))] >> 2;
    arow[t] = hfull + ((size_t)e * NB + b) * DH;
  }
  const u8* Bbase = pw2f8 + (size_t)((e * 8 + ntile) * 32) * 8192;

  f32x4 acc[4][4];
#pragma unroll
  for (int i = 0; i < 4; ++i)
#pragma unroll
    for (int j = 0; j < 4; ++j) acc[i][j] = (f32x4)0.f;

  for (int ks = 0; ks < 32; ++ks) {
    __syncthreads();
#pragma unroll
    for (int i = 0; i < 2; ++i) {
      int c = w * 2 + i;
      glds16(arow[i] + ks * 64 + ((lane >> 4) << 4), ldsA + c * 1024);
      glds16(Bbase + (size_t)ks * 8192 + c * 1024 + lane * 16, ldsB + c * 1024);
    }
    __syncthreads();
    int fo = (lane & 15) * 16 + (((lane >> 4) >> 1)) * 256 + ((lane >> 4) & 1) * 8;
#pragma unroll
    for (int ksub = 0; ksub < 2; ++ksub) {
      long a8[4], b8[4];
#pragma unroll
      for (int mi = 0; mi < 4; ++mi)
        a8[mi] = *(const long*)(const void*)(ldsA + (wm * 4 + mi) * 1024 + ksub * 512 + fo);
#pragma unroll
      for (int ni = 0; ni < 4; ++ni)
        b8[ni] = *(const long*)(const void*)(ldsB + (wn * 4 + ni) * 1024 + ksub * 512 + fo);
#pragma unroll
      for (int mi = 0; mi < 4; ++mi)
#pragma unroll
        for (int ni = 0; ni < 4; ++ni)
          acc[mi][ni] = __builtin_amdgcn_mfma_f32_16x16x32_fp8_fp8(a8[mi], b8[ni], acc[mi][ni], 0, 0, 0);
    }
  }
  float b2v[4];
#pragma unroll
  for (int ni = 0; ni < 4; ++ni)
    b2v[ni] = b2[e * DOUT + ntile * 128 + wn * 64 + ni * 16 + (lane & 15)];
#pragma unroll
  for (int mi = 0; mi < 4; ++mi)
#pragma unroll
    for (int r = 0; r < 4; ++r) {
      int ri = mtile * 128 + wm * 64 + mi * 16 + ((lane >> 4) << 2) + r;
      if (ri < cnt) {
        int ent = lists[e * NB + ri];
        int b = ent >> 2, slot = ent & 3;
#pragma unroll
        for (int ni = 0; ni < 4; ++ni) {
          int o = ntile * 128 + wn * 64 + ni * 16 + (lane & 15);
          contrib[(size_t)(b * 4 + slot) * DOUT + o] = f2h(acc[mi][ni][r] + b2v[ni]);
        }
      }
    }
}

// ---------- final: mean over 4 winner slots ----------
__global__ void finalize_kernel(const u16* __restrict__ contrib, float* __restrict__ out)
{
  int gid = blockIdx.x * 256 + threadIdx.x;
  int b = gid >> 7, o8 = (gid & 127) << 3;
  float s[8] = {0, 0, 0, 0, 0, 0, 0, 0};
#pragma unroll
  for (int sl = 0; sl < 4; ++sl) {
    short8 v = *(const short8*)(contrib + (size_t)(b * 4 + sl) * DOUT + o8);
#pragma unroll
    for (int j = 0; j < 8; ++j) s[j] += h2f((u16)v[j]);
  }
  float* op = out + (size_t)b * DOUT + o8;
#pragma unroll
  for (int j = 0; j < 8; ++j) op[j] = s[j] * 0.25f;
}

extern "C" void kernel_launch(void* const* d_in, const int* in_sizes, int n_in,
                              void* d_out, int out_size, void* d_ws, size_t ws_size,
                              hipStream_t stream)
{
  (void)in_sizes; (void)n_in; (void)out_size;
  if (ws_size < WS_NEED_SM) return;
  const bool big = (ws_size >= WS_NEED_BIG);

  const float* x  = (const float*)d_in[0];
  const float* W1 = (const float*)d_in[1];
  const float* b1 = (const float*)d_in[2];
  const float* W2 = (const float*)d_in[3];
  const float* b2 = (const float*)d_in[4];
  const float* Wb = (const float*)d_in[5];
  const float* bb = (const float*)d_in[6];

  char* ws = (char*)d_ws;
  float* outMain = (float*)d_out;
  float* outIdx  = (float*)d_out + (size_t)NB * DOUT;

  if (big) {
    u16* px      = (u16*)(ws + PXB);
    u16* pw1     = (u16*)(ws + PW1B);
    u8*  hfull   = (u8*)(ws + HFULLB);
    u8*  pw2f8   = (u8*)(ws + PW2F8B);
    u16* contrib = (u16*)(ws + CONTRB);
    float* bidp  = (float*)(ws + RPARTB);                        // early (dead before rpart writes)
    int* cnt1e   = (int*)(ws + RPARTB + (size_t)512 * 1024);     // early
    float* bids  = (float*)(ws + BIDSB);
    int* lists   = (int*)(ws + LISTSB);
    int* rle     = (int*)(ws + LISTSB);                          // early (dead before build_lists)
    int* counts  = (int*)(ws + CNTB);
    int* rcnt1   = (int*)(ws + RCNTB);
    int* rcnt2   = (int*)(ws + RCNTB + 4);
    u32* rlist1  = (u32*)(ws + RLIST1B);
    u32* rlist2  = (u32*)(ws + RLIST2B);
    double* rpart = (double*)(ws + RPARTB);
    float* rbp   = (float*)(ws + RBPB);

    hipMemsetAsync(rcnt1, 0, 2 * sizeof(int), stream);
    hipMemsetAsync(cnt1e, 0, 16 * sizeof(int), stream);
    pack_x_kernel <<<2048, 256, 0, stream>>>(x, px);
    pack_w1_kernel<<<16384, 256, 0, stream>>>(W1, pw1);
    gemm1_bids_kernel<true><<<1024, 256, 0, stream>>>(px, pw1, b1, Wb, bidp, hfull);
    topk_kernel<<<16, 256, 0, stream>>>(bidp, bb, bids, outIdx, rcnt1, rlist1, cnt1e, rle);
    repair1_kernel<<<dim3(16, 16), 256, 0, stream>>>(px, pw1, b1, Wb, cnt1e, rle, rbp);
    repair1_final_kernel<<<64, 64, 0, stream>>>(bb, rcnt1, rlist1, rbp, bids, outIdx, rcnt2, rlist2);
    repair_partial_kernel<<<2048, 256, 0, stream>>>(x, W1, b1, Wb, rcnt2, rlist2, rpart);  // overwrites bidp/cnt1e (dead)
    repair_final_kernel<<<64, 64, 0, stream>>>(bids, bb, rcnt2, rlist2, rpart, outIdx);
    build_lists_kernel<<<16, 256, 0, stream>>>(outIdx, lists, counts);   // overwrites rle (dead)
    pack_w2f8_kernel<<<16384, 256, 0, stream>>>(W2, pw2f8);              // overlays pw1 (dead)
    gemm2f8_kernel<<<4096, 256, 0, stream>>>(hfull, pw2f8, b2, lists, counts, contrib);
    finalize_kernel<<<2048, 256, 0, stream>>>(contrib, outMain);
  } else {
    u16* px      = (u16*)(ws + PX_OFF);
    u16* xsel    = (u16*)(ws + XSEL_OFF);
    u16* contrib = (u16*)(ws + CONTRIB_OFF);
    float* bidp  = (float*)(ws + RPART_OFF);                     // early (dead before rpart writes)
    int* cnt1e   = (int*)(ws + RPART_OFF + (size_t)512 * 1024);  // early
    u16* pw1     = (u16*)(ws + PW1_OFF);
    u16* pw2     = (u16*)(ws + PW2_OFF);
    u16* hselh   = (u16*)(ws + HSEL_OFF);
    float* bids  = (float*)(ws + BIDS_OFF);
    int* lists   = (int*)(ws + LISTS_OFF);
    int* rle     = (int*)(ws + LISTS_OFF);                       // early
    int* counts  = (int*)(ws + CNT_OFF);
    int* rcnt1   = (int*)(ws + RCNT_OFF);
    int* rcnt2   = (int*)(ws + RCNT_OFF + 4);
    u32* rlist1  = (u32*)(ws + RLIST1_OFF);
    u32* rlist2  = (u32*)(ws + RLIST2_OFF);
    double* rpart = (double*)(ws + RPART_OFF);
    float* rbp   = (float*)(ws + RBP_OFF);

    hipMemsetAsync(rcnt1, 0, 2 * sizeof(int), stream);
    hipMemsetAsync(cnt1e, 0, 16 * sizeof(int), stream);
    pack_x_kernel <<<2048, 256, 0, stream>>>(x, px);
    pack_w1_kernel<<<16384, 256, 0, stream>>>(W1, pw1);
    gemm1_bids_kernel<false><<<1024, 256, 0, stream>>>(px, pw1, b1, Wb, bidp, nullptr);
    topk_kernel<<<16, 256, 0, stream>>>(bidp, bb, bids, outIdx, rcnt1, rlist1, cnt1e, rle);
    repair1_kernel<<<dim3(16, 16), 256, 0, stream>>>(px, pw1, b1, Wb, cnt1e, rle, rbp);
    repair1_final_kernel<<<64, 64, 0, stream>>>(bb, rcnt1, rlist1, rbp, bids, outIdx, rcnt2, rlist2);
    repair_partial_kernel<<<2048, 256, 0, stream>>>(x, W1, b1, Wb, rcnt2, rlist2, rpart);
    repair_final_kernel<<<64, 64, 0, stream>>>(bids, bb, rcnt2, rlist2, rpart, outIdx);
    build_lists_kernel<<<16, 256, 0, stream>>>(outIdx, lists, counts);
    gather_xsel_kernel<<<4096, 256, 0, stream>>>(x, lists, counts, xsel);
    hsel_kernel<<<dim3(32, 16, 4), 256, 0, stream>>>(xsel, pw1, b1, counts, hselh);
    pack_w2_kernel<<<16384, 256, 0, stream>>>(W2, pw2);
    gemm2_kernel<<<dim3(32, 8, 16), 256, 0, stream>>>(hselh, pw2, b2, lists, counts, contrib);
    finalize_kernel<<<2048, 256, 0, stream>>>(contrib, outMain);
  }
}

// Round 14
// 861.468 us; speedup vs baseline: 2.1145x; 1.0620x over previous
//
#include <hip/hip_runtime.h>
#include <stdint.h>

typedef unsigned short u16;
typedef unsigned char u8;
typedef unsigned int u32;
typedef __attribute__((ext_vector_type(8))) short short8;
typedef __attribute__((ext_vector_type(8))) _Float16 half8;
typedef __attribute__((ext_vector_type(4))) float f32x4;

static constexpr int NE = 16, NB = 4096, DIN = 1024, DH = 2048, DOUT = 1024;
#define THR_GAP1 5e-3f
#define THR_GAP2 1e-4f

// ---- SMALL-path ws layout (~235 MiB) ----
static constexpr size_t PX_OFF      = 0;
static constexpr size_t XSEL_OFF    = 0;
static constexpr size_t CONTRIB_OFF = 0;
static constexpr size_t PW1_OFF     = (size_t)32 * 1024 * 1024;
static constexpr size_t PW2_OFF     = PW1_OFF;
static constexpr size_t HSEL_OFF    = PW1_OFF + (size_t)128 * 1024 * 1024;
static constexpr size_t BIDS_OFF    = HSEL_OFF + (size_t)16384 * 2048 * 2;
static constexpr size_t LISTS_OFF   = BIDS_OFF + (size_t)NE * NB * 4;   // rle early / lists late
static constexpr size_t CNT_OFF     = LISTS_OFF + (size_t)NE * NB * 4;
static constexpr size_t RCNT_OFF    = CNT_OFF + 64;
static constexpr size_t RLIST1_OFF  = RCNT_OFF + 64;
static constexpr size_t RLIST2_OFF  = RLIST1_OFF + (size_t)4096 * 4;
static constexpr size_t RPART_OFF   = RLIST2_OFF + (size_t)4096 * 4;    // bidp+cnt1e early / rpart late
static constexpr size_t RBP_OFF     = RPART_OFF + (size_t)4096 * 128 * 8;
static constexpr size_t WS_NEED_SM  = RBP_OFF + (size_t)16 * 16 * 4096 * 4;

// ---- BIG-path ws layout (~281 MiB) ----
static constexpr size_t PXB      = 0;                                    // 16 MiB
static constexpr size_t PW1B     = (size_t)16 * 1024 * 1024;             // 128 MiB (dead after repair1)
static constexpr size_t HFULLB   = (size_t)144 * 1024 * 1024;            // 128 MiB fp8 h
static constexpr size_t PW2F8B   = (size_t)16 * 1024 * 1024;             // 32 MiB (overlay pw1 after repair1)
static constexpr size_t CONTRB   = (size_t)48 * 1024 * 1024;             // 32 MiB (overlay pw1; late)
static constexpr size_t BIDSB    = (size_t)272 * 1024 * 1024;
static constexpr size_t LISTSB   = BIDSB + (size_t)NE * NB * 4;          // rle early / lists late
static constexpr size_t CNTB     = LISTSB + (size_t)NE * NB * 4;
static constexpr size_t RCNTB    = CNTB + 64;
static constexpr size_t RLIST1B  = RCNTB + 64;
static constexpr size_t RLIST2B  = RLIST1B + (size_t)4096 * 4;
static constexpr size_t RPARTB   = RLIST2B + (size_t)4096 * 4;           // bidp+cnt1e early / rpart late
static constexpr size_t RBPB     = RPARTB + (size_t)4096 * 128 * 8;
static constexpr size_t WS_NEED_BIG = RBPB + (size_t)16 * 16 * 4096 * 4;
// bidp (512 KB) + cnt1e (64 B) live at RPART*_OFF: written by gemm1/topk, read by
// topk/repair1, DEAD before repair_partial (the rpart region's first writer).

__device__ __forceinline__ u16 f2h(float f) {
  union { _Float16 h; u16 u; } c; c.h = (_Float16)f; return c.u;
}
__device__ __forceinline__ float h2f(u16 v) {
  union { _Float16 h; u16 u; } c; c.u = v; return (float)c.h;
}
__device__ __forceinline__ u8 f2e4m3(float f) {
  return (u8)(__builtin_amdgcn_cvt_pk_fp8_f32(f, f, 0, false) & 0xFF);
}
__device__ __forceinline__ void glds16(const void* gsrc, void* ldst) {
  __builtin_amdgcn_global_load_lds(
      (const __attribute__((address_space(1))) u32*)gsrc,
      (__attribute__((address_space(3))) u32*)ldst, 16, 0, 0);
}

// ---------- pack kernels ----------
__global__ void pack_x_kernel(const float* __restrict__ x, u16* __restrict__ px) {
  int gid = blockIdx.x * 256 + threadIdx.x;
  int kk = gid & 127, b = gid >> 7;
  int k0 = kk * 8;
  const float* xp = x + (size_t)b * DIN + k0;
  short8 hv, lv;
#pragma unroll
  for (int i = 0; i < 8; ++i) {
    float f = xp[i];
    u16 hb = f2h(f);
    hv[i] = (short)hb;
    lv[i] = (short)f2h(f - h2f(hb));
  }
  int mtile = b >> 7, m = b & 127;
  int kstep = k0 >> 6, kt = (k0 >> 5) & 1;
  int lane = (m & 15) + (((k0 >> 3) & 3) << 4);
  int sub = (m >> 4) * 2 + kt;
  u16* img = px + (size_t)(mtile * 16 + kstep) * 16384;
  *(short8*)(img + (size_t)((0 + sub) * 64 + lane) * 8) = hv;
  *(short8*)(img + (size_t)((16 + sub) * 64 + lane) * 8) = lv;
}

__global__ void pack_w1_kernel(const float* __restrict__ W1, u16* __restrict__ pw1) {
  int gid = blockIdx.x * 256 + threadIdx.x;
  int n = gid & 2047;
  int kc = (gid >> 11) & 127;
  int e = gid >> 18;
  int k0 = kc * 8;
  const float* wp = W1 + ((size_t)e * DIN + k0) * DH + n;
  short8 hv, lv;
#pragma unroll
  for (int i = 0; i < 8; ++i) {
    float f = wp[(size_t)i * DH];
    u16 hb = f2h(f);
    hv[i] = (short)hb;
    lv[i] = (short)f2h(f - h2f(hb));
  }
  int ntile = n >> 7, nt4 = (n >> 4) & 7, kt = (k0 >> 5) & 1;
  int lane = (n & 15) + (((k0 >> 3) & 3) << 4);
  int sub = nt4 * 2 + kt;
  u16* img = pw1 + (size_t)((e * 16 + ntile) * 16 + (k0 >> 6)) * 16384;
  *(short8*)(img + (size_t)((0 + sub) * 64 + lane) * 8) = hv;
  *(short8*)(img + (size_t)((16 + sub) * 64 + lane) * 8) = lv;
}

// fp16 W2 image (small path)
__global__ void pack_w2_kernel(const float* __restrict__ W2, u16* __restrict__ pw2) {
  int gid = blockIdx.x * 256 + threadIdx.x;
  int n = gid & 1023;
  int kc = (gid >> 10) & 255;
  int e = gid >> 18;
  int k0 = kc * 8;
  const float* wp = W2 + ((size_t)e * DH + k0) * DOUT + n;
  short8 hv;
#pragma unroll
  for (int i = 0; i < 8; ++i) hv[i] = (short)f2h(wp[(size_t)i * DOUT]);
  int ntile = n >> 7, nt4 = (n >> 4) & 7, kt = (k0 >> 5) & 1;
  int lane = (n & 15) + (((k0 >> 3) & 3) << 4);
  int sub = nt4 * 2 + kt;
  u16* img = pw2 + (size_t)((e * 8 + ntile) * 32 + (k0 >> 6)) * 8192;
  *(short8*)(img + (size_t)(sub * 64 + lane) * 8) = hv;
}

// fp8 W2 image (big path)
__global__ void pack_w2f8_kernel(const float* __restrict__ W2, u8* __restrict__ pw2f8) {
  int gid = blockIdx.x * 256 + threadIdx.x;
  int n = gid & 1023;
  int kc = (gid >> 10) & 255;
  int e = gid >> 18;
  int k0 = kc * 8;
  const float* wp = W2 + ((size_t)e * DH + k0) * DOUT + n;
  float f[8];
#pragma unroll
  for (int i = 0; i < 8; ++i) f[i] = wp[(size_t)i * DOUT];
  u32 lo = (u32)__builtin_amdgcn_cvt_pk_fp8_f32(f[0], f[1], 0, false);
  lo = (u32)__builtin_amdgcn_cvt_pk_fp8_f32(f[2], f[3], (int)lo, true);
  u32 hi = (u32)__builtin_amdgcn_cvt_pk_fp8_f32(f[4], f[5], 0, false);
  hi = (u32)__builtin_amdgcn_cvt_pk_fp8_f32(f[6], f[7], (int)hi, true);
  int ntile = n >> 7, c = (n >> 4) & 7, ks = k0 >> 6;
  int l = (n & 15) + 16 * ((k0 & 63) >> 4);
  u8* img = pw2f8 + (size_t)((e * 8 + ntile) * 32 + ks) * 8192 + c * 1024 + l * 16 + (k0 & 15);
  *(u32*)img = lo;
  *(u32*)(img + 4) = hi;
}

// ---------- GEMM1: plain fp16, ng-split x2, XCD-chunked swizzle, partial bids ----------
template <bool SH>
__global__ __launch_bounds__(256, 4) void gemm1_bids_kernel(
    const u16* __restrict__ px, const u16* __restrict__ pw1,
    const float* __restrict__ b1, const float* __restrict__ Wb,
    float* __restrict__ bidp, u8* __restrict__ hfull)
{
  __shared__ u16 ldsA[8192];
  __shared__ u16 ldsB[8192];
  __shared__ float bidred[2][128];
  const int id = blockIdx.x;
  const int swz = (id & 7) * 128 + (id >> 3);          // bijective (1024 % 8 == 0)
  const int mtile = swz & 31, e = (swz >> 5) & 15, ng = swz >> 9;
  const int tid = threadIdx.x, w = tid >> 6, lane = tid & 63;
  const int wm = w >> 1, wn = w & 1;

  const char* Abase = (const char*)px + (size_t)(mtile * 16) * 32768;
  const char* BbaseE = (const char*)pw1 + (size_t)(e * 16) * 16 * 32768;

  float bp[4][4];
#pragma unroll
  for (int mi = 0; mi < 4; ++mi)
#pragma unroll
    for (int r = 0; r < 4; ++r) bp[mi][r] = 0.f;

  for (int nto = 0; nto < 8; ++nto) {
    int nt = ng * 8 + nto;
    f32x4 acc[4][4];
#pragma unroll
    for (int i = 0; i < 4; ++i)
#pragma unroll
      for (int j = 0; j < 4; ++j) acc[i][j] = (f32x4)0.f;
    const char* Bnt = BbaseE + (size_t)nt * 16 * 32768;

    for (int ks = 0; ks < 16; ++ks) {
      __syncthreads();
      const char* Ak = Abase + (size_t)ks * 32768;
      const char* Bk = Bnt + (size_t)ks * 32768;
#pragma unroll
      for (int i = 0; i < 4; ++i) {
        int c = w * 4 + i;
        glds16(Ak + c * 1024 + lane * 16, (char*)ldsA + c * 1024);
        glds16(Bk + c * 1024 + lane * 16, (char*)ldsB + c * 1024);
      }
      __syncthreads();
#pragma unroll
      for (int ksub = 0; ksub < 2; ++ksub) {
        half8 ah[4], bh[4];
#pragma unroll
        for (int mi = 0; mi < 4; ++mi)
          ah[mi] = *(const half8*)(const void*)(ldsA + (size_t)(((wm * 4 + mi) * 2 + ksub) * 64 + lane) * 8);
#pragma unroll
        for (int ni = 0; ni < 4; ++ni)
          bh[ni] = *(const half8*)(const void*)(ldsB + (size_t)(((wn * 4 + ni) * 2 + ksub) * 64 + lane) * 8);
#pragma unroll
        for (int mi = 0; mi < 4; ++mi)
#pragma unroll
          for (int ni = 0; ni < 4; ++ni)
            acc[mi][ni] = __builtin_amdgcn_mfma_f32_16x16x32_f16(ah[mi], bh[ni], acc[mi][ni], 0, 0, 0);
      }
    }
    float b1v[4], wbv[4];
#pragma unroll
    for (int ni = 0; ni < 4; ++ni) {
      int n = nt * 128 + wn * 64 + ni * 16 + (lane & 15);
      b1v[ni] = b1[e * DH + n];
      wbv[ni] = Wb[e * DH + n];
    }
#pragma unroll
    for (int mi = 0; mi < 4; ++mi)
#pragma unroll
      for (int r = 0; r < 4; ++r)
#pragma unroll
        for (int ni = 0; ni < 4; ++ni) {
          float v = fmaxf(acc[mi][ni][r] + b1v[ni], 0.f);
          bp[mi][r] += v * wbv[ni];
        }
    if (SH) {
#pragma unroll
      for (int mi = 0; mi < 4; ++mi)
#pragma unroll
        for (int r = 0; r < 4; ++r) {
          int row = mtile * 128 + wm * 64 + mi * 16 + ((lane >> 4) << 2) + r;
          u8* hrow = hfull + ((size_t)e * NB + row) * DH;
#pragma unroll
          for (int ni = 0; ni < 4; ++ni) {
            float v = fmaxf(acc[mi][ni][r] + b1v[ni], 0.f);
            hrow[nt * 128 + wn * 64 + ni * 16 + (lane & 15)] = f2e4m3(v);
          }
        }
    }
  }
#pragma unroll
  for (int mi = 0; mi < 4; ++mi)
#pragma unroll
    for (int r = 0; r < 4; ++r) {
      float s = bp[mi][r];
      s += __shfl_xor(s, 1);
      s += __shfl_xor(s, 2);
      s += __shfl_xor(s, 4);
      s += __shfl_xor(s, 8);
      if ((lane & 15) == 0)
        bidred[wn][wm * 64 + mi * 16 + ((lane >> 4) << 2) + r] = s;
    }
  __syncthreads();
  if (tid < 128)
    bidp[(size_t)(e * 2 + ng) * NB + mtile * 128 + tid] = bidred[0][tid] + bidred[1][tid];
}

// ---------- top-4 + tier-1 flagging with ambiguous-expert mask + per-expert lists ----------
__global__ void topk_kernel(const float* __restrict__ bidp, const float* __restrict__ bb,
                            float* __restrict__ bids, float* __restrict__ outIdx,
                            int* __restrict__ rcnt1, u32* __restrict__ rlist1,
                            int* __restrict__ cnt1e, int* __restrict__ rle)
{
  int b = blockIdx.x * 256 + threadIdx.x;
  float v[16];
#pragma unroll
  for (int e = 0; e < 16; ++e) {
    float s = bidp[(size_t)(e * 2) * NB + b] + bidp[(size_t)(e * 2 + 1) * NB + b] + bb[e];
    v[e] = s;
    bids[(size_t)e * NB + b] = s;
  }
  int ord[16]; u32 used = 0;
  for (int j = 0; j < 16; ++j) {
    int best = 0; float bv = -3.4e38f;
    for (int t = 0; t < 16; ++t)
      if (!((used >> t) & 1) && v[t] > bv) { bv = v[t]; best = t; }
    ord[j] = best; used |= 1u << best;
  }
  for (int k = 0; k < 4; ++k) outIdx[b * 4 + k] = (float)ord[k];
  bool flag = false;
  for (int j = 0; j < 4; ++j)
    if (v[ord[j]] - v[ord[j + 1]] < THR_GAP1) flag = true;
  if (flag) {
    float vmin = v[ord[3]] - 2.f * THR_GAP1;
    u32 mask = 0;
    for (int e = 0; e < 16; ++e)
      if (v[e] >= vmin) mask |= 1u << e;
    int slot = atomicAdd(rcnt1, 1);
    rlist1[slot] = (u32)b | (mask << 16);
    for (int e = 0; e < 16; ++e)
      if ((mask >> e) & 1) {
        int p = atomicAdd(&cnt1e[e], 1);
        rle[e * NB + p] = b;
      }
  }
}

// ---------- tier-1 repair: grid (nt=16, e=16, ms=2); m strided by 2 for 2 blocks/CU ----------
__global__ __launch_bounds__(256, 2) void repair1_kernel(
    const u16* __restrict__ px, const u16* __restrict__ pw1,
    const float* __restrict__ b1, const float* __restrict__ Wb,
    const int* __restrict__ cnt1e, const int* __restrict__ rle,
    float* __restrict__ rbp)
{
  __shared__ u16 ldsA[16384];
  __shared__ u16 ldsB[16384];
  __shared__ float bidred[2][128];
  const int nt = blockIdx.x, e = blockIdx.y, ms = blockIdx.z;
  const int cnt = cnt1e[e];
  if (cnt == 0) return;
  const int nm = (cnt + 127) >> 7;
  if (ms >= nm) return;
  const int tid = threadIdx.x, w = tid >> 6, lane = tid & 63;
  const int wm = w >> 1, wn = w & 1;
  const char* Bnt = (const char*)pw1 + (size_t)((e * 16 + nt) * 16) * 32768;
  const int* myList = rle + e * NB;

  float b1v[4], wbv[4];
#pragma unroll
  for (int ni = 0; ni < 4; ++ni) {
    int n = nt * 128 + wn * 64 + ni * 16 + (lane & 15);
    b1v[ni] = b1[e * DH + n];
    wbv[ni] = Wb[e * DH + n];
  }

  for (int m = ms; m < nm; m += 2) {
    int rowb[4];
#pragma unroll
    for (int t = 0; t < 4; ++t) {
      int ri = m * 128 + ((w & 1) * 4 + t) * 16 + (lane & 15);
      rowb[t] = myList[(ri < cnt) ? ri : (cnt - 1)];
    }
    f32x4 acc[4][4];
#pragma unroll
    for (int i = 0; i < 4; ++i)
#pragma unroll
      for (int j = 0; j < 4; ++j) acc[i][j] = (f32x4)0.f;

    for (int ks = 0; ks < 16; ++ks) {
      __syncthreads();
#pragma unroll
      for (int i = 0; i < 8; ++i) {
        int c = w * 8 + i;
        int b = rowb[i >> 1];
        const char* srcA = (const char*)px
            + (size_t)((b >> 7) * 16 + ks) * 32768
            + (c >> 4) * 16384
            + (((b & 127) >> 4) * 2 + (i & 1)) * 1024
            + ((b & 15) + ((lane >> 4) << 4)) * 16;
        glds16(srcA, (char*)ldsA + c * 1024);
        glds16(Bnt + (size_t)ks * 32768 + c * 1024 + lane * 16, (char*)ldsB + c * 1024);
      }
      __syncthreads();
#pragma unroll
      for (int ksub = 0; ksub < 2; ++ksub) {
        half8 ah[4], bh[4], t[4];
#pragma unroll
        for (int mi = 0; mi < 4; ++mi)
          ah[mi] = *(const half8*)(const void*)(ldsA + (size_t)(((wm * 4 + mi) * 2 + ksub) * 64 + lane) * 8);
#pragma unroll
        for (int ni = 0; ni < 4; ++ni)
          bh[ni] = *(const half8*)(const void*)(ldsB + (size_t)(((wn * 4 + ni) * 2 + ksub) * 64 + lane) * 8);
#pragma unroll
        for (int mi = 0; mi < 4; ++mi)
#pragma unroll
          for (int ni = 0; ni < 4; ++ni)
            acc[mi][ni] = __builtin_amdgcn_mfma_f32_16x16x32_f16(ah[mi], bh[ni], acc[mi][ni], 0, 0, 0);
#pragma unroll
        for (int ni = 0; ni < 4; ++ni)
          t[ni] = *(const half8*)(const void*)(ldsB + (size_t)((16 + (wn * 4 + ni) * 2 + ksub) * 64 + lane) * 8);
#pragma unroll
        for (int mi = 0; mi < 4; ++mi)
#pragma unroll
          for (int ni = 0; ni < 4; ++ni)
            acc[mi][ni] = __builtin_amdgcn_mfma_f32_16x16x32_f16(ah[mi], t[ni], acc[mi][ni], 0, 0, 0);
#pragma unroll
        for (int mi = 0; mi < 4; ++mi)
          ah[mi] = *(const half8*)(const void*)(ldsA + (size_t)((16 + (wm * 4 + mi) * 2 + ksub) * 64 + lane) * 8);
#pragma unroll
        for (int mi = 0; mi < 4; ++mi)
#pragma unroll
          for (int ni = 0; ni < 4; ++ni)
            acc[mi][ni] = __builtin_amdgcn_mfma_f32_16x16x32_f16(ah[mi], bh[ni], acc[mi][ni], 0, 0, 0);
      }
    }
    float bp[4][4];
#pragma unroll
    for (int mi = 0; mi < 4; ++mi)
#pragma unroll
      for (int r = 0; r < 4; ++r) {
        bp[mi][r] = 0.f;
#pragma unroll
        for (int ni = 0; ni < 4; ++ni) {
          float v = fmaxf(acc[mi][ni][r] + b1v[ni], 0.f);
          bp[mi][r] += v * wbv[ni];
        }
      }
#pragma unroll
    for (int mi = 0; mi < 4; ++mi)
#pragma unroll
      for (int r = 0; r < 4; ++r) {
        float s = bp[mi][r];
        s += __shfl_xor(s, 1);
        s += __shfl_xor(s, 2);
        s += __shfl_xor(s, 4);
        s += __shfl_xor(s, 8);
        if ((lane & 15) == 0)
          bidred[wn][wm * 64 + mi * 16 + ((lane >> 4) << 2) + r] = s;
      }
    __syncthreads();
    if (tid < 128) {
      int ri = m * 128 + tid;
      if (ri < cnt) {
        int row = myList[ri];
        rbp[(size_t)(e * 16 + nt) * 4096 + row] = bidred[0][tid] + bidred[1][tid];
      }
    }
  }
}

// ---------- tier-1 finalize ----------
__global__ void repair1_final_kernel(const float* __restrict__ bb,
                                     const int* __restrict__ rcnt1,
                                     const u32* __restrict__ rlist1,
                                     const float* __restrict__ rbp,
                                     float* __restrict__ bids,
                                     float* __restrict__ outIdx,
                                     int* __restrict__ rcnt2, u32* __restrict__ rlist2)
{
  int idx = blockIdx.x * 64 + threadIdx.x;
  int cnt = *rcnt1;
  if (idx >= cnt) return;
  u32 ent1 = rlist1[idx];
  int b = ent1 & 0xFFFF;
  u32 mask1 = ent1 >> 16;
  float v[16];
#pragma unroll
  for (int e = 0; e < 16; ++e) {
    if ((mask1 >> e) & 1) {
      float s = bb[e];
      for (int nt = 0; nt < 16; ++nt) s += rbp[(size_t)(e * 16 + nt) * 4096 + b];
      v[e] = s;
      bids[(size_t)e * NB + b] = s;
    } else {
      v[e] = bids[(size_t)e * NB + b];
    }
  }
  int ord[16]; u32 used = 0;
  for (int j = 0; j < 16; ++j) {
    int best = 0; float bv = -3.4e38f;
    for (int t = 0; t < 16; ++t)
      if (!((used >> t) & 1) && v[t] > bv) { bv = v[t]; best = t; }
    ord[j] = best; used |= 1u << best;
  }
  for (int k = 0; k < 4; ++k) outIdx[b * 4 + k] = (float)ord[k];
  u32 mask = 0;
  for (int j = 0; j < 4; ++j)
    if (v[ord[j]] - v[ord[j + 1]] < THR_GAP2) { mask |= 1u << ord[j]; mask |= 1u << ord[j + 1]; }
  if (mask) {
    int jj = 4;
    while (jj < 15 && ((mask >> ord[jj]) & 1) && v[ord[jj]] - v[ord[jj + 1]] < THR_GAP2) {
      mask |= 1u << ord[jj + 1]; ++jj;
    }
    int slot = atomicAdd(rcnt2, 1);
    rlist2[slot] = (u32)b | (mask << 16);
  }
}

// ---------- tier-2 fp64 ----------
__global__ __launch_bounds__(256) void repair_partial_kernel(
    const float* __restrict__ x, const float* __restrict__ W1,
    const float* __restrict__ b1, const float* __restrict__ Wb,
    const int* __restrict__ rcnt2, const u32* __restrict__ rlist2,
    double* __restrict__ rpart)
{
  __shared__ float xrow[DIN];
  __shared__ double red[256];
  const int tid = threadIdx.x;
  int cnt = *rcnt2;
  int nit = cnt << 7;
  for (int item = blockIdx.x; item < nit; item += gridDim.x) {
    int it = item >> 7, e = (item >> 3) & 15, jc = item & 7;
    u32 ent = rlist2[it];
    if (!((ent >> (16 + e)) & 1)) continue;
    int b = ent & 0xFFFF;
    for (int i = tid; i < DIN; i += 256) xrow[i] = x[(size_t)b * DIN + i];
    __syncthreads();
    int j = jc * 256 + tid;
    const float* wcol = W1 + (size_t)e * DIN * DH + j;
    double z0 = 0, z1 = 0, z2 = 0, z3 = 0;
    for (int k = 0; k < DIN; k += 4) {
      z0 += (double)xrow[k]     * (double)wcol[(size_t)k * DH];
      z1 += (double)xrow[k + 1] * (double)wcol[(size_t)(k + 1) * DH];
      z2 += (double)xrow[k + 2] * (double)wcol[(size_t)(k + 2) * DH];
      z3 += (double)xrow[k + 3] * (double)wcol[(size_t)(k + 3) * DH];
    }
    double z = ((z0 + z1) + (z2 + z3)) + (double)b1[e * DH + j];
    red[tid] = (z > 0.0) ? z * (double)Wb[e * DH + j] : 0.0;
    __syncthreads();
    for (int off = 128; off > 0; off >>= 1) {
      if (tid < off) red[tid] += red[tid + off];
      __syncthreads();
    }
    if (tid == 0) rpart[item] = red[0];
    __syncthreads();
  }
}

__global__ void repair_final_kernel(const float* __restrict__ bids,
                                    const float* __restrict__ bb,
                                    const int* __restrict__ rcnt2,
                                    const u32* __restrict__ rlist2,
                                    const double* __restrict__ rpart,
                                    float* __restrict__ outIdx)
{
  __shared__ double v[16];
  int cnt = *rcnt2;
  int tid = threadIdx.x;
  for (int it = blockIdx.x; it < cnt; it += gridDim.x) {
    u32 ent = rlist2[it];
    int b = ent & 0xFFFF;
    if (tid < 16) {
      double val;
      if ((ent >> (16 + tid)) & 1) {
        double s = (double)bb[tid];
        for (int jc = 0; jc < 8; ++jc) s += rpart[(it << 7) + (tid << 3) + jc];
        val = s;
      } else {
        val = (double)bids[(size_t)tid * NB + b];
      }
      v[tid] = val;
    }
    __syncthreads();
    if (tid == 0) {
      u32 used = 0;
      for (int k = 0; k < 4; ++k) {
        int best = 0; double bv = -1e300;
        for (int t = 0; t < 16; ++t)
          if (!((used >> t) & 1) && v[t] > bv) { bv = v[t]; best = t; }
        outIdx[b * 4 + k] = (float)best; used |= 1u << best;
      }
    }
    __syncthreads();
  }
}

// ---------- per-expert row lists ----------
__global__ void build_lists_kernel(const float* __restrict__ outIdx,
                                   int* __restrict__ lists, int* __restrict__ counts)
{
  int e = blockIdx.x, tid = threadIdx.x;
  __shared__ int scan[256];
  __shared__ int base;
  if (tid == 0) base = 0;
  __syncthreads();
  for (int chunk = 0; chunk < NB; chunk += 256) {
    int b = chunk + tid;
    int slot = -1;
#pragma unroll
    for (int k = 0; k < 4; ++k)
      if ((int)outIdx[b * 4 + k] == e) slot = k;
    int flag = (slot >= 0) ? 1 : 0;
    scan[tid] = flag;
    __syncthreads();
    for (int off = 1; off < 256; off <<= 1) {
      int t = (tid >= off) ? scan[tid - off] : 0;
      __syncthreads();
      scan[tid] += t;
      __syncthreads();
    }
    if (flag) lists[e * NB + base + scan[tid] - 1] = (b << 2) | slot;
    int tot = scan[255];
    __syncthreads();
    if (tid == 0) base += tot;
    __syncthreads();
  }
  if (tid == 0) counts[e] = base;
}

// ============ SMALL path ============
__global__ void gather_xsel_kernel(const float* __restrict__ x,
                                   const int* __restrict__ lists,
                                   const int* __restrict__ counts,
                                   u16* __restrict__ xsel)
{
  int tid = threadIdx.x;
  int sub = tid >> 6, lane = tid & 63;
  int ri = blockIdx.x * 4 + sub;
  int e = 0, off = 0;
  for (int i = 0; i < 16; ++i) {
    int c = counts[i];
    if (ri < off + c) { e = i; break; }
    off += c;
  }
  int b = lists[e * NB + (ri - off)] >> 2;
  const float* src = x + (size_t)b * DIN + lane * 16;
  u16* dst = xsel + (size_t)ri * DIN + lane * 16;
  short8 o0, o1;
#pragma unroll
  for (int j = 0; j < 8; ++j) o0[j] = (short)f2h(src[j]);
#pragma unroll
  for (int j = 0; j < 8; ++j) o1[j] = (short)f2h(src[8 + j]);
  *(short8*)dst = o0;
  *(short8*)(dst + 8) = o1;
}

__global__ __launch_bounds__(256, 2) void hsel_kernel(
    const u16* __restrict__ xsel, const u16* __restrict__ pw1,
    const float* __restrict__ b1, const int* __restrict__ counts,
    u16* __restrict__ hselh)
{
  __shared__ u16 ldsA[8192];
  __shared__ u16 ldsB[8192];
  const int mtile = blockIdx.x, e = blockIdx.y, ng = blockIdx.z;
  const int cnt = counts[e];
  if (mtile * 128 >= cnt) return;
  int offs = 0;
  for (int i = 0; i < e; ++i) offs += counts[i];
  const int tid = threadIdx.x, w = tid >> 6, lane = tid & 63;
  const int wm = w >> 1, wn = w & 1;

  int r0 = mtile * 128 + (w * 2) * 16 + (lane & 15);
  int r1 = r0 + 16;
  r0 = (r0 < cnt) ? r0 : (cnt - 1);
  r1 = (r1 < cnt) ? r1 : (cnt - 1);
  const u16* arow0 = xsel + (size_t)(offs + r0) * DIN;
  const u16* arow1 = xsel + (size_t)(offs + r1) * DIN;
  const char* BbaseE = (const char*)pw1 + (size_t)(e * 16) * 16 * 32768;

  for (int nto = 0; nto < 4; ++nto) {
    int nt = ng * 4 + nto;
    f32x4 acc[4][4];
#pragma unroll
    for (int i = 0; i < 4; ++i)
#pragma unroll
      for (int j = 0; j < 4; ++j) acc[i][j] = (f32x4)0.f;
    const char* Bnt = BbaseE + (size_t)nt * 16 * 32768;

    for (int ks = 0; ks < 16; ++ks) {
      __syncthreads();
#pragma unroll
      for (int i = 0; i < 4; ++i) {
        int c = w * 4 + i, kt = c & 1;
        const u16* ga = ((i >> 1) ? arow1 : arow0) + ks * 64 + kt * 32 + ((lane >> 4) << 3);
        glds16(ga, (char*)ldsA + c * 1024);
        glds16(Bnt + (size_t)ks * 32768 + c * 1024 + lane * 16, (char*)ldsB + c * 1024);
      }
      __syncthreads();
#pragma unroll
      for (int ksub = 0; ksub < 2; ++ksub) {
        half8 ah[4], bh[4];
#pragma unroll
        for (int mi = 0; mi < 4; ++mi)
          ah[mi] = *(const half8*)(const void*)(ldsA + (size_t)(((wm * 4 + mi) * 2 + ksub) * 64 + lane) * 8);
#pragma unroll
        for (int ni = 0; ni < 4; ++ni)
          bh[ni] = *(const half8*)(const void*)(ldsB + (size_t)(((wn * 4 + ni) * 2 + ksub) * 64 + lane) * 8);
#pragma unroll
        for (int mi = 0; mi < 4; ++mi)
#pragma unroll
          for (int ni = 0; ni < 4; ++ni)
            acc[mi][ni] = __builtin_amdgcn_mfma_f32_16x16x32_f16(ah[mi], bh[ni], acc[mi][ni], 0, 0, 0);
      }
    }
    float b1v[4];
#pragma unroll
    for (int ni = 0; ni < 4; ++ni)
      b1v[ni] = b1[e * DH + nt * 128 + wn * 64 + ni * 16 + (lane & 15)];
#pragma unroll
    for (int mi = 0; mi < 4; ++mi)
#pragma unroll
      for (int r = 0; r < 4; ++r) {
        int ri = mtile * 128 + wm * 64 + mi * 16 + ((lane >> 4) << 2) + r;
        if (ri < cnt) {
          u16* hrow = hselh + (size_t)(offs + ri) * DH;
#pragma unroll
          for (int ni = 0; ni < 4; ++ni) {
            float v = fmaxf(acc[mi][ni][r] + b1v[ni], 0.f);
            hrow[nt * 128 + wn * 64 + ni * 16 + (lane & 15)] = f2h(v);
          }
        }
      }
  }
}

__global__ __launch_bounds__(256, 2) void gemm2_kernel(
    const u16* __restrict__ hselh, const u16* __restrict__ pw2,
    const float* __restrict__ b2, const int* __restrict__ lists,
    const int* __restrict__ counts, u16* __restrict__ contrib)
{
  __shared__ u16 ldsA[8192], ldsB[8192];
  const int mtile = blockIdx.x, ntile = blockIdx.y, e = blockIdx.z;
  const int cnt = counts[e];
  if (mtile * 128 >= cnt) return;
  int offs = 0;
  for (int i = 0; i < e; ++i) offs += counts[i];
  const int tid = threadIdx.x, w = tid >> 6, lane = tid & 63;
  const int wm = w >> 1, wn = w & 1;

  int rowg[2];
#pragma unroll
  for (int t = 0; t < 2; ++t) {
    int ri = mtile * 128 + (w * 2 + t) * 16 + (lane & 15);
    rowg[t] = offs + ((ri < cnt) ? ri : (cnt - 1));
  }
  const char* Bbase = (const char*)pw2 + (size_t)((e * 8 + ntile) * 32) * 16384;

  f32x4 acc[4][4];
#pragma unroll
  for (int i = 0; i < 4; ++i)
#pragma unroll
    for (int j = 0; j < 4; ++j) acc[i][j] = (f32x4)0.f;

  for (int ks = 0; ks < 32; ++ks) {
    __syncthreads();
#pragma unroll
    for (int i = 0; i < 4; ++i) {
      int c = w * 4 + i, kt = c & 1;
      const u16* ga = hselh + (size_t)rowg[i >> 1] * DH + ks * 64 + kt * 32 + ((lane >> 4) << 3);
      glds16(ga, (char*)ldsA + c * 1024);
      glds16(Bbase + (size_t)ks * 16384 + c * 1024 + lane * 16, (char*)ldsB + c * 1024);
    }
    __syncthreads();
#pragma unroll
    for (int ksub = 0; ksub < 2; ++ksub) {
      half8 af[4], bf[4];
#pragma unroll
      for (int mi = 0; mi < 4; ++mi)
        af[mi] = *(const half8*)(const void*)(ldsA + (size_t)(((wm * 4 + mi) * 2 + ksub) * 64 + lane) * 8);
#pragma unroll
      for (int ni = 0; ni < 4; ++ni)
        bf[ni] = *(const half8*)(const void*)(ldsB + (size_t)(((wn * 4 + ni) * 2 + ksub) * 64 + lane) * 8);
#pragma unroll
      for (int mi = 0; mi < 4; ++mi)
#pragma unroll
        for (int ni = 0; ni < 4; ++ni)
          acc[mi][ni] = __builtin_amdgcn_mfma_f32_16x16x32_f16(af[mi], bf[ni], acc[mi][ni], 0, 0, 0);
    }
  }
  float b2v[4];
#pragma unroll
  for (int ni = 0; ni < 4; ++ni)
    b2v[ni] = b2[e * DOUT + ntile * 128 + wn * 64 + ni * 16 + (lane & 15)];
#pragma unroll
  for (int mi = 0; mi < 4; ++mi)
#pragma unroll
    for (int r = 0; r < 4; ++r) {
      int ri = mtile * 128 + wm * 64 + mi * 16 + ((lane >> 4) << 2) + r;
      if (ri < cnt) {
        int ent = lists[e * NB + ri];
        int b = ent >> 2, slot = ent & 3;
#pragma unroll
        for (int ni = 0; ni < 4; ++ni) {
          int o = ntile * 128 + wn * 64 + ni * 16 + (lane & 15);
          contrib[(size_t)(b * 4 + slot) * DOUT + o] = f2h(acc[mi][ni][r] + b2v[ni]);
        }
      }
    }
}

// ============ BIG path: gemm2 fp8, XCD-chunked swizzle, 4 blocks/CU ============
__global__ __launch_bounds__(256, 4) void gemm2f8_kernel(
    const u8* __restrict__ hfull, const u8* __restrict__ pw2f8,
    const float* __restrict__ b2, const int* __restrict__ lists,
    const int* __restrict__ counts, u16* __restrict__ contrib)
{
  __shared__ u8 ldsA[8192], ldsB[8192];
  const int id = blockIdx.x;
  const int swz = (id & 7) * 512 + (id >> 3);          // bijective (4096 % 8 == 0)
  const int mtile = swz & 31, ntile = (swz >> 5) & 7, e = swz >> 8;
  const int cnt = counts[e];
  if (mtile * 128 >= cnt) return;
  const int tid = threadIdx.x, w = tid >> 6, lane = tid & 63;
  const int wm = w >> 1, wn = w & 1;

  const u8* arow[2];
#pragma unroll
  for (int t = 0; t < 2; ++t) {
    int ri = mtile * 128 + (w * 2 + t) * 16 + (lane & 15);
    int b = lists[e * NB + ((ri < cnt) ? ri : (cnt - 1))] >> 2;
    arow[t] = hfull + ((size_t)e * NB + b) * DH;
  }
  const u8* Bbase = pw2f8 + (size_t)((e * 8 + ntile) * 32) * 8192;

  f32x4 acc[4][4];
#pragma unroll
  for (int i = 0; i < 4; ++i)
#pragma unroll
    for (int j = 0; j < 4; ++j) acc[i][j] = (f32x4)0.f;

  for (int ks = 0; ks < 32; ++ks) {
    __syncthreads();
#pragma unroll
    for (int i = 0; i < 2; ++i) {
      int c = w * 2 + i;
      glds16(arow[i] + ks * 64 + ((lane >> 4) << 4), ldsA + c * 1024);
      glds16(Bbase + (size_t)ks * 8192 + c * 1024 + lane * 16, ldsB + c * 1024);
    }
    __syncthreads();
    int fo = (lane & 15) * 16 + (((lane >> 4) >> 1)) * 256 + ((lane >> 4) & 1) * 8;
#pragma unroll
    for (int ksub = 0; ksub < 2; ++ksub) {
      long a8[4], b8[4];
#pragma unroll
      for (int mi = 0; mi < 4; ++mi)
        a8[mi] = *(const long*)(const void*)(ldsA + (wm * 4 + mi) * 1024 + ksub * 512 + fo);
#pragma unroll
      for (int ni = 0; ni < 4; ++ni)
        b8[ni] = *(const long*)(const void*)(ldsB + (wn * 4 + ni) * 1024 + ksub * 512 + fo);
#pragma unroll
      for (int mi = 0; mi < 4; ++mi)
#pragma unroll
        for (int ni = 0; ni < 4; ++ni)
          acc[mi][ni] = __builtin_amdgcn_mfma_f32_16x16x32_fp8_fp8(a8[mi], b8[ni], acc[mi][ni], 0, 0, 0);
    }
  }
  float b2v[4];
#pragma unroll
  for (int ni = 0; ni < 4; ++ni)
    b2v[ni] = b2[e * DOUT + ntile * 128 + wn * 64 + ni * 16 + (lane & 15)];
#pragma unroll
  for (int mi = 0; mi < 4; ++mi)
#pragma unroll
    for (int r = 0; r < 4; ++r) {
      int ri = mtile * 128 + wm * 64 + mi * 16 + ((lane >> 4) << 2) + r;
      if (ri < cnt) {
        int ent = lists[e * NB + ri];
        int b = ent >> 2, slot = ent & 3;
#pragma unroll
        for (int ni = 0; ni < 4; ++ni) {
          int o = ntile * 128 + wn * 64 + ni * 16 + (lane & 15);
          contrib[(size_t)(b * 4 + slot) * DOUT + o] = f2h(acc[mi][ni][r] + b2v[ni]);
        }
      }
    }
}

// ---------- final: mean over 4 winner slots ----------
__global__ void finalize_kernel(const u16* __restrict__ contrib, float* __restrict__ out)
{
  int gid = blockIdx.x * 256 + threadIdx.x;
  int b = gid >> 7, o8 = (gid & 127) << 3;
  float s[8] = {0, 0, 0, 0, 0, 0, 0, 0};
#pragma unroll
  for (int sl = 0; sl < 4; ++sl) {
    short8 v = *(const short8*)(contrib + (size_t)(b * 4 + sl) * DOUT + o8);
#pragma unroll
    for (int j = 0; j < 8; ++j) s[j] += h2f((u16)v[j]);
  }
  float* op = out + (size_t)b * DOUT + o8;
#pragma unroll
  for (int j = 0; j < 8; ++j) op[j] = s[j] * 0.25f;
}

extern "C" void kernel_launch(void* const* d_in, const int* in_sizes, int n_in,
                              void* d_out, int out_size, void* d_ws, size_t ws_size,
                              hipStream_t stream)
{
  (void)in_sizes; (void)n_in; (void)out_size;
  if (ws_size < WS_NEED_SM) return;
  const bool big = (ws_size >= WS_NEED_BIG);

  const float* x  = (const float*)d_in[0];
  const float* W1 = (const float*)d_in[1];
  const float* b1 = (const float*)d_in[2];
  const float* W2 = (const float*)d_in[3];
  const float* b2 = (const float*)d_in[4];
  const float* Wb = (const float*)d_in[5];
  const float* bb = (const float*)d_in[6];

  char* ws = (char*)d_ws;
  float* outMain = (float*)d_out;
  float* outIdx  = (float*)d_out + (size_t)NB * DOUT;

  if (big) {
    u16* px      = (u16*)(ws + PXB);
    u16* pw1     = (u16*)(ws + PW1B);
    u8*  hfull   = (u8*)(ws + HFULLB);
    u8*  pw2f8   = (u8*)(ws + PW2F8B);
    u16* contrib = (u16*)(ws + CONTRB);
    float* bidp  = (float*)(ws + RPARTB);                        // early (dead before rpart writes)
    int* cnt1e   = (int*)(ws + RPARTB + (size_t)512 * 1024);     // early
    float* bids  = (float*)(ws + BIDSB);
    int* lists   = (int*)(ws + LISTSB);
    int* rle     = (int*)(ws + LISTSB);                          // early (dead before build_lists)
    int* counts  = (int*)(ws + CNTB);
    int* rcnt1   = (int*)(ws + RCNTB);
    int* rcnt2   = (int*)(ws + RCNTB + 4);
    u32* rlist1  = (u32*)(ws + RLIST1B);
    u32* rlist2  = (u32*)(ws + RLIST2B);
    double* rpart = (double*)(ws + RPARTB);
    float* rbp   = (float*)(ws + RBPB);

    hipMemsetAsync(rcnt1, 0, 2 * sizeof(int), stream);
    hipMemsetAsync(cnt1e, 0, 16 * sizeof(int), stream);
    pack_x_kernel <<<2048, 256, 0, stream>>>(x, px);
    pack_w1_kernel<<<16384, 256, 0, stream>>>(W1, pw1);
    gemm1_bids_kernel<true><<<1024, 256, 0, stream>>>(px, pw1, b1, Wb, bidp, hfull);
    topk_kernel<<<16, 256, 0, stream>>>(bidp, bb, bids, outIdx, rcnt1, rlist1, cnt1e, rle);
    repair1_kernel<<<dim3(16, 16, 2), 256, 0, stream>>>(px, pw1, b1, Wb, cnt1e, rle, rbp);
    repair1_final_kernel<<<64, 64, 0, stream>>>(bb, rcnt1, rlist1, rbp, bids, outIdx, rcnt2, rlist2);
    repair_partial_kernel<<<2048, 256, 0, stream>>>(x, W1, b1, Wb, rcnt2, rlist2, rpart);  // overwrites bidp/cnt1e (dead)
    repair_final_kernel<<<64, 64, 0, stream>>>(bids, bb, rcnt2, rlist2, rpart, outIdx);
    build_lists_kernel<<<16, 256, 0, stream>>>(outIdx, lists, counts);   // overwrites rle (dead)
    pack_w2f8_kernel<<<16384, 256, 0, stream>>>(W2, pw2f8);              // overlays pw1 (dead)
    gemm2f8_kernel<<<4096, 256, 0, stream>>>(hfull, pw2f8, b2, lists, counts, contrib);
    finalize_kernel<<<2048, 256, 0, stream>>>(contrib, outMain);
  } else {
    u16* px      = (u16*)(ws + PX_OFF);
    u16* xsel    = (u16*)(ws + XSEL_OFF);
    u16* contrib = (u16*)(ws + CONTRIB_OFF);
    float* bidp  = (float*)(ws + RPART_OFF);                     // early (dead before rpart writes)
    int* cnt1e   = (int*)(ws + RPART_OFF + (size_t)512 * 1024);  // early
    u16* pw1     = (u16*)(ws + PW1_OFF);
    u16* pw2     = (u16*)(ws + PW2_OFF);
    u16* hselh   = (u16*)(ws + HSEL_OFF);
    float* bids  = (float*)(ws + BIDS_OFF);
    int* lists   = (int*)(ws + LISTS_OFF);
    int* rle     = (int*)(ws + LISTS_OFF);                       // early
    int* counts  = (int*)(ws + CNT_OFF);
    int* rcnt1   = (int*)(ws + RCNT_OFF);
    int* rcnt2   = (int*)(ws + RCNT_OFF + 4);
    u32* rlist1  = (u32*)(ws + RLIST1_OFF);
    u32* rlist2  = (u32*)(ws + RLIST2_OFF);
    double* rpart = (double*)(ws + RPART_OFF);
    float* rbp   = (float*)(ws + RBP_OFF);

    hipMemsetAsync(rcnt1, 0, 2 * sizeof(int), stream);
    hipMemsetAsync(cnt1e, 0, 16 * sizeof(int), stream);
    pack_x_kernel <<<2048, 256, 0, stream>>>(x, px);
    pack_w1_kernel<<<16384, 256, 0, stream>>>(W1, pw1);
    gemm1_bids_kernel<false><<<1024, 256, 0, stream>>>(px, pw1, b1, Wb, bidp, nullptr);
    topk_kernel<<<16, 256, 0, stream>>>(bidp, bb, bids, outIdx, rcnt1, rlist1, cnt1e, rle);
    repair1_kernel<<<dim3(16, 16, 2), 256, 0, stream>>>(px, pw1, b1, Wb, cnt1e, rle, rbp);
    repair1_final_kernel<<<64, 64, 0, stream>>>(bb, rcnt1, rlist1, rbp, bids, outIdx, rcnt2, rlist2);
    repair_partial_kernel<<<2048, 256, 0, stream>>>(x, W1, b1, Wb, rcnt2, rlist2, rpart);
    repair_final_kernel<<<64, 64, 0, stream>>>(bids, bb, rcnt2, rlist2, rpart, outIdx);
    build_lists_kernel<<<16, 256, 0, stream>>>(outIdx, lists, counts);
    gather_xsel_kernel<<<4096, 256, 0, stream>>>(x, lists, counts, xsel);
    hsel_kernel<<<dim3(32, 16, 4), 256, 0, stream>>>(xsel, pw1, b1, counts, hselh);
    pack_w2_kernel<<<16384, 256, 0, stream>>>(W2, pw2);
    gemm2_kernel<<<dim3(32, 8, 16), 256, 0, stream>>>(hselh, pw2, b2, lists, counts, contrib);
    finalize_kernel<<<2048, 256, 0, stream>>>(contrib, outMain);
  }
}

// Round 15
// 845.209 us; speedup vs baseline: 2.1552x; 1.0192x over previous
//
#include <hip/hip_runtime.h>
#include <stdint.h>

typedef unsigned short u16;
typedef unsigned char u8;
typedef unsigned int u32;
typedef __attribute__((ext_vector_type(8))) short short8;
typedef __attribute__((ext_vector_type(8))) _Float16 half8;
typedef __attribute__((ext_vector_type(4))) float f32x4;

static constexpr int NE = 16, NB = 4096, DIN = 1024, DH = 2048, DOUT = 1024;
#define THR_GAP1 5e-3f
#define THR_GAP2 1e-4f

// ---- SMALL-path ws layout (~235 MiB) ----
static constexpr size_t PX_OFF      = 0;
static constexpr size_t XSEL_OFF    = 0;
static constexpr size_t CONTRIB_OFF = 0;
static constexpr size_t PW1_OFF     = (size_t)32 * 1024 * 1024;
static constexpr size_t PW2_OFF     = PW1_OFF;
static constexpr size_t HSEL_OFF    = PW1_OFF + (size_t)128 * 1024 * 1024;
static constexpr size_t BIDS_OFF    = HSEL_OFF + (size_t)16384 * 2048 * 2;
static constexpr size_t LISTS_OFF   = BIDS_OFF + (size_t)NE * NB * 4;   // rle early / lists late
static constexpr size_t CNT_OFF     = LISTS_OFF + (size_t)NE * NB * 4;
static constexpr size_t RCNT_OFF    = CNT_OFF + 64;
static constexpr size_t RLIST1_OFF  = RCNT_OFF + 64;
static constexpr size_t RLIST2_OFF  = RLIST1_OFF + (size_t)4096 * 4;
static constexpr size_t RPART_OFF   = RLIST2_OFF + (size_t)4096 * 4;    // bidp+cnt1e early / rpart late
static constexpr size_t RBP_OFF     = RPART_OFF + (size_t)4096 * 128 * 8;
static constexpr size_t WS_NEED_SM  = RBP_OFF + (size_t)16 * 16 * 4096 * 4;

// ---- BIG-path ws layout (~281 MiB) ----
static constexpr size_t PXB      = 0;                                    // 16 MiB
static constexpr size_t PW1B     = (size_t)16 * 1024 * 1024;             // 128 MiB (dead after repair1)
static constexpr size_t HFULLB   = (size_t)144 * 1024 * 1024;            // 128 MiB fp8 h
static constexpr size_t PW2F8B   = (size_t)16 * 1024 * 1024;             // 32 MiB (overlay pw1 after repair1)
static constexpr size_t CONTRB   = (size_t)48 * 1024 * 1024;             // 32 MiB (overlay pw1; late)
static constexpr size_t BIDSB    = (size_t)272 * 1024 * 1024;
static constexpr size_t LISTSB   = BIDSB + (size_t)NE * NB * 4;          // rle early / lists late
static constexpr size_t CNTB     = LISTSB + (size_t)NE * NB * 4;
static constexpr size_t RCNTB    = CNTB + 64;
static constexpr size_t RLIST1B  = RCNTB + 64;
static constexpr size_t RLIST2B  = RLIST1B + (size_t)4096 * 4;
static constexpr size_t RPARTB   = RLIST2B + (size_t)4096 * 4;           // bidp+cnt1e early / rpart late
static constexpr size_t RBPB     = RPARTB + (size_t)4096 * 128 * 8;
static constexpr size_t WS_NEED_BIG = RBPB + (size_t)16 * 16 * 4096 * 4;
// bidp (512 KB) + cnt1e (64 B) live at RPART*_OFF: written by gemm1/topk, read by
// topk/repair1, DEAD before repair_partial (the rpart region's first writer).

__device__ __forceinline__ u16 f2h(float f) {
  union { _Float16 h; u16 u; } c; c.h = (_Float16)f; return c.u;
}
__device__ __forceinline__ float h2f(u16 v) {
  union { _Float16 h; u16 u; } c; c.u = v; return (float)c.h;
}
__device__ __forceinline__ u8 f2e4m3(float f) {
  return (u8)(__builtin_amdgcn_cvt_pk_fp8_f32(f, f, 0, false) & 0xFF);
}
__device__ __forceinline__ void glds16(const void* gsrc, void* ldst) {
  __builtin_amdgcn_global_load_lds(
      (const __attribute__((address_space(1))) u32*)gsrc,
      (__attribute__((address_space(3))) u32*)ldst, 16, 0, 0);
}

// ---------- pack kernels ----------
__global__ void pack_x_kernel(const float* __restrict__ x, u16* __restrict__ px) {
  int gid = blockIdx.x * 256 + threadIdx.x;
  int kk = gid & 127, b = gid >> 7;
  int k0 = kk * 8;
  const float* xp = x + (size_t)b * DIN + k0;
  short8 hv, lv;
#pragma unroll
  for (int i = 0; i < 8; ++i) {
    float f = xp[i];
    u16 hb = f2h(f);
    hv[i] = (short)hb;
    lv[i] = (short)f2h(f - h2f(hb));
  }
  int mtile = b >> 7, m = b & 127;
  int kstep = k0 >> 6, kt = (k0 >> 5) & 1;
  int lane = (m & 15) + (((k0 >> 3) & 3) << 4);
  int sub = (m >> 4) * 2 + kt;
  u16* img = px + (size_t)(mtile * 16 + kstep) * 16384;
  *(short8*)(img + (size_t)((0 + sub) * 64 + lane) * 8) = hv;
  *(short8*)(img + (size_t)((16 + sub) * 64 + lane) * 8) = lv;
}

__global__ void pack_w1_kernel(const float* __restrict__ W1, u16* __restrict__ pw1) {
  int gid = blockIdx.x * 256 + threadIdx.x;
  int n = gid & 2047;
  int kc = (gid >> 11) & 127;
  int e = gid >> 18;
  int k0 = kc * 8;
  const float* wp = W1 + ((size_t)e * DIN + k0) * DH + n;
  short8 hv, lv;
#pragma unroll
  for (int i = 0; i < 8; ++i) {
    float f = wp[(size_t)i * DH];
    u16 hb = f2h(f);
    hv[i] = (short)hb;
    lv[i] = (short)f2h(f - h2f(hb));
  }
  int ntile = n >> 7, nt4 = (n >> 4) & 7, kt = (k0 >> 5) & 1;
  int lane = (n & 15) + (((k0 >> 3) & 3) << 4);
  int sub = nt4 * 2 + kt;
  u16* img = pw1 + (size_t)((e * 16 + ntile) * 16 + (k0 >> 6)) * 16384;
  *(short8*)(img + (size_t)((0 + sub) * 64 + lane) * 8) = hv;
  *(short8*)(img + (size_t)((16 + sub) * 64 + lane) * 8) = lv;
}

// fp16 W2 image (small path)
__global__ void pack_w2_kernel(const float* __restrict__ W2, u16* __restrict__ pw2) {
  int gid = blockIdx.x * 256 + threadIdx.x;
  int n = gid & 1023;
  int kc = (gid >> 10) & 255;
  int e = gid >> 18;
  int k0 = kc * 8;
  const float* wp = W2 + ((size_t)e * DH + k0) * DOUT + n;
  short8 hv;
#pragma unroll
  for (int i = 0; i < 8; ++i) hv[i] = (short)f2h(wp[(size_t)i * DOUT]);
  int ntile = n >> 7, nt4 = (n >> 4) & 7, kt = (k0 >> 5) & 1;
  int lane = (n & 15) + (((k0 >> 3) & 3) << 4);
  int sub = nt4 * 2 + kt;
  u16* img = pw2 + (size_t)((e * 8 + ntile) * 32 + (k0 >> 6)) * 8192;
  *(short8*)(img + (size_t)(sub * 64 + lane) * 8) = hv;
}

// fp8 W2 image (big path)
__global__ void pack_w2f8_kernel(const float* __restrict__ W2, u8* __restrict__ pw2f8) {
  int gid = blockIdx.x * 256 + threadIdx.x;
  int n = gid & 1023;
  int kc = (gid >> 10) & 255;
  int e = gid >> 18;
  int k0 = kc * 8;
  const float* wp = W2 + ((size_t)e * DH + k0) * DOUT + n;
  float f[8];
#pragma unroll
  for (int i = 0; i < 8; ++i) f[i] = wp[(size_t)i * DOUT];
  u32 lo = (u32)__builtin_amdgcn_cvt_pk_fp8_f32(f[0], f[1], 0, false);
  lo = (u32)__builtin_amdgcn_cvt_pk_fp8_f32(f[2], f[3], (int)lo, true);
  u32 hi = (u32)__builtin_amdgcn_cvt_pk_fp8_f32(f[4], f[5], 0, false);
  hi = (u32)__builtin_amdgcn_cvt_pk_fp8_f32(f[6], f[7], (int)hi, true);
  int ntile = n >> 7, c = (n >> 4) & 7, ks = k0 >> 6;
  int l = (n & 15) + 16 * ((k0 & 63) >> 4);
  u8* img = pw2f8 + (size_t)((e * 8 + ntile) * 32 + ks) * 8192 + c * 1024 + l * 16 + (k0 & 15);
  *(u32*)img = lo;
  *(u32*)(img + 4) = hi;
}

// ---------- GEMM1: plain fp16, ng-split x2, XCD-chunked swizzle, partial bids ----------
template <bool SH>
__global__ __launch_bounds__(256, 4) void gemm1_bids_kernel(
    const u16* __restrict__ px, const u16* __restrict__ pw1,
    const float* __restrict__ b1, const float* __restrict__ Wb,
    float* __restrict__ bidp, u8* __restrict__ hfull)
{
  __shared__ u16 ldsA[8192];
  __shared__ u16 ldsB[8192];
  __shared__ float bidred[2][128];
  const int id = blockIdx.x;
  const int swz = (id & 7) * 128 + (id >> 3);          // bijective (1024 % 8 == 0)
  const int mtile = swz & 31, e = (swz >> 5) & 15, ng = swz >> 9;
  const int tid = threadIdx.x, w = tid >> 6, lane = tid & 63;
  const int wm = w >> 1, wn = w & 1;

  const char* Abase = (const char*)px + (size_t)(mtile * 16) * 32768;
  const char* BbaseE = (const char*)pw1 + (size_t)(e * 16) * 16 * 32768;

  float bp[4][4];
#pragma unroll
  for (int mi = 0; mi < 4; ++mi)
#pragma unroll
    for (int r = 0; r < 4; ++r) bp[mi][r] = 0.f;

  for (int nto = 0; nto < 8; ++nto) {
    int nt = ng * 8 + nto;
    f32x4 acc[4][4];
#pragma unroll
    for (int i = 0; i < 4; ++i)
#pragma unroll
      for (int j = 0; j < 4; ++j) acc[i][j] = (f32x4)0.f;
    const char* Bnt = BbaseE + (size_t)nt * 16 * 32768;

    for (int ks = 0; ks < 16; ++ks) {
      __syncthreads();
      const char* Ak = Abase + (size_t)ks * 32768;
      const char* Bk = Bnt + (size_t)ks * 32768;
#pragma unroll
      for (int i = 0; i < 4; ++i) {
        int c = w * 4 + i;
        glds16(Ak + c * 1024 + lane * 16, (char*)ldsA + c * 1024);
        glds16(Bk + c * 1024 + lane * 16, (char*)ldsB + c * 1024);
      }
      __syncthreads();
#pragma unroll
      for (int ksub = 0; ksub < 2; ++ksub) {
        half8 ah[4], bh[4];
#pragma unroll
        for (int mi = 0; mi < 4; ++mi)
          ah[mi] = *(const half8*)(const void*)(ldsA + (size_t)(((wm * 4 + mi) * 2 + ksub) * 64 + lane) * 8);
#pragma unroll
        for (int ni = 0; ni < 4; ++ni)
          bh[ni] = *(const half8*)(const void*)(ldsB + (size_t)(((wn * 4 + ni) * 2 + ksub) * 64 + lane) * 8);
#pragma unroll
        for (int mi = 0; mi < 4; ++mi)
#pragma unroll
          for (int ni = 0; ni < 4; ++ni)
            acc[mi][ni] = __builtin_amdgcn_mfma_f32_16x16x32_f16(ah[mi], bh[ni], acc[mi][ni], 0, 0, 0);
      }
    }
    float b1v[4], wbv[4];
#pragma unroll
    for (int ni = 0; ni < 4; ++ni) {
      int n = nt * 128 + wn * 64 + ni * 16 + (lane & 15);
      b1v[ni] = b1[e * DH + n];
      wbv[ni] = Wb[e * DH + n];
    }
#pragma unroll
    for (int mi = 0; mi < 4; ++mi)
#pragma unroll
      for (int r = 0; r < 4; ++r)
#pragma unroll
        for (int ni = 0; ni < 4; ++ni) {
          float v = fmaxf(acc[mi][ni][r] + b1v[ni], 0.f);
          bp[mi][r] += v * wbv[ni];
        }
    if (SH) {
#pragma unroll
      for (int mi = 0; mi < 4; ++mi)
#pragma unroll
        for (int r = 0; r < 4; ++r) {
          int row = mtile * 128 + wm * 64 + mi * 16 + ((lane >> 4) << 2) + r;
          u8* hrow = hfull + ((size_t)e * NB + row) * DH;
#pragma unroll
          for (int ni = 0; ni < 4; ++ni) {
            float v = fmaxf(acc[mi][ni][r] + b1v[ni], 0.f);
            hrow[nt * 128 + wn * 64 + ni * 16 + (lane & 15)] = f2e4m3(v);
          }
        }
    }
  }
#pragma unroll
  for (int mi = 0; mi < 4; ++mi)
#pragma unroll
    for (int r = 0; r < 4; ++r) {
      float s = bp[mi][r];
      s += __shfl_xor(s, 1);
      s += __shfl_xor(s, 2);
      s += __shfl_xor(s, 4);
      s += __shfl_xor(s, 8);
      if ((lane & 15) == 0)
        bidred[wn][wm * 64 + mi * 16 + ((lane >> 4) << 2) + r] = s;
    }
  __syncthreads();
  if (tid < 128)
    bidp[(size_t)(e * 2 + ng) * NB + mtile * 128 + tid] = bidred[0][tid] + bidred[1][tid];
}

// ---------- top-4 + tier-1 flagging with ambiguous-expert mask + per-expert lists ----------
__global__ void topk_kernel(const float* __restrict__ bidp, const float* __restrict__ bb,
                            float* __restrict__ bids, float* __restrict__ outIdx,
                            int* __restrict__ rcnt1, u32* __restrict__ rlist1,
                            int* __restrict__ cnt1e, int* __restrict__ rle)
{
  int b = blockIdx.x * 256 + threadIdx.x;
  float v[16];
#pragma unroll
  for (int e = 0; e < 16; ++e) {
    float s = bidp[(size_t)(e * 2) * NB + b] + bidp[(size_t)(e * 2 + 1) * NB + b] + bb[e];
    v[e] = s;
    bids[(size_t)e * NB + b] = s;
  }
  int ord[16]; u32 used = 0;
  for (int j = 0; j < 16; ++j) {
    int best = 0; float bv = -3.4e38f;
    for (int t = 0; t < 16; ++t)
      if (!((used >> t) & 1) && v[t] > bv) { bv = v[t]; best = t; }
    ord[j] = best; used |= 1u << best;
  }
  for (int k = 0; k < 4; ++k) outIdx[b * 4 + k] = (float)ord[k];
  bool flag = false;
  for (int j = 0; j < 4; ++j)
    if (v[ord[j]] - v[ord[j + 1]] < THR_GAP1) flag = true;
  if (flag) {
    float vmin = v[ord[3]] - 2.f * THR_GAP1;
    u32 mask = 0;
    for (int e = 0; e < 16; ++e)
      if (v[e] >= vmin) mask |= 1u << e;
    int slot = atomicAdd(rcnt1, 1);
    rlist1[slot] = (u32)b | (mask << 16);
    for (int e = 0; e < 16; ++e)
      if ((mask >> e) & 1) {
        int p = atomicAdd(&cnt1e[e], 1);
        rle[e * NB + p] = b;
      }
  }
}

// ---------- tier-1 repair: grid (nt=16, e=16, ms=2); m strided by 2 for 2 blocks/CU ----------
__global__ __launch_bounds__(256, 2) void repair1_kernel(
    const u16* __restrict__ px, const u16* __restrict__ pw1,
    const float* __restrict__ b1, const float* __restrict__ Wb,
    const int* __restrict__ cnt1e, const int* __restrict__ rle,
    float* __restrict__ rbp)
{
  __shared__ u16 ldsA[16384];
  __shared__ u16 ldsB[16384];
  __shared__ float bidred[2][128];
  const int nt = blockIdx.x, e = blockIdx.y, ms = blockIdx.z;
  const int cnt = cnt1e[e];
  if (cnt == 0) return;
  const int nm = (cnt + 127) >> 7;
  if (ms >= nm) return;
  const int tid = threadIdx.x, w = tid >> 6, lane = tid & 63;
  const int wm = w >> 1, wn = w & 1;
  const char* Bnt = (const char*)pw1 + (size_t)((e * 16 + nt) * 16) * 32768;
  const int* myList = rle + e * NB;

  float b1v[4], wbv[4];
#pragma unroll
  for (int ni = 0; ni < 4; ++ni) {
    int n = nt * 128 + wn * 64 + ni * 16 + (lane & 15);
    b1v[ni] = b1[e * DH + n];
    wbv[ni] = Wb[e * DH + n];
  }

  for (int m = ms; m < nm; m += 2) {
    int rowb[4];
#pragma unroll
    for (int t = 0; t < 4; ++t) {
      int ri = m * 128 + ((w & 1) * 4 + t) * 16 + (lane & 15);
      rowb[t] = myList[(ri < cnt) ? ri : (cnt - 1)];
    }
    f32x4 acc[4][4];
#pragma unroll
    for (int i = 0; i < 4; ++i)
#pragma unroll
      for (int j = 0; j < 4; ++j) acc[i][j] = (f32x4)0.f;

    for (int ks = 0; ks < 16; ++ks) {
      __syncthreads();
#pragma unroll
      for (int i = 0; i < 8; ++i) {
        int c = w * 8 + i;
        int b = rowb[i >> 1];
        const char* srcA = (const char*)px
            + (size_t)((b >> 7) * 16 + ks) * 32768
            + (c >> 4) * 16384
            + (((b & 127) >> 4) * 2 + (i & 1)) * 1024
            + ((b & 15) + ((lane >> 4) << 4)) * 16;
        glds16(srcA, (char*)ldsA + c * 1024);
        glds16(Bnt + (size_t)ks * 32768 + c * 1024 + lane * 16, (char*)ldsB + c * 1024);
      }
      __syncthreads();
#pragma unroll
      for (int ksub = 0; ksub < 2; ++ksub) {
        half8 ah[4], bh[4], t[4];
#pragma unroll
        for (int mi = 0; mi < 4; ++mi)
          ah[mi] = *(const half8*)(const void*)(ldsA + (size_t)(((wm * 4 + mi) * 2 + ksub) * 64 + lane) * 8);
#pragma unroll
        for (int ni = 0; ni < 4; ++ni)
          bh[ni] = *(const half8*)(const void*)(ldsB + (size_t)(((wn * 4 + ni) * 2 + ksub) * 64 + lane) * 8);
#pragma unroll
        for (int mi = 0; mi < 4; ++mi)
#pragma unroll
          for (int ni = 0; ni < 4; ++ni)
            acc[mi][ni] = __builtin_amdgcn_mfma_f32_16x16x32_f16(ah[mi], bh[ni], acc[mi][ni], 0, 0, 0);
#pragma unroll
        for (int ni = 0; ni < 4; ++ni)
          t[ni] = *(const half8*)(const void*)(ldsB + (size_t)((16 + (wn * 4 + ni) * 2 + ksub) * 64 + lane) * 8);
#pragma unroll
        for (int mi = 0; mi < 4; ++mi)
#pragma unroll
          for (int ni = 0; ni < 4; ++ni)
            acc[mi][ni] = __builtin_amdgcn_mfma_f32_16x16x32_f16(ah[mi], t[ni], acc[mi][ni], 0, 0, 0);
#pragma unroll
        for (int mi = 0; mi < 4; ++mi)
          ah[mi] = *(const half8*)(const void*)(ldsA + (size_t)((16 + (wm * 4 + mi) * 2 + ksub) * 64 + lane) * 8);
#pragma unroll
        for (int mi = 0; mi < 4; ++mi)
#pragma unroll
          for (int ni = 0; ni < 4; ++ni)
            acc[mi][ni] = __builtin_amdgcn_mfma_f32_16x16x32_f16(ah[mi], bh[ni], acc[mi][ni], 0, 0, 0);
      }
    }
    float bp[4][4];
#pragma unroll
    for (int mi = 0; mi < 4; ++mi)
#pragma unroll
      for (int r = 0; r < 4; ++r) {
        bp[mi][r] = 0.f;
#pragma unroll
        for (int ni = 0; ni < 4; ++ni) {
          float v = fmaxf(acc[mi][ni][r] + b1v[ni], 0.f);
          bp[mi][r] += v * wbv[ni];
        }
      }
#pragma unroll
    for (int mi = 0; mi < 4; ++mi)
#pragma unroll
      for (int r = 0; r < 4; ++r) {
        float s = bp[mi][r];
        s += __shfl_xor(s, 1);
        s += __shfl_xor(s, 2);
        s += __shfl_xor(s, 4);
        s += __shfl_xor(s, 8);
        if ((lane & 15) == 0)
          bidred[wn][wm * 64 + mi * 16 + ((lane >> 4) << 2) + r] = s;
      }
    __syncthreads();
    if (tid < 128) {
      int ri = m * 128 + tid;
      if (ri < cnt) {
        int row = myList[ri];
        rbp[(size_t)(e * 16 + nt) * 4096 + row] = bidred[0][tid] + bidred[1][tid];
      }
    }
  }
}

// ---------- tier-1 finalize ----------
__global__ void repair1_final_kernel(const float* __restrict__ bb,
                                     const int* __restrict__ rcnt1,
                                     const u32* __restrict__ rlist1,
                                     const float* __restrict__ rbp,
                                     float* __restrict__ bids,
                                     float* __restrict__ outIdx,
                                     int* __restrict__ rcnt2, u32* __restrict__ rlist2)
{
  int idx = blockIdx.x * 64 + threadIdx.x;
  int cnt = *rcnt1;
  if (idx >= cnt) return;
  u32 ent1 = rlist1[idx];
  int b = ent1 & 0xFFFF;
  u32 mask1 = ent1 >> 16;
  float v[16];
#pragma unroll
  for (int e = 0; e < 16; ++e) {
    if ((mask1 >> e) & 1) {
      float s = bb[e];
      for (int nt = 0; nt < 16; ++nt) s += rbp[(size_t)(e * 16 + nt) * 4096 + b];
      v[e] = s;
      bids[(size_t)e * NB + b] = s;
    } else {
      v[e] = bids[(size_t)e * NB + b];
    }
  }
  int ord[16]; u32 used = 0;
  for (int j = 0; j < 16; ++j) {
    int best = 0; float bv = -3.4e38f;
    for (int t = 0; t < 16; ++t)
      if (!((used >> t) & 1) && v[t] > bv) { bv = v[t]; best = t; }
    ord[j] = best; used |= 1u << best;
  }
  for (int k = 0; k < 4; ++k) outIdx[b * 4 + k] = (float)ord[k];
  u32 mask = 0;
  for (int j = 0; j < 4; ++j)
    if (v[ord[j]] - v[ord[j + 1]] < THR_GAP2) { mask |= 1u << ord[j]; mask |= 1u << ord[j + 1]; }
  if (mask) {
    int jj = 4;
    while (jj < 15 && ((mask >> ord[jj]) & 1) && v[ord[jj]] - v[ord[jj + 1]] < THR_GAP2) {
      mask |= 1u << ord[jj + 1]; ++jj;
    }
    int slot = atomicAdd(rcnt2, 1);
    rlist2[slot] = (u32)b | (mask << 16);
  }
}

// ---------- tier-2 fp64 ----------
__global__ __launch_bounds__(256) void repair_partial_kernel(
    const float* __restrict__ x, const float* __restrict__ W1,
    const float* __restrict__ b1, const float* __restrict__ Wb,
    const int* __restrict__ rcnt2, const u32* __restrict__ rlist2,
    double* __restrict__ rpart)
{
  __shared__ float xrow[DIN];
  __shared__ double red[256];
  const int tid = threadIdx.x;
  int cnt = *rcnt2;
  int nit = cnt << 7;
  for (int item = blockIdx.x; item < nit; item += gridDim.x) {
    int it = item >> 7, e = (item >> 3) & 15, jc = item & 7;
    u32 ent = rlist2[it];
    if (!((ent >> (16 + e)) & 1)) continue;
    int b = ent & 0xFFFF;
    for (int i = tid; i < DIN; i += 256) xrow[i] = x[(size_t)b * DIN + i];
    __syncthreads();
    int j = jc * 256 + tid;
    const float* wcol = W1 + (size_t)e * DIN * DH + j;
    double z0 = 0, z1 = 0, z2 = 0, z3 = 0;
    for (int k = 0; k < DIN; k += 4) {
      z0 += (double)xrow[k]     * (double)wcol[(size_t)k * DH];
      z1 += (double)xrow[k + 1] * (double)wcol[(size_t)(k + 1) * DH];
      z2 += (double)xrow[k + 2] * (double)wcol[(size_t)(k + 2) * DH];
      z3 += (double)xrow[k + 3] * (double)wcol[(size_t)(k + 3) * DH];
    }
    double z = ((z0 + z1) + (z2 + z3)) + (double)b1[e * DH + j];
    red[tid] = (z > 0.0) ? z * (double)Wb[e * DH + j] : 0.0;
    __syncthreads();
    for (int off = 128; off > 0; off >>= 1) {
      if (tid < off) red[tid] += red[tid + off];
      __syncthreads();
    }
    if (tid == 0) rpart[item] = red[0];
    __syncthreads();
  }
}

__global__ void repair_final_kernel(const float* __restrict__ bids,
                                    const float* __restrict__ bb,
                                    const int* __restrict__ rcnt2,
                                    const u32* __restrict__ rlist2,
                                    const double* __restrict__ rpart,
                                    float* __restrict__ outIdx)
{
  __shared__ double v[16];
  int cnt = *rcnt2;
  int tid = threadIdx.x;
  for (int it = blockIdx.x; it < cnt; it += gridDim.x) {
    u32 ent = rlist2[it];
    int b = ent & 0xFFFF;
    if (tid < 16) {
      double val;
      if ((ent >> (16 + tid)) & 1) {
        double s = (double)bb[tid];
        for (int jc = 0; jc < 8; ++jc) s += rpart[(it << 7) + (tid << 3) + jc];
        val = s;
      } else {
        val = (double)bids[(size_t)tid * NB + b];
      }
      v[tid] = val;
    }
    __syncthreads();
    if (tid == 0) {
      u32 used = 0;
      for (int k = 0; k < 4; ++k) {
        int best = 0; double bv = -1e300;
        for (int t = 0; t < 16; ++t)
          if (!((used >> t) & 1) && v[t] > bv) { bv = v[t]; best = t; }
        outIdx[b * 4 + k] = (float)best; used |= 1u << best;
      }
    }
    __syncthreads();
  }
}

// ---------- per-expert row lists: single-pass scan (17 barriers vs ~256) ----------
__global__ void build_lists_kernel(const float* __restrict__ outIdx,
                                   int* __restrict__ lists, int* __restrict__ counts)
{
  int e = blockIdx.x, tid = threadIdx.x;
  __shared__ int scan[256];
  int slot[16];
  int lc = 0;
#pragma unroll
  for (int j = 0; j < 16; ++j) {
    int b = tid * 16 + j;
    int s = -1;
#pragma unroll
    for (int k = 0; k < 4; ++k)
      if ((int)outIdx[b * 4 + k] == e) s = k;
    slot[j] = s;
    if (s >= 0) ++lc;
  }
  scan[tid] = lc;
  __syncthreads();
  for (int off = 1; off < 256; off <<= 1) {
    int t = (tid >= off) ? scan[tid - off] : 0;
    __syncthreads();
    scan[tid] += t;
    __syncthreads();
  }
  int pos = (tid > 0) ? scan[tid - 1] : 0;
#pragma unroll
  for (int j = 0; j < 16; ++j) {
    if (slot[j] >= 0) {
      int b = tid * 16 + j;
      lists[e * NB + pos] = (b << 2) | slot[j];
      ++pos;
    }
  }
  if (tid == 255) counts[e] = scan[255];
}

// ============ SMALL path ============
__global__ void gather_xsel_kernel(const float* __restrict__ x,
                                   const int* __restrict__ lists,
                                   const int* __restrict__ counts,
                                   u16* __restrict__ xsel)
{
  int tid = threadIdx.x;
  int sub = tid >> 6, lane = tid & 63;
  int ri = blockIdx.x * 4 + sub;
  int e = 0, off = 0;
  for (int i = 0; i < 16; ++i) {
    int c = counts[i];
    if (ri < off + c) { e = i; break; }
    off += c;
  }
  int b = lists[e * NB + (ri - off)] >> 2;
  const float* src = x + (size_t)b * DIN + lane * 16;
  u16* dst = xsel + (size_t)ri * DIN + lane * 16;
  short8 o0, o1;
#pragma unroll
  for (int j = 0; j < 8; ++j) o0[j] = (short)f2h(src[j]);
#pragma unroll
  for (int j = 0; j < 8; ++j) o1[j] = (short)f2h(src[8 + j]);
  *(short8*)dst = o0;
  *(short8*)(dst + 8) = o1;
}

__global__ __launch_bounds__(256, 2) void hsel_kernel(
    const u16* __restrict__ xsel, const u16* __restrict__ pw1,
    const float* __restrict__ b1, const int* __restrict__ counts,
    u16* __restrict__ hselh)
{
  __shared__ u16 ldsA[8192];
  __shared__ u16 ldsB[8192];
  const int mtile = blockIdx.x, e = blockIdx.y, ng = blockIdx.z;
  const int cnt = counts[e];
  if (mtile * 128 >= cnt) return;
  int offs = 0;
  for (int i = 0; i < e; ++i) offs += counts[i];
  const int tid = threadIdx.x, w = tid >> 6, lane = tid & 63;
  const int wm = w >> 1, wn = w & 1;

  int r0 = mtile * 128 + (w * 2) * 16 + (lane & 15);
  int r1 = r0 + 16;
  r0 = (r0 < cnt) ? r0 : (cnt - 1);
  r1 = (r1 < cnt) ? r1 : (cnt - 1);
  const u16* arow0 = xsel + (size_t)(offs + r0) * DIN;
  const u16* arow1 = xsel + (size_t)(offs + r1) * DIN;
  const char* BbaseE = (const char*)pw1 + (size_t)(e * 16) * 16 * 32768;

  for (int nto = 0; nto < 4; ++nto) {
    int nt = ng * 4 + nto;
    f32x4 acc[4][4];
#pragma unroll
    for (int i = 0; i < 4; ++i)
#pragma unroll
      for (int j = 0; j < 4; ++j) acc[i][j] = (f32x4)0.f;
    const char* Bnt = BbaseE + (size_t)nt * 16 * 32768;

    for (int ks = 0; ks < 16; ++ks) {
      __syncthreads();
#pragma unroll
      for (int i = 0; i < 4; ++i) {
        int c = w * 4 + i, kt = c & 1;
        const u16* ga = ((i >> 1) ? arow1 : arow0) + ks * 64 + kt * 32 + ((lane >> 4) << 3);
        glds16(ga, (char*)ldsA + c * 1024);
        glds16(Bnt + (size_t)ks * 32768 + c * 1024 + lane * 16, (char*)ldsB + c * 1024);
      }
      __syncthreads();
#pragma unroll
      for (int ksub = 0; ksub < 2; ++ksub) {
        half8 ah[4], bh[4];
#pragma unroll
        for (int mi = 0; mi < 4; ++mi)
          ah[mi] = *(const half8*)(const void*)(ldsA + (size_t)(((wm * 4 + mi) * 2 + ksub) * 64 + lane) * 8);
#pragma unroll
        for (int ni = 0; ni < 4; ++ni)
          bh[ni] = *(const half8*)(const void*)(ldsB + (size_t)(((wn * 4 + ni) * 2 + ksub) * 64 + lane) * 8);
#pragma unroll
        for (int mi = 0; mi < 4; ++mi)
#pragma unroll
          for (int ni = 0; ni < 4; ++ni)
            acc[mi][ni] = __builtin_amdgcn_mfma_f32_16x16x32_f16(ah[mi], bh[ni], acc[mi][ni], 0, 0, 0);
      }
    }
    float b1v[4];
#pragma unroll
    for (int ni = 0; ni < 4; ++ni)
      b1v[ni] = b1[e * DH + nt * 128 + wn * 64 + ni * 16 + (lane & 15)];
#pragma unroll
    for (int mi = 0; mi < 4; ++mi)
#pragma unroll
      for (int r = 0; r < 4; ++r) {
        int ri = mtile * 128 + wm * 64 + mi * 16 + ((lane >> 4) << 2) + r;
        if (ri < cnt) {
          u16* hrow = hselh + (size_t)(offs + ri) * DH;
#pragma unroll
          for (int ni = 0; ni < 4; ++ni) {
            float v = fmaxf(acc[mi][ni][r] + b1v[ni], 0.f);
            hrow[nt * 128 + wn * 64 + ni * 16 + (lane & 15)] = f2h(v);
          }
        }
      }
  }
}

__global__ __launch_bounds__(256, 2) void gemm2_kernel(
    const u16* __restrict__ hselh, const u16* __restrict__ pw2,
    const float* __restrict__ b2, const int* __restrict__ lists,
    const int* __restrict__ counts, u16* __restrict__ contrib)
{
  __shared__ u16 ldsA[8192], ldsB[8192];
  const int mtile = blockIdx.x, ntile = blockIdx.y, e = blockIdx.z;
  const int cnt = counts[e];
  if (mtile * 128 >= cnt) return;
  int offs = 0;
  for (int i = 0; i < e; ++i) offs += counts[i];
  const int tid = threadIdx.x, w = tid >> 6, lane = tid & 63;
  const int wm = w >> 1, wn = w & 1;

  int rowg[2];
#pragma unroll
  for (int t = 0; t < 2; ++t) {
    int ri = mtile * 128 + (w * 2 + t) * 16 + (lane & 15);
    rowg[t] = offs + ((ri < cnt) ? ri : (cnt - 1));
  }
  const char* Bbase = (const char*)pw2 + (size_t)((e * 8 + ntile) * 32) * 16384;

  f32x4 acc[4][4];
#pragma unroll
  for (int i = 0; i < 4; ++i)
#pragma unroll
    for (int j = 0; j < 4; ++j) acc[i][j] = (f32x4)0.f;

  for (int ks = 0; ks < 32; ++ks) {
    __syncthreads();
#pragma unroll
    for (int i = 0; i < 4; ++i) {
      int c = w * 4 + i, kt = c & 1;
      const u16* ga = hselh + (size_t)rowg[i >> 1] * DH + ks * 64 + kt * 32 + ((lane >> 4) << 3);
      glds16(ga, (char*)ldsA + c * 1024);
      glds16(Bbase + (size_t)ks * 16384 + c * 1024 + lane * 16, (char*)ldsB + c * 1024);
    }
    __syncthreads();
#pragma unroll
    for (int ksub = 0; ksub < 2; ++ksub) {
      half8 af[4], bf[4];
#pragma unroll
      for (int mi = 0; mi < 4; ++mi)
        af[mi] = *(const half8*)(const void*)(ldsA + (size_t)(((wm * 4 + mi) * 2 + ksub) * 64 + lane) * 8);
#pragma unroll
      for (int ni = 0; ni < 4; ++ni)
        bf[ni] = *(const half8*)(const void*)(ldsB + (size_t)(((wn * 4 + ni) * 2 + ksub) * 64 + lane) * 8);
#pragma unroll
      for (int mi = 0; mi < 4; ++mi)
#pragma unroll
        for (int ni = 0; ni < 4; ++ni)
          acc[mi][ni] = __builtin_amdgcn_mfma_f32_16x16x32_f16(af[mi], bf[ni], acc[mi][ni], 0, 0, 0);
    }
  }
  float b2v[4];
#pragma unroll
  for (int ni = 0; ni < 4; ++ni)
    b2v[ni] = b2[e * DOUT + ntile * 128 + wn * 64 + ni * 16 + (lane & 15)];
#pragma unroll
  for (int mi = 0; mi < 4; ++mi)
#pragma unroll
    for (int r = 0; r < 4; ++r) {
      int ri = mtile * 128 + wm * 64 + mi * 16 + ((lane >> 4) << 2) + r;
      if (ri < cnt) {
        int ent = lists[e * NB + ri];
        int b = ent >> 2, slot = ent & 3;
#pragma unroll
        for (int ni = 0; ni < 4; ++ni) {
          int o = ntile * 128 + wn * 64 + ni * 16 + (lane & 15);
          contrib[(size_t)(b * 4 + slot) * DOUT + o] = f2h(acc[mi][ni][r] + b2v[ni]);
        }
      }
    }
}

// ============ BIG path: gemm2 fp8, BK=128 (2 k-slabs/barrier), XCD swizzle, 4/CU ============
__global__ __launch_bounds__(256, 4) void gemm2f8_kernel(
    const u8* __restrict__ hfull, const u8* __restrict__ pw2f8,
    const float* __restrict__ b2, const int* __restrict__ lists,
    const int* __restrict__ counts, u16* __restrict__ contrib)
{
  __shared__ u8 ldsA[16384], ldsB[16384];
  const int id = blockIdx.x;
  const int swz = (id & 7) * 512 + (id >> 3);          // bijective (4096 % 8 == 0)
  const int mtile = swz & 31, ntile = (swz >> 5) & 7, e = swz >> 8;
  const int cnt = counts[e];
  if (mtile * 128 >= cnt) return;
  const int tid = threadIdx.x, w = tid >> 6, lane = tid & 63;
  const int wm = w >> 1, wn = w & 1;

  const u8* arow[2];
#pragma unroll
  for (int t = 0; t < 2; ++t) {
    int ri = mtile * 128 + (w * 2 + t) * 16 + (lane & 15);
    int b = lists[e * NB + ((ri < cnt) ? ri : (cnt - 1))] >> 2;
    arow[t] = hfull + ((size_t)e * NB + b) * DH;
  }
  const u8* Bbase = pw2f8 + (size_t)((e * 8 + ntile) * 32) * 8192;

  f32x4 acc[4][4];
#pragma unroll
  for (int i = 0; i < 4; ++i)
#pragma unroll
    for (int j = 0; j < 4; ++j) acc[i][j] = (f32x4)0.f;

  for (int ks = 0; ks < 16; ++ks) {
    __syncthreads();
#pragma unroll
    for (int s = 0; s < 2; ++s)
#pragma unroll
      for (int i = 0; i < 2; ++i) {
        int c = w * 2 + i;
        int k2 = ks * 2 + s;
        glds16(arow[i] + k2 * 64 + ((lane >> 4) << 4), ldsA + s * 8192 + c * 1024);
        glds16(Bbase + (size_t)k2 * 8192 + c * 1024 + lane * 16, ldsB + s * 8192 + c * 1024);
      }
    __syncthreads();
    int fo = (lane & 15) * 16 + (((lane >> 4) >> 1)) * 256 + ((lane >> 4) & 1) * 8;
#pragma unroll
    for (int s = 0; s < 2; ++s)
#pragma unroll
      for (int ksub = 0; ksub < 2; ++ksub) {
        long a8[4], b8[4];
#pragma unroll
        for (int mi = 0; mi < 4; ++mi)
          a8[mi] = *(const long*)(const void*)(ldsA + s * 8192 + (wm * 4 + mi) * 1024 + ksub * 512 + fo);
#pragma unroll
        for (int ni = 0; ni < 4; ++ni)
          b8[ni] = *(const long*)(const void*)(ldsB + s * 8192 + (wn * 4 + ni) * 1024 + ksub * 512 + fo);
#pragma unroll
        for (int mi = 0; mi < 4; ++mi)
#pragma unroll
          for (int ni = 0; ni < 4; ++ni)
            acc[mi][ni] = __builtin_amdgcn_mfma_f32_16x16x32_fp8_fp8(a8[mi], b8[ni], acc[mi][ni], 0, 0, 0);
      }
  }
  float b2v[4];
#pragma unroll
  for (int ni = 0; ni < 4; ++ni)
    b2v[ni] = b2[e * DOUT + ntile * 128 + wn * 64 + ni * 16 + (lane & 15)];
#pragma unroll
  for (int mi = 0; mi < 4; ++mi)
#pragma unroll
    for (int r = 0; r < 4; ++r) {
      int ri = mtile * 128 + wm * 64 + mi * 16 + ((lane >> 4) << 2) + r;
      if (ri < cnt) {
        int ent = lists[e * NB + ri];
        int b = ent >> 2, slot = ent & 3;
#pragma unroll
        for (int ni = 0; ni < 4; ++ni) {
          int o = ntile * 128 + wn * 64 + ni * 16 + (lane & 15);
          contrib[(size_t)(b * 4 + slot) * DOUT + o] = f2h(acc[mi][ni][r] + b2v[ni]);
        }
      }
    }
}

// ---------- final: mean over 4 winner slots ----------
__global__ void finalize_kernel(const u16* __restrict__ contrib, float* __restrict__ out)
{
  int gid = blockIdx.x * 256 + threadIdx.x;
  int b = gid >> 7, o8 = (gid & 127) << 3;
  float s[8] = {0, 0, 0, 0, 0, 0, 0, 0};
#pragma unroll
  for (int sl = 0; sl < 4; ++sl) {
    short8 v = *(const short8*)(contrib + (size_t)(b * 4 + sl) * DOUT + o8);
#pragma unroll
    for (int j = 0; j < 8; ++j) s[j] += h2f((u16)v[j]);
  }
  float* op = out + (size_t)b * DOUT + o8;
#pragma unroll
  for (int j = 0; j < 8; ++j) op[j] = s[j] * 0.25f;
}

extern "C" void kernel_launch(void* const* d_in, const int* in_sizes, int n_in,
                              void* d_out, int out_size, void* d_ws, size_t ws_size,
                              hipStream_t stream)
{
  (void)in_sizes; (void)n_in; (void)out_size;
  if (ws_size < WS_NEED_SM) return;
  const bool big = (ws_size >= WS_NEED_BIG);

  const float* x  = (const float*)d_in[0];
  const float* W1 = (const float*)d_in[1];
  const float* b1 = (const float*)d_in[2];
  const float* W2 = (const float*)d_in[3];
  const float* b2 = (const float*)d_in[4];
  const float* Wb = (const float*)d_in[5];
  const float* bb = (const float*)d_in[6];

  char* ws = (char*)d_ws;
  float* outMain = (float*)d_out;
  float* outIdx  = (float*)d_out + (size_t)NB * DOUT;

  if (big) {
    u16* px      = (u16*)(ws + PXB);
    u16* pw1     = (u16*)(ws + PW1B);
    u8*  hfull   = (u8*)(ws + HFULLB);
    u8*  pw2f8   = (u8*)(ws + PW2F8B);
    u16* contrib = (u16*)(ws + CONTRB);
    float* bidp  = (float*)(ws + RPARTB);                        // early (dead before rpart writes)
    int* cnt1e   = (int*)(ws + RPARTB + (size_t)512 * 1024);     // early
    float* bids  = (float*)(ws + BIDSB);
    int* lists   = (int*)(ws + LISTSB);
    int* rle     = (int*)(ws + LISTSB);                          // early (dead before build_lists)
    int* counts  = (int*)(ws + CNTB);
    int* rcnt1   = (int*)(ws + RCNTB);
    int* rcnt2   = (int*)(ws + RCNTB + 4);
    u32* rlist1  = (u32*)(ws + RLIST1B);
    u32* rlist2  = (u32*)(ws + RLIST2B);
    double* rpart = (double*)(ws + RPARTB);
    float* rbp   = (float*)(ws + RBPB);

    hipMemsetAsync(rcnt1, 0, 2 * sizeof(int), stream);
    hipMemsetAsync(cnt1e, 0, 16 * sizeof(int), stream);
    pack_x_kernel <<<2048, 256, 0, stream>>>(x, px);
    pack_w1_kernel<<<16384, 256, 0, stream>>>(W1, pw1);
    gemm1_bids_kernel<true><<<1024, 256, 0, stream>>>(px, pw1, b1, Wb, bidp, hfull);
    topk_kernel<<<16, 256, 0, stream>>>(bidp, bb, bids, outIdx, rcnt1, rlist1, cnt1e, rle);
    repair1_kernel<<<dim3(16, 16, 2), 256, 0, stream>>>(px, pw1, b1, Wb, cnt1e, rle, rbp);
    repair1_final_kernel<<<64, 64, 0, stream>>>(bb, rcnt1, rlist1, rbp, bids, outIdx, rcnt2, rlist2);
    repair_partial_kernel<<<2048, 256, 0, stream>>>(x, W1, b1, Wb, rcnt2, rlist2, rpart);  // overwrites bidp/cnt1e (dead)
    repair_final_kernel<<<64, 64, 0, stream>>>(bids, bb, rcnt2, rlist2, rpart, outIdx);
    build_lists_kernel<<<16, 256, 0, stream>>>(outIdx, lists, counts);   // overwrites rle (dead)
    pack_w2f8_kernel<<<16384, 256, 0, stream>>>(W2, pw2f8);              // overlays pw1 (dead)
    gemm2f8_kernel<<<4096, 256, 0, stream>>>(hfull, pw2f8, b2, lists, counts, contrib);
    finalize_kernel<<<2048, 256, 0, stream>>>(contrib, outMain);
  } else {
    u16* px      = (u16*)(ws + PX_OFF);
    u16* xsel    = (u16*)(ws + XSEL_OFF);
    u16* contrib = (u16*)(ws + CONTRIB_OFF);
    float* bidp  = (float*)(ws + RPART_OFF);                     // early (dead before rpart writes)
    int* cnt1e   = (int*)(ws + RPART_OFF + (size_t)512 * 1024);  // early
    u16* pw1     = (u16*)(ws + PW1_OFF);
    u16* pw2     = (u16*)(ws + PW2_OFF);
    u16* hselh   = (u16*)(ws + HSEL_OFF);
    float* bids  = (float*)(ws + BIDS_OFF);
    int* lists   = (int*)(ws + LISTS_OFF);
    int* rle     = (int*)(ws + LISTS_OFF);                       // early
    int* counts  = (int*)(ws + CNT_OFF);
    int* rcnt1   = (int*)(ws + RCNT_OFF);
    int* rcnt2   = (int*)(ws + RCNT_OFF + 4);
    u32* rlist1  = (u32*)(ws + RLIST1_OFF);
    u32* rlist2  = (u32*)(ws + RLIST2_OFF);
    double* rpart = (double*)(ws + RPART_OFF);
    float* rbp   = (float*)(ws + RBP_OFF);

    hipMemsetAsync(rcnt1, 0, 2 * sizeof(int), stream);
    hipMemsetAsync(cnt1e, 0, 16 * sizeof(int), stream);
    pack_x_kernel <<<2048, 256, 0, stream>>>(x, px);
    pack_w1_kernel<<<16384, 256, 0, stream>>>(W1, pw1);
    gemm1_bids_kernel<false><<<1024, 256, 0, stream>>>(px, pw1, b1, Wb, bidp, nullptr);
    topk_kernel<<<16, 256, 0, stream>>>(bidp, bb, bids, outIdx, rcnt1, rlist1, cnt1e, rle);
    repair1_kernel<<<dim3(16, 16, 2), 256, 0, stream>>>(px, pw1, b1, Wb, cnt1e, rle, rbp);
    repair1_final_kernel<<<64, 64, 0, stream>>>(bb, rcnt1, rlist1, rbp, bids, outIdx, rcnt2, rlist2);
    repair_partial_kernel<<<2048, 256, 0, stream>>>(x, W1, b1, Wb, rcnt2, rlist2, rpart);
    repair_final_kernel<<<64, 64, 0, stream>>>(bids, bb, rcnt2, rlist2, rpart, outIdx);
    build_lists_kernel<<<16, 256, 0, stream>>>(outIdx, lists, counts);
    gather_xsel_kernel<<<4096, 256, 0, stream>>>(x, lists, counts, xsel);
    hsel_kernel<<<dim3(32, 16, 4), 256, 0, stream>>>(xsel, pw1, b1, counts, hselh);
    pack_w2_kernel<<<16384, 256, 0, stream>>>(W2, pw2);
    gemm2_kernel<<<dim3(32, 8, 16), 256, 0, stream>>>(hselh, pw2, b2, lists, counts, contrib);
    finalize_kernel<<<2048, 256, 0, stream>>>(contrib, outMain);
  }
}